// Round 1
// baseline (2989.570 us; speedup 1.0000x reference)
//
#include <hip/hip_runtime.h>

#define H 128
#define EF 32
#define TT 14
#define LH 32
#define KDIM 416   // 3H+EF
#define GOUT 512   // [r_pre, z_pre, i_n, h_n] each 128
#define KTOT 544   // 416 (agg) + 128 (memory)

__device__ __forceinline__ float sigmoidf_(float x) { return 1.0f / (1.0f + __expf(-x)); }
__device__ __forceinline__ float tanhfast_(float x) { float e = __expf(2.0f * x); return 1.0f - 2.0f / (e + 1.0f); }

// ---------------- K1: build Wcat [544][512] and W1t [384][64] ----------------
__global__ __launch_bounds__(256) void build_weights(
    const float* __restrict__ Wih, const float* __restrict__ Whh,
    const float* __restrict__ W1, float* __restrict__ Wcat, float* __restrict__ W1t) {
  int i = blockIdx.x * 256 + threadIdx.x;
  const int tot1 = KTOT * GOUT;
  if (i < tot1) {
    int k = i >> 9;        // / 512
    int o = i & 511;
    int j = o & 127;
    float v = 0.f;
    if (o < 256) {  // r (o<128) and z (o<256): gi+gh fused
      int row = (o < 128) ? j : (128 + j);
      v = (k < KDIM) ? Wih[row * KDIM + k] : Whh[row * H + (k - KDIM)];
    } else if (o < 384) {  // i_n
      v = (k < KDIM) ? Wih[(256 + j) * KDIM + k] : 0.f;
    } else {               // h_n
      v = (k < KDIM) ? 0.f : Whh[(256 + j) * H + (k - KDIM)];
    }
    Wcat[i] = v;
  } else {
    int i2 = i - tot1;
    if (i2 < 384 * 64) {
      int jj = i2 >> 6, o = i2 & 63;
      W1t[i2] = W1[o * 384 + jj];
    }
  }
}

// ---------------- K2a: degree count ----------------
__global__ void count_kernel(const int* __restrict__ src, const int* __restrict__ dst,
                             int* cnt, int E) {
  int e = blockIdx.x * blockDim.x + threadIdx.x;
  if (e < E) {
    atomicAdd(&cnt[dst[e]], 1);
    atomicAdd(&cnt[src[e]], 1);
  }
}

// ---------------- K2b: exclusive scan (single block) ----------------
__global__ __launch_bounds__(1024) void scan_kernel(const int* __restrict__ cnt,
                                                    int* __restrict__ offs,
                                                    int* __restrict__ cursor, int N) {
  __shared__ int part[1024];
  int tid = threadIdx.x;
  int chunk = (N + 1023) / 1024;
  int beg = tid * chunk;
  int end = min(beg + chunk, N);
  int s = 0;
  for (int i = beg; i < end; i++) s += cnt[i];
  part[tid] = s;
  __syncthreads();
  for (int d = 1; d < 1024; d <<= 1) {
    int v = (tid >= d) ? part[tid - d] : 0;
    __syncthreads();
    part[tid] += v;
    __syncthreads();
  }
  int run = (tid > 0) ? part[tid - 1] : 0;
  for (int i = beg; i < end; i++) {
    offs[i] = run;
    cursor[i] = run;
    run += cnt[i];
  }
  if (tid == 1023) offs[N] = part[1023];
}

// ---------------- K2c: CSR fill ----------------
__global__ void fill_kernel(const int* __restrict__ src, const int* __restrict__ dst,
                            int* cursor, int* __restrict__ other, int* __restrict__ eid, int E) {
  int e = blockIdx.x * blockDim.x + threadIdx.x;
  if (e >= E) return;
  int s = src[e], d = dst[e];
  int p1 = atomicAdd(&cursor[d], 1);
  other[p1] = s; eid[p1] = e;
  int p2 = atomicAdd(&cursor[s], 1);
  other[p2] = d; eid[p2] = e;
}

// ---------------- K2d: per-node aggregation -> agg [N][416] ----------------
// contribution per incident entry (e, u) for node v: [mem[u], mem[v], msg[e], cos((t[e]-lu[v])*w+b)]
__global__ __launch_bounds__(256) void agg_kernel(
    const int* __restrict__ offs, const int* __restrict__ other, const int* __restrict__ eid,
    const float* __restrict__ mem, const float* __restrict__ msg,
    const float* __restrict__ t, const float* __restrict__ lu,
    const float* __restrict__ tw, const float* __restrict__ tb,
    const int* __restrict__ cnt, float* __restrict__ agg, int N) {
  int v = blockIdx.x;
  int tid = threadIdx.x;
  int beg = offs[v], end = offs[v + 1];
  float lupd = lu[v];
  float w = 0.f, b = 0.f;
  if (tid >= 32 && tid < 160) { w = tw[tid - 32]; b = tb[tid - 32]; }
  float a0 = 0.f, a1 = 0.f;
  for (int p = beg; p < end; p++) {
    int u = other[p];
    int e = eid[p];
    if (tid < 128) a0 += mem[u * H + tid];
    if (tid < 32) a1 += msg[e * EF + tid];
    else if (tid < 160) a1 += cosf(fmaf(t[e] - lupd, w, b));
  }
  int cv = cnt[v];
  float inv = 1.f / (float)max(cv, 1);
  float* arow = agg + (size_t)v * KDIM;
  if (tid < 128) arow[tid] = a0 * inv;
  else arow[tid] = (cv > 0) ? mem[v * H + (tid - 128)] : 0.f;  // mean of cv copies of mem[v]
  if (tid < 160) arow[256 + tid] = a1 * inv;
}

// ---------------- K3: GEMM gates[N][512] = A[N][544] @ Wcat[544][512] ----------------
// A[n][k] = k<416 ? agg[n][k] : memory[n][k-416]
__global__ __launch_bounds__(256) void gru_gemm(
    const float* __restrict__ agg, const float* __restrict__ mem,
    const float* __restrict__ Wcat, float* __restrict__ gates, int N) {
  __shared__ float As[64][33];
  __shared__ float Bs[32][65];
  int tid = threadIdx.x;
  int row0 = blockIdx.x * 64;
  int col0 = blockIdx.y * 64;
  int tx = tid & 15, ty = tid >> 4;
  float acc[4][4] = {};
  for (int k0 = 0; k0 < KTOT; k0 += 32) {
#pragma unroll
    for (int i = 0; i < 8; i++) {
      int idx = tid + i * 256;
      int r = idx >> 5, cc = idx & 31;
      int gr = row0 + r, gc = k0 + cc;
      float v = 0.f;
      if (gr < N) v = (gc < KDIM) ? agg[(size_t)gr * KDIM + gc] : mem[(size_t)gr * H + gc - KDIM];
      As[r][cc] = v;
    }
#pragma unroll
    for (int i = 0; i < 8; i++) {
      int idx = tid + i * 256;
      int r = idx >> 6, cc = idx & 63;
      Bs[r][cc] = Wcat[(size_t)(k0 + r) * GOUT + col0 + cc];
    }
    __syncthreads();
#pragma unroll
    for (int kk = 0; kk < 32; kk++) {
      float a[4], bb[4];
#pragma unroll
      for (int i = 0; i < 4; i++) a[i] = As[ty * 4 + i][kk];
#pragma unroll
      for (int j = 0; j < 4; j++) bb[j] = Bs[kk][tx * 4 + j];
#pragma unroll
      for (int i = 0; i < 4; i++)
#pragma unroll
        for (int j = 0; j < 4; j++) acc[i][j] = fmaf(a[i], bb[j], acc[i][j]);
    }
    __syncthreads();
  }
#pragma unroll
  for (int i = 0; i < 4; i++) {
    int gr = row0 + ty * 4 + i;
    if (gr < N) {
#pragma unroll
      for (int j = 0; j < 4; j++) gates[(size_t)gr * GOUT + col0 + tx * 4 + j] = acc[i][j];
    }
  }
}

// ---------------- K4: GRU nonlinearity -> mem_new [N][128] ----------------
__global__ __launch_bounds__(256) void gru_finalize(
    const float* __restrict__ gates, const float* __restrict__ mem, const int* __restrict__ cnt,
    const float* __restrict__ bih, const float* __restrict__ bhh,
    float* __restrict__ mem_new, int N) {
  int i = blockIdx.x * 256 + threadIdx.x;
  if (i >= N * H) return;
  int n = i >> 7, j = i & 127;
  float m = mem[i];
  float o;
  if (cnt[n] > 0) {
    const float* g = gates + (size_t)n * GOUT;
    float r = sigmoidf_(g[j] + bih[j] + bhh[j]);
    float z = sigmoidf_(g[128 + j] + bih[128 + j] + bhh[128 + j]);
    float nn = tanhfast_(g[256 + j] + bih[256 + j] + r * (g[384 + j] + bhh[256 + j]));
    o = (1.f - z) * nn + z * m;
  } else {
    o = m;
  }
  mem_new[i] = o;
}

// ---------------- K5: per-edge fused LSTM + static + gather + predictor ----------------
__global__ __launch_bounds__(256) void edge_kernel(
    const int* __restrict__ src, const int* __restrict__ dst,
    const float* __restrict__ price_seq, const int* __restrict__ x_static,
    const float* __restrict__ mem_new,
    const float* __restrict__ party_emb, const float* __restrict__ state_emb,
    const float* __restrict__ static_W, const float* __restrict__ static_b,
    const float* __restrict__ lWih, const float* __restrict__ lWhh,
    const float* __restrict__ lbih, const float* __restrict__ lbhh,
    const float* __restrict__ price_W, const float* __restrict__ price_b,
    const float* __restrict__ W1t, const float* __restrict__ b1,
    const float* __restrict__ W2, const float* __restrict__ b2,
    float* __restrict__ out, int E) {
  __shared__ float ps[256 * TT];
  int tid = threadIdx.x;
  int e0 = blockIdx.x * 256;
  int nval = (min(256, E - e0)) * TT;
  for (int i = tid; i < nval; i += 256) ps[i] = price_seq[(size_t)e0 * TT + i];
  __syncthreads();
  int e = e0 + tid;
  if (e >= E) return;

  // ---- price LSTM (hidden 32, T=14), h/c fully in registers ----
  float h[LH], c[LH];
#pragma unroll
  for (int j = 0; j < LH; j++) { h[j] = 0.f; c[j] = 0.f; }
  for (int st = 0; st < TT; st++) {
    float x = ps[tid * TT + st];
    float hn[LH];
#pragma unroll
    for (int j = 0; j < LH; j++) {
      float gi = fmaf(x, lWih[j],          lbih[j]          + lbhh[j]);
      float gf = fmaf(x, lWih[LH + j],     lbih[LH + j]     + lbhh[LH + j]);
      float gg = fmaf(x, lWih[2 * LH + j], lbih[2 * LH + j] + lbhh[2 * LH + j]);
      float go = fmaf(x, lWih[3 * LH + j], lbih[3 * LH + j] + lbhh[3 * LH + j]);
#pragma unroll
      for (int k = 0; k < LH; k++) {
        float hk = h[k];
        gi = fmaf(hk, lWhh[j * LH + k], gi);
        gf = fmaf(hk, lWhh[(LH + j) * LH + k], gf);
        gg = fmaf(hk, lWhh[(2 * LH + j) * LH + k], gg);
        go = fmaf(hk, lWhh[(3 * LH + j) * LH + k], go);
      }
      float cj = fmaf(sigmoidf_(gf), c[j], sigmoidf_(gi) * tanhfast_(gg));
      c[j] = cj;
      hn[j] = sigmoidf_(go) * tanhfast_(cj);
    }
#pragma unroll
    for (int j = 0; j < LH; j++) h[j] = hn[j];
  }

  // ---- static features ----
  int s = src[e], d = dst[e];
  int p = x_static[s * 2], stt = x_static[s * 2 + 1];
  float sf[32];
#pragma unroll
  for (int k = 0; k < 16; k++) sf[k] = party_emb[p * 16 + k];
#pragma unroll
  for (int k = 0; k < 16; k++) sf[16 + k] = state_emb[stt * 16 + k];

  float hid[64];
#pragma unroll
  for (int o = 0; o < 64; o++) hid[o] = b1[o];

  const float* msrow = mem_new + (size_t)s * H;
  const float* mdrow = mem_new + (size_t)d * H;

  // ---- pol_ctx contribution: j in [0,128) of combined ----
  for (int j4 = 0; j4 < H; j4 += 4) {
    float4 ms = *reinterpret_cast<const float4*>(msrow + j4);
    float msa[4] = {ms.x, ms.y, ms.z, ms.w};
#pragma unroll
    for (int jj = 0; jj < 4; jj++) {
      int j = j4 + jj;
      float ss = static_b[j];
#pragma unroll
      for (int k = 0; k < 32; k++) ss = fmaf(sf[k], static_W[j * 32 + k], ss);
      float pol = msa[jj] + ss;
      const float* wr = W1t + j * 64;
#pragma unroll
      for (int o = 0; o < 64; o++) hid[o] = fmaf(pol, wr[o], hid[o]);
    }
  }

  // ---- comp_ctx + price_emb contributions: j in [128,384) of combined ----
  for (int j4 = 0; j4 < H; j4 += 4) {
    float4 md = *reinterpret_cast<const float4*>(mdrow + j4);
    float mda[4] = {md.x, md.y, md.z, md.w};
#pragma unroll
    for (int jj = 0; jj < 4; jj++) {
      int j = j4 + jj;
      float pe = price_b[j];
#pragma unroll
      for (int k = 0; k < LH; k++) pe = fmaf(h[k], price_W[j * LH + k], pe);
      float comp = mda[jj] + pe;
      const float* wr1 = W1t + (128 + j) * 64;
      const float* wr2 = W1t + (256 + j) * 64;
#pragma unroll
      for (int o = 0; o < 64; o++) hid[o] = fmaf(comp, wr1[o], fmaf(pe, wr2[o], hid[o]));
    }
  }

  float acc = b2[0];
#pragma unroll
  for (int o = 0; o < 64; o++) acc = fmaf(fmaxf(hid[o], 0.f), W2[o], acc);
  out[e] = acc;
}

// ---------------- launch ----------------
extern "C" void kernel_launch(void* const* d_in, const int* in_sizes, int n_in,
                              void* d_out, int out_size, void* d_ws, size_t ws_size,
                              hipStream_t stream) {
  const int* src = (const int*)d_in[0];
  const int* dst = (const int*)d_in[1];
  const float* t = (const float*)d_in[2];
  const float* msg = (const float*)d_in[3];
  const float* price_seq = (const float*)d_in[4];
  // d_in[5] trade_t unused by reference
  const int* x_static = (const int*)d_in[6];
  const float* memory = (const float*)d_in[7];
  const float* last_update = (const float*)d_in[8];
  const float* time_w = (const float*)d_in[9];
  const float* time_b = (const float*)d_in[10];
  const float* gWih = (const float*)d_in[11];
  const float* gWhh = (const float*)d_in[12];
  const float* gbih = (const float*)d_in[13];
  const float* gbhh = (const float*)d_in[14];
  const float* party_emb = (const float*)d_in[15];
  const float* state_emb = (const float*)d_in[16];
  const float* static_W = (const float*)d_in[17];
  const float* static_b = (const float*)d_in[18];
  const float* lWih = (const float*)d_in[19];
  const float* lWhh = (const float*)d_in[20];
  const float* lbih = (const float*)d_in[21];
  const float* lbhh = (const float*)d_in[22];
  const float* price_W = (const float*)d_in[23];
  const float* price_b = (const float*)d_in[24];
  const float* W1 = (const float*)d_in[25];
  const float* b1 = (const float*)d_in[26];
  const float* W2 = (const float*)d_in[27];
  const float* b2 = (const float*)d_in[28];
  float* out = (float*)d_out;

  const int E = in_sizes[0];
  const int N = in_sizes[8];

  char* ws = (char*)d_ws;
  size_t off = 0;
  auto alloc = [&](size_t bytes) { size_t o = off; off += (bytes + 255) & ~(size_t)255; return o; };
  int* cnt     = (int*)(ws + alloc((size_t)N * 4));
  int* offs    = (int*)(ws + alloc((size_t)(N + 1) * 4));
  int* cursor  = (int*)(ws + alloc((size_t)N * 4));
  int* other   = (int*)(ws + alloc((size_t)2 * E * 4));
  int* eid     = (int*)(ws + alloc((size_t)2 * E * 4));
  float* Wcat  = (float*)(ws + alloc((size_t)KTOT * GOUT * 4));
  float* W1t   = (float*)(ws + alloc((size_t)384 * 64 * 4));
  float* agg   = (float*)(ws + alloc((size_t)N * KDIM * 4));
  float* gates = (float*)(ws + alloc((size_t)N * GOUT * 4));
  float* mem_new = (float*)(ws + alloc((size_t)N * H * 4));
  (void)ws_size;

  hipMemsetAsync(cnt, 0, (size_t)N * 4, stream);

  int bw_elems = KTOT * GOUT + 384 * 64;
  build_weights<<<(bw_elems + 255) / 256, 256, 0, stream>>>(gWih, gWhh, W1, Wcat, W1t);
  count_kernel<<<(E + 255) / 256, 256, 0, stream>>>(src, dst, cnt, E);
  scan_kernel<<<1, 1024, 0, stream>>>(cnt, offs, cursor, N);
  fill_kernel<<<(E + 255) / 256, 256, 0, stream>>>(src, dst, cursor, other, eid, E);
  agg_kernel<<<N, 256, 0, stream>>>(offs, other, eid, memory, msg, t, last_update,
                                    time_w, time_b, cnt, agg, N);
  dim3 g3((N + 63) / 64, GOUT / 64);
  gru_gemm<<<g3, 256, 0, stream>>>(agg, memory, Wcat, gates, N);
  gru_finalize<<<(N * H + 255) / 256, 256, 0, stream>>>(gates, memory, cnt, gbih, gbhh, mem_new, N);
  edge_kernel<<<(E + 255) / 256, 256, 0, stream>>>(src, dst, price_seq, x_static, mem_new,
      party_emb, state_emb, static_W, static_b, lWih, lWhh, lbih, lbhh,
      price_W, price_b, W1t, b1, W2, b2, out, E);
}

// Round 2
// 1641.390 us; speedup vs baseline: 1.8214x; 1.8214x over previous
//
#include <hip/hip_runtime.h>

#define H 128
#define EF 32
#define TT 14
#define LH 32
#define KDIM 416   // 3H+EF
#define GOUT 512   // [r_pre, z_pre, i_n, h_n] each 128
#define KTOT 544   // 416 (agg) + 128 (memory)

__device__ __forceinline__ float sigmoidf_(float x) { return 1.0f / (1.0f + __expf(-x)); }
__device__ __forceinline__ float tanhfast_(float x) { float e = __expf(2.0f * x); return 1.0f - 2.0f / (e + 1.0f); }

// ---------------- K1: build Wcat [544][512] and W1t [384][64] ----------------
__global__ __launch_bounds__(256) void build_weights(
    const float* __restrict__ Wih, const float* __restrict__ Whh,
    const float* __restrict__ W1, float* __restrict__ Wcat, float* __restrict__ W1t) {
  int i = blockIdx.x * 256 + threadIdx.x;
  const int tot1 = KTOT * GOUT;
  if (i < tot1) {
    int k = i >> 9;        // / 512
    int o = i & 511;
    int j = o & 127;
    float v = 0.f;
    if (o < 256) {  // r (o<128) and z (o<256): gi+gh fused
      int row = (o < 128) ? j : (128 + j);
      v = (k < KDIM) ? Wih[row * KDIM + k] : Whh[row * H + (k - KDIM)];
    } else if (o < 384) {  // i_n
      v = (k < KDIM) ? Wih[(256 + j) * KDIM + k] : 0.f;
    } else {               // h_n
      v = (k < KDIM) ? 0.f : Whh[(256 + j) * H + (k - KDIM)];
    }
    Wcat[i] = v;
  } else {
    int i2 = i - tot1;
    if (i2 < 384 * 64) {
      int jj = i2 >> 6, o = i2 & 63;
      W1t[i2] = W1[o * 384 + jj];
    }
  }
}

// ---------------- K2a: degree count ----------------
__global__ void count_kernel(const int* __restrict__ src, const int* __restrict__ dst,
                             int* cnt, int E) {
  int e = blockIdx.x * blockDim.x + threadIdx.x;
  if (e < E) {
    atomicAdd(&cnt[dst[e]], 1);
    atomicAdd(&cnt[src[e]], 1);
  }
}

// ---------------- K2b: exclusive scan (single block) ----------------
__global__ __launch_bounds__(1024) void scan_kernel(const int* __restrict__ cnt,
                                                    int* __restrict__ offs,
                                                    int* __restrict__ cursor, int N) {
  __shared__ int part[1024];
  int tid = threadIdx.x;
  int chunk = (N + 1023) / 1024;
  int beg = tid * chunk;
  int end = min(beg + chunk, N);
  int s = 0;
  for (int i = beg; i < end; i++) s += cnt[i];
  part[tid] = s;
  __syncthreads();
  for (int d = 1; d < 1024; d <<= 1) {
    int v = (tid >= d) ? part[tid - d] : 0;
    __syncthreads();
    part[tid] += v;
    __syncthreads();
  }
  int run = (tid > 0) ? part[tid - 1] : 0;
  for (int i = beg; i < end; i++) {
    offs[i] = run;
    cursor[i] = run;
    run += cnt[i];
  }
  if (tid == 1023) offs[N] = part[1023];
}

// ---------------- K2c: CSR fill ----------------
__global__ void fill_kernel(const int* __restrict__ src, const int* __restrict__ dst,
                            int* cursor, int* __restrict__ other, int* __restrict__ eid, int E) {
  int e = blockIdx.x * blockDim.x + threadIdx.x;
  if (e >= E) return;
  int s = src[e], d = dst[e];
  int p1 = atomicAdd(&cursor[d], 1);
  other[p1] = s; eid[p1] = e;
  int p2 = atomicAdd(&cursor[s], 1);
  other[p2] = d; eid[p2] = e;
}

// ---------------- K2d: per-node aggregation -> agg [N][416] ----------------
__global__ __launch_bounds__(256) void agg_kernel(
    const int* __restrict__ offs, const int* __restrict__ other, const int* __restrict__ eid,
    const float* __restrict__ mem, const float* __restrict__ msg,
    const float* __restrict__ t, const float* __restrict__ lu,
    const float* __restrict__ tw, const float* __restrict__ tb,
    const int* __restrict__ cnt, float* __restrict__ agg, int N) {
  int v = blockIdx.x;
  int tid = threadIdx.x;
  int beg = offs[v], end = offs[v + 1];
  float lupd = lu[v];
  float w = 0.f, b = 0.f;
  if (tid >= 32 && tid < 160) { w = tw[tid - 32]; b = tb[tid - 32]; }
  float a0 = 0.f, a1 = 0.f;
  for (int p = beg; p < end; p++) {
    int u = other[p];
    int e = eid[p];
    if (tid < 128) a0 += mem[u * H + tid];
    if (tid < 32) a1 += msg[e * EF + tid];
    else if (tid < 160) a1 += cosf(fmaf(t[e] - lupd, w, b));
  }
  int cv = cnt[v];
  float inv = 1.f / (float)max(cv, 1);
  float* arow = agg + (size_t)v * KDIM;
  if (tid < 128) arow[tid] = a0 * inv;
  else arow[tid] = (cv > 0) ? mem[v * H + (tid - 128)] : 0.f;
  if (tid < 160) arow[256 + tid] = a1 * inv;
}

// ---------------- K3: GEMM gates[N][512] = A[N][544] @ Wcat[544][512] ----------------
__global__ __launch_bounds__(256) void gru_gemm(
    const float* __restrict__ agg, const float* __restrict__ mem,
    const float* __restrict__ Wcat, float* __restrict__ gates, int N) {
  __shared__ float As[64][33];
  __shared__ float Bs[32][65];
  int tid = threadIdx.x;
  int row0 = blockIdx.x * 64;
  int col0 = blockIdx.y * 64;
  int tx = tid & 15, ty = tid >> 4;
  float acc[4][4] = {};
  for (int k0 = 0; k0 < KTOT; k0 += 32) {
#pragma unroll
    for (int i = 0; i < 8; i++) {
      int idx = tid + i * 256;
      int r = idx >> 5, cc = idx & 31;
      int gr = row0 + r, gc = k0 + cc;
      float v = 0.f;
      if (gr < N) v = (gc < KDIM) ? agg[(size_t)gr * KDIM + gc] : mem[(size_t)gr * H + gc - KDIM];
      As[r][cc] = v;
    }
#pragma unroll
    for (int i = 0; i < 8; i++) {
      int idx = tid + i * 256;
      int r = idx >> 6, cc = idx & 63;
      Bs[r][cc] = Wcat[(size_t)(k0 + r) * GOUT + col0 + cc];
    }
    __syncthreads();
#pragma unroll
    for (int kk = 0; kk < 32; kk++) {
      float a[4], bb[4];
#pragma unroll
      for (int i = 0; i < 4; i++) a[i] = As[ty * 4 + i][kk];
#pragma unroll
      for (int j = 0; j < 4; j++) bb[j] = Bs[kk][tx * 4 + j];
#pragma unroll
      for (int i = 0; i < 4; i++)
#pragma unroll
        for (int j = 0; j < 4; j++) acc[i][j] = fmaf(a[i], bb[j], acc[i][j]);
    }
    __syncthreads();
  }
#pragma unroll
  for (int i = 0; i < 4; i++) {
    int gr = row0 + ty * 4 + i;
    if (gr < N) {
#pragma unroll
      for (int j = 0; j < 4; j++) gates[(size_t)gr * GOUT + col0 + tx * 4 + j] = acc[i][j];
    }
  }
}

// ---------------- K4: GRU nonlinearity -> mem_new [N][128] ----------------
__global__ __launch_bounds__(256) void gru_finalize(
    const float* __restrict__ gates, const float* __restrict__ mem, const int* __restrict__ cnt,
    const float* __restrict__ bih, const float* __restrict__ bhh,
    float* __restrict__ mem_new, int N) {
  int i = blockIdx.x * 256 + threadIdx.x;
  if (i >= N * H) return;
  int n = i >> 7, j = i & 127;
  float m = mem[i];
  float o;
  if (cnt[n] > 0) {
    const float* g = gates + (size_t)n * GOUT;
    float r = sigmoidf_(g[j] + bih[j] + bhh[j]);
    float z = sigmoidf_(g[128 + j] + bih[128 + j] + bhh[128 + j]);
    float nn = tanhfast_(g[256 + j] + bih[256 + j] + r * (g[384 + j] + bhh[256 + j]));
    o = (1.f - z) * nn + z * m;
  } else {
    o = m;
  }
  mem_new[i] = o;
}

// ---------------- K5a: price LSTM, 1 edge per wave ----------------
// Lane l: j = l&31, half = l>>5. Gate rows (torch order i,f,g,o):
//   rowA = half*32 + j  (i_j for low half, f_j for high half)
//   rowB = rowA + 64    (g_j for low half, o_j for high half)
// Whh rows for rowA/rowB live in VGPRs (64/lane, loaded once).
// h (wave-uniform, 32 values) lives in SGPRs via v_readlane each step.
__global__ __launch_bounds__(256) void lstm_kernel(
    const float* __restrict__ price_seq,
    const float* __restrict__ lWih, const float* __restrict__ lWhh,
    const float* __restrict__ lbih, const float* __restrict__ lbhh,
    float* __restrict__ hout, int E) {
  int lane = threadIdx.x & 63;
  int j = lane & 31;
  int half = lane >> 5;
  int gid = blockIdx.x * 4 + (threadIdx.x >> 6);
  int e = __builtin_amdgcn_readfirstlane(gid);
  if (e >= E) return;

  int rowA = half * 32 + j;
  int rowB = rowA + 64;

  // per-lane weights (held in VGPRs for the whole kernel)
  float wA[LH], wB[LH];
#pragma unroll
  for (int k4 = 0; k4 < LH; k4 += 4) {
    float4 a = *reinterpret_cast<const float4*>(lWhh + rowA * LH + k4);
    float4 b = *reinterpret_cast<const float4*>(lWhh + rowB * LH + k4);
    wA[k4] = a.x; wA[k4 + 1] = a.y; wA[k4 + 2] = a.z; wA[k4 + 3] = a.w;
    wB[k4] = b.x; wB[k4 + 1] = b.y; wB[k4 + 2] = b.z; wB[k4 + 3] = b.w;
  }
  float wihA = lWih[rowA], wihB = lWih[rowB];
  float bA = lbih[rowA] + lbhh[rowA];
  float bB = lbih[rowB] + lbhh[rowB];

  // wave-uniform price inputs -> SGPRs
  const float* pr = price_seq + (size_t)e * TT;
  float xv[TT];
#pragma unroll
  for (int st = 0; st < TT; st++) xv[st] = pr[st];

  int bpaddr = ((lane ^ 32) & 63) << 2;  // ds_bpermute byte addr for half-swap

  float hs[LH];
#pragma unroll
  for (int k = 0; k < LH; k++) hs[k] = 0.f;
  float c = 0.f;
  float hcur = 0.f;

#pragma unroll
  for (int st = 0; st < TT; st++) {
    float x = xv[st];
    float gA = fmaf(x, wihA, bA);
    float gB = fmaf(x, wihB, bB);
#pragma unroll
    for (int k = 0; k < LH; k++) {
      gA = fmaf(hs[k], wA[k], gA);
      gB = fmaf(hs[k], wB[k], gB);
    }
    float sA = sigmoidf_(gA);   // low: sig(i), high: sig(f)
    float tB = tanhfast_(gB);   // low: tanh(g)
    float sB = sigmoidf_(gB);   // high: sig(o)
    float sF = __int_as_float(__builtin_amdgcn_ds_bpermute(bpaddr, __float_as_int(sA)));  // low gets sig(f)
    float cn = fmaf(sF, c, sA * tB);  // valid on low half
    c = cn;
    float tc = tanhfast_(cn);
    float sO = __int_as_float(__builtin_amdgcn_ds_bpermute(bpaddr, __float_as_int(sB)));  // low gets sig(o)
    hcur = sO * tc;  // valid on low half: h_j
#pragma unroll
    for (int k = 0; k < LH; k++)
      hs[k] = __int_as_float(__builtin_amdgcn_readlane(__float_as_int(hcur), k));
  }
  if (lane < 32) hout[(size_t)e * LH + j] = hcur;
}

// ---------------- K5b: per-edge static + gather + predictor ----------------
__global__ __launch_bounds__(256) void pred_kernel(
    const int* __restrict__ src, const int* __restrict__ dst,
    const int* __restrict__ x_static,
    const float* __restrict__ mem_new, const float* __restrict__ hout,
    const float* __restrict__ party_emb, const float* __restrict__ state_emb,
    const float* __restrict__ static_W, const float* __restrict__ static_b,
    const float* __restrict__ price_W, const float* __restrict__ price_b,
    const float* __restrict__ W1t, const float* __restrict__ b1,
    const float* __restrict__ W2, const float* __restrict__ b2,
    float* __restrict__ out, int E) {
  int e = blockIdx.x * 256 + threadIdx.x;
  if (e >= E) return;

  float h[LH];
#pragma unroll
  for (int k4 = 0; k4 < LH; k4 += 4) {
    float4 v = *reinterpret_cast<const float4*>(hout + (size_t)e * LH + k4);
    h[k4] = v.x; h[k4 + 1] = v.y; h[k4 + 2] = v.z; h[k4 + 3] = v.w;
  }

  int s = src[e], d = dst[e];
  int p = x_static[s * 2], stt = x_static[s * 2 + 1];
  float sf[32];
#pragma unroll
  for (int k = 0; k < 16; k++) sf[k] = party_emb[p * 16 + k];
#pragma unroll
  for (int k = 0; k < 16; k++) sf[16 + k] = state_emb[stt * 16 + k];

  float hid[64];
#pragma unroll
  for (int o = 0; o < 64; o++) hid[o] = b1[o];

  const float* msrow = mem_new + (size_t)s * H;
  const float* mdrow = mem_new + (size_t)d * H;

  // pol_ctx contribution: j in [0,128)
  for (int j4 = 0; j4 < H; j4 += 4) {
    float4 ms = *reinterpret_cast<const float4*>(msrow + j4);
    float msa[4] = {ms.x, ms.y, ms.z, ms.w};
#pragma unroll
    for (int jj = 0; jj < 4; jj++) {
      int j = j4 + jj;
      float ss = static_b[j];
#pragma unroll
      for (int k = 0; k < 32; k++) ss = fmaf(sf[k], static_W[j * 32 + k], ss);
      float pol = msa[jj] + ss;
      const float* wr = W1t + j * 64;
#pragma unroll
      for (int o = 0; o < 64; o++) hid[o] = fmaf(pol, wr[o], hid[o]);
    }
  }

  // comp_ctx + price_emb contributions: j in [128,384)
  for (int j4 = 0; j4 < H; j4 += 4) {
    float4 md = *reinterpret_cast<const float4*>(mdrow + j4);
    float mda[4] = {md.x, md.y, md.z, md.w};
#pragma unroll
    for (int jj = 0; jj < 4; jj++) {
      int j = j4 + jj;
      float pe = price_b[j];
#pragma unroll
      for (int k = 0; k < LH; k++) pe = fmaf(h[k], price_W[j * LH + k], pe);
      float comp = mda[jj] + pe;
      const float* wr1 = W1t + (128 + j) * 64;
      const float* wr2 = W1t + (256 + j) * 64;
#pragma unroll
      for (int o = 0; o < 64; o++) hid[o] = fmaf(comp, wr1[o], fmaf(pe, wr2[o], hid[o]));
    }
  }

  float acc = b2[0];
#pragma unroll
  for (int o = 0; o < 64; o++) acc = fmaf(fmaxf(hid[o], 0.f), W2[o], acc);
  out[e] = acc;
}

// ---------------- launch ----------------
extern "C" void kernel_launch(void* const* d_in, const int* in_sizes, int n_in,
                              void* d_out, int out_size, void* d_ws, size_t ws_size,
                              hipStream_t stream) {
  const int* src = (const int*)d_in[0];
  const int* dst = (const int*)d_in[1];
  const float* t = (const float*)d_in[2];
  const float* msg = (const float*)d_in[3];
  const float* price_seq = (const float*)d_in[4];
  const int* x_static = (const int*)d_in[6];
  const float* memory = (const float*)d_in[7];
  const float* last_update = (const float*)d_in[8];
  const float* time_w = (const float*)d_in[9];
  const float* time_b = (const float*)d_in[10];
  const float* gWih = (const float*)d_in[11];
  const float* gWhh = (const float*)d_in[12];
  const float* gbih = (const float*)d_in[13];
  const float* gbhh = (const float*)d_in[14];
  const float* party_emb = (const float*)d_in[15];
  const float* state_emb = (const float*)d_in[16];
  const float* static_W = (const float*)d_in[17];
  const float* static_b = (const float*)d_in[18];
  const float* lWih = (const float*)d_in[19];
  const float* lWhh = (const float*)d_in[20];
  const float* lbih = (const float*)d_in[21];
  const float* lbhh = (const float*)d_in[22];
  const float* price_W = (const float*)d_in[23];
  const float* price_b = (const float*)d_in[24];
  const float* W1 = (const float*)d_in[25];
  const float* b1 = (const float*)d_in[26];
  const float* W2 = (const float*)d_in[27];
  const float* b2 = (const float*)d_in[28];
  float* out = (float*)d_out;

  const int E = in_sizes[0];
  const int N = in_sizes[8];

  char* ws = (char*)d_ws;
  size_t off = 0;
  auto alloc = [&](size_t bytes) { size_t o = off; off += (bytes + 255) & ~(size_t)255; return o; };
  int* cnt     = (int*)(ws + alloc((size_t)N * 4));
  int* offs    = (int*)(ws + alloc((size_t)(N + 1) * 4));
  int* cursor  = (int*)(ws + alloc((size_t)N * 4));
  int* other   = (int*)(ws + alloc((size_t)2 * E * 4));
  int* eid     = (int*)(ws + alloc((size_t)2 * E * 4));
  float* Wcat  = (float*)(ws + alloc((size_t)KTOT * GOUT * 4));
  float* W1t   = (float*)(ws + alloc((size_t)384 * 64 * 4));
  float* agg   = (float*)(ws + alloc((size_t)N * KDIM * 4));
  float* gates = (float*)(ws + alloc((size_t)N * GOUT * 4));
  float* mem_new = (float*)(ws + alloc((size_t)N * H * 4));
  float* hout  = agg;  // alias: agg [N*416 fl = 33.3MB] is dead after gru_gemm; hout needs E*32 fl = 25.6MB
  (void)ws_size;

  hipMemsetAsync(cnt, 0, (size_t)N * 4, stream);

  int bw_elems = KTOT * GOUT + 384 * 64;
  build_weights<<<(bw_elems + 255) / 256, 256, 0, stream>>>(gWih, gWhh, W1, Wcat, W1t);
  count_kernel<<<(E + 255) / 256, 256, 0, stream>>>(src, dst, cnt, E);
  scan_kernel<<<1, 1024, 0, stream>>>(cnt, offs, cursor, N);
  fill_kernel<<<(E + 255) / 256, 256, 0, stream>>>(src, dst, cursor, other, eid, E);
  agg_kernel<<<N, 256, 0, stream>>>(offs, other, eid, memory, msg, t, last_update,
                                    time_w, time_b, cnt, agg, N);
  dim3 g3((N + 63) / 64, GOUT / 64);
  gru_gemm<<<g3, 256, 0, stream>>>(agg, memory, Wcat, gates, N);
  gru_finalize<<<(N * H + 255) / 256, 256, 0, stream>>>(gates, memory, cnt, gbih, gbhh, mem_new, N);
  // lstm writes hout over agg -> must come after gru_gemm (stream-ordered)
  lstm_kernel<<<(E + 3) / 4, 256, 0, stream>>>(price_seq, lWih, lWhh, lbih, lbhh, hout, E);
  pred_kernel<<<(E + 255) / 256, 256, 0, stream>>>(src, dst, x_static, mem_new, hout,
      party_emb, state_emb, static_W, static_b, price_W, price_b,
      W1t, b1, W2, b2, out, E);
}

// Round 3
// 1519.461 us; speedup vs baseline: 1.9675x; 1.0802x over previous
//
#include <hip/hip_runtime.h>

#define H 128
#define EF 32
#define TT 14
#define LH 32
#define KDIM 416   // 3H+EF
#define GOUT 512   // [r_pre, z_pre, i_n, h_n] each 128
#define KTOT 544   // 416 (agg) + 128 (memory)
#define KP 288     // pred GEMM K: 128 ms + 128 md + 32 h

__device__ __forceinline__ float sigmoidf_(float x) { return 1.0f / (1.0f + __expf(-x)); }
__device__ __forceinline__ float tanhfast_(float x) { float e = __expf(2.0f * x); return 1.0f - 2.0f / (e + 1.0f); }

// ---------------- K1: build Wcat [544][512] ----------------
__global__ __launch_bounds__(256) void build_weights(
    const float* __restrict__ Wih, const float* __restrict__ Whh,
    float* __restrict__ Wcat) {
  int i = blockIdx.x * 256 + threadIdx.x;
  const int tot1 = KTOT * GOUT;
  if (i < tot1) {
    int k = i >> 9;        // / 512
    int o = i & 511;
    int j = o & 127;
    float v = 0.f;
    if (o < 256) {  // r (o<128) and z (o<256): gi+gh fused
      int row = (o < 128) ? j : (128 + j);
      v = (k < KDIM) ? Wih[row * KDIM + k] : Whh[row * H + (k - KDIM)];
    } else if (o < 384) {  // i_n
      v = (k < KDIM) ? Wih[(256 + j) * KDIM + k] : 0.f;
    } else {               // h_n
      v = (k < KDIM) ? 0.f : Whh[(256 + j) * H + (k - KDIM)];
    }
    Wcat[i] = v;
  }
}

// ---------------- K1b: predictor algebra collapse ----------------
// hid = W1a@ms + W1b@md + M2@h + bias2 + tab_p[p] + tab_s[st];  out = relu(hid)@W2 + b2
__global__ __launch_bounds__(256) void prep_pred(
    const float* __restrict__ W1, const float* __restrict__ b1,
    const float* __restrict__ static_W, const float* __restrict__ static_b,
    const float* __restrict__ price_W, const float* __restrict__ price_b,
    const float* __restrict__ party_emb, const float* __restrict__ state_emb,
    float* __restrict__ Wcomb, float* __restrict__ tab_p, float* __restrict__ tab_s,
    float* __restrict__ bias2) {
  __shared__ float G1[64][32];
  int tid = threadIdx.x;
  // G1[o][k] = sum_j W1[o][j]*static_W[j][k];  Wcomb rows 256..287 = M2^T
  for (int idx = tid; idx < 2048; idx += 256) {
    int o = idx >> 5, k = idx & 31;
    float g = 0.f, m = 0.f;
    for (int j = 0; j < 128; j++) {
      g = fmaf(W1[o * 384 + j], static_W[j * 32 + k], g);
      m = fmaf(W1[o * 384 + 128 + j] + W1[o * 384 + 256 + j], price_W[j * 32 + k], m);
    }
    G1[o][k] = g;
    Wcomb[(256 + k) * 64 + o] = m;
  }
  // Wcomb rows 0..255: transpose of W1[:,0:256]
  for (int idx = tid; idx < 256 * 64; idx += 256) {
    int j = idx >> 6, o = idx & 63;
    Wcomb[idx] = W1[o * 384 + j];
  }
  __syncthreads();
  for (int idx = tid; idx < 4 * 64; idx += 256) {
    int p = idx >> 6, o = idx & 63;
    float s = 0.f;
    for (int k = 0; k < 16; k++) s = fmaf(G1[o][k], party_emb[p * 16 + k], s);
    tab_p[idx] = s;
  }
  for (int idx = tid; idx < 50 * 64; idx += 256) {
    int si = idx >> 6, o = idx & 63;
    float s = 0.f;
    for (int k = 0; k < 16; k++) s = fmaf(G1[o][16 + k], state_emb[si * 16 + k], s);
    tab_s[idx] = s;
  }
  if (tid < 64) {
    float s = b1[tid];
    for (int j = 0; j < 128; j++) {
      s = fmaf(W1[tid * 384 + j], static_b[j], s);
      s = fmaf(W1[tid * 384 + 128 + j] + W1[tid * 384 + 256 + j], price_b[j], s);
    }
    bias2[tid] = s;
  }
}

// ---------------- K2a: degree count ----------------
__global__ void count_kernel(const int* __restrict__ src, const int* __restrict__ dst,
                             int* cnt, int E) {
  int e = blockIdx.x * blockDim.x + threadIdx.x;
  if (e < E) {
    atomicAdd(&cnt[dst[e]], 1);
    atomicAdd(&cnt[src[e]], 1);
  }
}

// ---------------- K2b: exclusive scan (single block) ----------------
__global__ __launch_bounds__(1024) void scan_kernel(const int* __restrict__ cnt,
                                                    int* __restrict__ offs,
                                                    int* __restrict__ cursor, int N) {
  __shared__ int part[1024];
  int tid = threadIdx.x;
  int chunk = (N + 1023) / 1024;
  int beg = tid * chunk;
  int end = min(beg + chunk, N);
  int s = 0;
  for (int i = beg; i < end; i++) s += cnt[i];
  part[tid] = s;
  __syncthreads();
  for (int d = 1; d < 1024; d <<= 1) {
    int v = (tid >= d) ? part[tid - d] : 0;
    __syncthreads();
    part[tid] += v;
    __syncthreads();
  }
  int run = (tid > 0) ? part[tid - 1] : 0;
  for (int i = beg; i < end; i++) {
    offs[i] = run;
    cursor[i] = run;
    run += cnt[i];
  }
  if (tid == 1023) offs[N] = part[1023];
}

// ---------------- K2c: CSR fill ----------------
__global__ void fill_kernel(const int* __restrict__ src, const int* __restrict__ dst,
                            int* cursor, int* __restrict__ other, int* __restrict__ eid, int E) {
  int e = blockIdx.x * blockDim.x + threadIdx.x;
  if (e >= E) return;
  int s = src[e], d = dst[e];
  int p1 = atomicAdd(&cursor[d], 1);
  other[p1] = s; eid[p1] = e;
  int p2 = atomicAdd(&cursor[s], 1);
  other[p2] = d; eid[p2] = e;
}

// ---------------- K2d: per-node aggregation -> agg [N][416] ----------------
__global__ __launch_bounds__(256) void agg_kernel(
    const int* __restrict__ offs, const int* __restrict__ other, const int* __restrict__ eid,
    const float* __restrict__ mem, const float* __restrict__ msg,
    const float* __restrict__ t, const float* __restrict__ lu,
    const float* __restrict__ tw, const float* __restrict__ tb,
    const int* __restrict__ cnt, float* __restrict__ agg, int N) {
  int v = blockIdx.x;
  int tid = threadIdx.x;
  int beg = offs[v], end = offs[v + 1];
  float lupd = lu[v];
  float w = 0.f, b = 0.f;
  if (tid >= 32 && tid < 160) { w = tw[tid - 32]; b = tb[tid - 32]; }
  float a0 = 0.f, a1 = 0.f;
  for (int p = beg; p < end; p++) {
    int u = other[p];
    int e = eid[p];
    if (tid < 128) a0 += mem[u * H + tid];
    if (tid < 32) a1 += msg[e * EF + tid];
    else if (tid < 160) a1 += cosf(fmaf(t[e] - lupd, w, b));
  }
  int cv = cnt[v];
  float inv = 1.f / (float)max(cv, 1);
  float* arow = agg + (size_t)v * KDIM;
  if (tid < 128) arow[tid] = a0 * inv;
  else arow[tid] = (cv > 0) ? mem[v * H + (tid - 128)] : 0.f;
  if (tid < 160) arow[256 + tid] = a1 * inv;
}

// ---------------- K3: GEMM gates[N][512] = A[N][544] @ Wcat[544][512] ----------------
__global__ __launch_bounds__(256) void gru_gemm(
    const float* __restrict__ agg, const float* __restrict__ mem,
    const float* __restrict__ Wcat, float* __restrict__ gates, int N) {
  __shared__ float As[64][33];
  __shared__ float Bs[32][65];
  int tid = threadIdx.x;
  int row0 = blockIdx.x * 64;
  int col0 = blockIdx.y * 64;
  int tx = tid & 15, ty = tid >> 4;
  float acc[4][4] = {};
  for (int k0 = 0; k0 < KTOT; k0 += 32) {
#pragma unroll
    for (int i = 0; i < 8; i++) {
      int idx = tid + i * 256;
      int r = idx >> 5, cc = idx & 31;
      int gr = row0 + r, gc = k0 + cc;
      float v = 0.f;
      if (gr < N) v = (gc < KDIM) ? agg[(size_t)gr * KDIM + gc] : mem[(size_t)gr * H + gc - KDIM];
      As[r][cc] = v;
    }
#pragma unroll
    for (int i = 0; i < 8; i++) {
      int idx = tid + i * 256;
      int r = idx >> 6, cc = idx & 63;
      Bs[r][cc] = Wcat[(size_t)(k0 + r) * GOUT + col0 + cc];
    }
    __syncthreads();
#pragma unroll
    for (int kk = 0; kk < 32; kk++) {
      float a[4], bb[4];
#pragma unroll
      for (int i = 0; i < 4; i++) a[i] = As[ty * 4 + i][kk];
#pragma unroll
      for (int j = 0; j < 4; j++) bb[j] = Bs[kk][tx * 4 + j];
#pragma unroll
      for (int i = 0; i < 4; i++)
#pragma unroll
        for (int j = 0; j < 4; j++) acc[i][j] = fmaf(a[i], bb[j], acc[i][j]);
    }
    __syncthreads();
  }
#pragma unroll
  for (int i = 0; i < 4; i++) {
    int gr = row0 + ty * 4 + i;
    if (gr < N) {
#pragma unroll
      for (int j = 0; j < 4; j++) gates[(size_t)gr * GOUT + col0 + tx * 4 + j] = acc[i][j];
    }
  }
}

// ---------------- K4: GRU nonlinearity -> mem_new [N][128] ----------------
__global__ __launch_bounds__(256) void gru_finalize(
    const float* __restrict__ gates, const float* __restrict__ mem, const int* __restrict__ cnt,
    const float* __restrict__ bih, const float* __restrict__ bhh,
    float* __restrict__ mem_new, int N) {
  int i = blockIdx.x * 256 + threadIdx.x;
  if (i >= N * H) return;
  int n = i >> 7, j = i & 127;
  float m = mem[i];
  float o;
  if (cnt[n] > 0) {
    const float* g = gates + (size_t)n * GOUT;
    float r = sigmoidf_(g[j] + bih[j] + bhh[j]);
    float z = sigmoidf_(g[128 + j] + bih[128 + j] + bhh[128 + j]);
    float nn = tanhfast_(g[256 + j] + bih[256 + j] + r * (g[384 + j] + bhh[256 + j]));
    o = (1.f - z) * nn + z * m;
  } else {
    o = m;
  }
  mem_new[i] = o;
}

// ---------------- K5a: price LSTM, 1 edge per wave ----------------
__global__ __launch_bounds__(256) void lstm_kernel(
    const float* __restrict__ price_seq,
    const float* __restrict__ lWih, const float* __restrict__ lWhh,
    const float* __restrict__ lbih, const float* __restrict__ lbhh,
    float* __restrict__ hout, int E) {
  int lane = threadIdx.x & 63;
  int j = lane & 31;
  int half = lane >> 5;
  int gid = blockIdx.x * 4 + (threadIdx.x >> 6);
  int e = __builtin_amdgcn_readfirstlane(gid);
  if (e >= E) return;

  int rowA = half * 32 + j;
  int rowB = rowA + 64;

  // per-lane weights, pinned in VGPRs (asm blocks rematerialization)
  float wA[LH], wB[LH];
#pragma unroll
  for (int k4 = 0; k4 < LH; k4 += 4) {
    float4 a = *reinterpret_cast<const float4*>(lWhh + rowA * LH + k4);
    float4 b = *reinterpret_cast<const float4*>(lWhh + rowB * LH + k4);
    wA[k4] = a.x; wA[k4 + 1] = a.y; wA[k4 + 2] = a.z; wA[k4 + 3] = a.w;
    wB[k4] = b.x; wB[k4 + 1] = b.y; wB[k4 + 2] = b.z; wB[k4 + 3] = b.w;
  }
  float wihA = lWih[rowA], wihB = lWih[rowB];
  float bA = lbih[rowA] + lbhh[rowA];
  float bB = lbih[rowB] + lbhh[rowB];
#pragma unroll
  for (int k4 = 0; k4 < LH; k4 += 4) {
    asm volatile("" : "+v"(wA[k4]), "+v"(wA[k4 + 1]), "+v"(wA[k4 + 2]), "+v"(wA[k4 + 3]));
    asm volatile("" : "+v"(wB[k4]), "+v"(wB[k4 + 1]), "+v"(wB[k4 + 2]), "+v"(wB[k4 + 3]));
  }
  asm volatile("" : "+v"(wihA), "+v"(wihB), "+v"(bA), "+v"(bB));

  // wave-uniform price inputs -> SGPRs, pinned
  const float* pr = price_seq + (size_t)e * TT;
  float xv[TT];
#pragma unroll
  for (int st = 0; st < TT; st++) xv[st] = pr[st];
  asm volatile("" : "+s"(xv[0]), "+s"(xv[1]), "+s"(xv[2]), "+s"(xv[3]), "+s"(xv[4]),
                    "+s"(xv[5]), "+s"(xv[6]), "+s"(xv[7]), "+s"(xv[8]), "+s"(xv[9]),
                    "+s"(xv[10]), "+s"(xv[11]), "+s"(xv[12]), "+s"(xv[13]));

  int bpaddr = ((lane ^ 32) & 63) << 2;  // ds_bpermute byte addr for half-swap

  float hs[LH];
#pragma unroll
  for (int k = 0; k < LH; k++) hs[k] = 0.f;
  float c = 0.f;
  float hcur = 0.f;

#pragma unroll
  for (int st = 0; st < TT; st++) {
    float x = xv[st];
    float gA = fmaf(x, wihA, bA);
    float gB = fmaf(x, wihB, bB);
#pragma unroll
    for (int k = 0; k < LH; k++) {
      gA = fmaf(hs[k], wA[k], gA);
      gB = fmaf(hs[k], wB[k], gB);
    }
    float sA = sigmoidf_(gA);   // low: sig(i), high: sig(f)
    float tB = tanhfast_(gB);   // low: tanh(g)
    float sB = sigmoidf_(gB);   // high: sig(o)
    float sF = __int_as_float(__builtin_amdgcn_ds_bpermute(bpaddr, __float_as_int(sA)));
    float cn = fmaf(sF, c, sA * tB);  // valid on low half
    c = cn;
    float tc = tanhfast_(cn);
    float sO = __int_as_float(__builtin_amdgcn_ds_bpermute(bpaddr, __float_as_int(sB)));
    hcur = sO * tc;  // valid on low half: h_j
#pragma unroll
    for (int k = 0; k < LH; k++)
      hs[k] = __int_as_float(__builtin_amdgcn_readlane(__float_as_int(hcur), k));
  }
  if (lane < 32) hout[(size_t)e * LH + j] = hcur;
}

// ---------------- K5b: pred GEMM out[E] from X[E][288] @ Wcomb[288][64] ----------------
__global__ __launch_bounds__(256) void pred_gemm(
    const int* __restrict__ src, const int* __restrict__ dst,
    const int* __restrict__ x_static,
    const float* __restrict__ mem_new, const float* __restrict__ hout,
    const float* __restrict__ Wcomb, const float* __restrict__ tab_p,
    const float* __restrict__ tab_s, const float* __restrict__ bias2,
    const float* __restrict__ W2, const float* __restrict__ b2,
    float* __restrict__ out, int E) {
  __shared__ float As[64][33];
  __shared__ float Bs[32][65];
  __shared__ int sidx[64], didx[64], pidx[64], stix[64];
  int tid = threadIdx.x;
  int row0 = blockIdx.x * 64;
  if (tid < 64) {
    int e = row0 + tid;
    int s = (e < E) ? src[e] : 0;
    int d = (e < E) ? dst[e] : 0;
    sidx[tid] = s; didx[tid] = d;
    pidx[tid] = x_static[s * 2]; stix[tid] = x_static[s * 2 + 1];
  }
  __syncthreads();
  int tx = tid & 15, ty = tid >> 4;
  float acc[4][4] = {};
  for (int k0 = 0; k0 < KP; k0 += 32) {
#pragma unroll
    for (int i = 0; i < 8; i++) {
      int idx = tid + i * 256;
      int r = idx >> 5, cc = idx & 31;
      int e = row0 + r;
      int k = k0 + cc;
      float v = 0.f;
      if (e < E) {
        if (k < 128) v = mem_new[(size_t)sidx[r] * H + k];
        else if (k < 256) v = mem_new[(size_t)didx[r] * H + (k - 128)];
        else v = hout[(size_t)e * LH + (k - 256)];
      }
      As[r][cc] = v;
    }
#pragma unroll
    for (int i = 0; i < 8; i++) {
      int idx = tid + i * 256;
      int r = idx >> 6, cc = idx & 63;
      Bs[r][cc] = Wcomb[(k0 + r) * 64 + cc];
    }
    __syncthreads();
#pragma unroll
    for (int kk = 0; kk < 32; kk++) {
      float a[4], bb[4];
#pragma unroll
      for (int i = 0; i < 4; i++) a[i] = As[ty * 4 + i][kk];
#pragma unroll
      for (int j = 0; j < 4; j++) bb[j] = Bs[kk][tx * 4 + j];
#pragma unroll
      for (int i = 0; i < 4; i++)
#pragma unroll
        for (int j = 0; j < 4; j++) acc[i][j] = fmaf(a[i], bb[j], acc[i][j]);
    }
    __syncthreads();
  }
  // epilogue: hid = acc + bias2 + tab_p[p] + tab_s[st]; out = relu(hid)@W2 + b2
  float part[4];
#pragma unroll
  for (int i = 0; i < 4; i++) {
    int r = ty * 4 + i;
    int p = pidx[r], st = stix[r];
    float s = 0.f;
#pragma unroll
    for (int jj = 0; jj < 4; jj++) {
      int cidx = tx * 4 + jj;
      float hv = acc[i][jj] + bias2[cidx] + tab_p[p * 64 + cidx] + tab_s[st * 64 + cidx];
      s = fmaf(fmaxf(hv, 0.f), W2[cidx], s);
    }
    part[i] = s;
  }
#pragma unroll
  for (int d = 1; d < 16; d <<= 1) {
#pragma unroll
    for (int i = 0; i < 4; i++) part[i] += __shfl_xor(part[i], d);
  }
  if (tx == 0) {
    float bb2 = b2[0];
#pragma unroll
    for (int i = 0; i < 4; i++) {
      int e = row0 + ty * 4 + i;
      if (e < E) out[e] = part[i] + bb2;
    }
  }
}

// ---------------- launch ----------------
extern "C" void kernel_launch(void* const* d_in, const int* in_sizes, int n_in,
                              void* d_out, int out_size, void* d_ws, size_t ws_size,
                              hipStream_t stream) {
  const int* src = (const int*)d_in[0];
  const int* dst = (const int*)d_in[1];
  const float* t = (const float*)d_in[2];
  const float* msg = (const float*)d_in[3];
  const float* price_seq = (const float*)d_in[4];
  const int* x_static = (const int*)d_in[6];
  const float* memory = (const float*)d_in[7];
  const float* last_update = (const float*)d_in[8];
  const float* time_w = (const float*)d_in[9];
  const float* time_b = (const float*)d_in[10];
  const float* gWih = (const float*)d_in[11];
  const float* gWhh = (const float*)d_in[12];
  const float* gbih = (const float*)d_in[13];
  const float* gbhh = (const float*)d_in[14];
  const float* party_emb = (const float*)d_in[15];
  const float* state_emb = (const float*)d_in[16];
  const float* static_W = (const float*)d_in[17];
  const float* static_b = (const float*)d_in[18];
  const float* lWih = (const float*)d_in[19];
  const float* lWhh = (const float*)d_in[20];
  const float* lbih = (const float*)d_in[21];
  const float* lbhh = (const float*)d_in[22];
  const float* price_W = (const float*)d_in[23];
  const float* price_b = (const float*)d_in[24];
  const float* W1 = (const float*)d_in[25];
  const float* b1 = (const float*)d_in[26];
  const float* W2 = (const float*)d_in[27];
  const float* b2 = (const float*)d_in[28];
  float* out = (float*)d_out;

  const int E = in_sizes[0];
  const int N = in_sizes[8];

  char* ws = (char*)d_ws;
  size_t off = 0;
  auto alloc = [&](size_t bytes) { size_t o = off; off += (bytes + 255) & ~(size_t)255; return o; };
  int* cnt     = (int*)(ws + alloc((size_t)N * 4));
  int* offs    = (int*)(ws + alloc((size_t)(N + 1) * 4));
  int* cursor  = (int*)(ws + alloc((size_t)N * 4));
  int* other   = (int*)(ws + alloc((size_t)2 * E * 4));
  int* eid     = (int*)(ws + alloc((size_t)2 * E * 4));
  float* Wcat  = (float*)(ws + alloc((size_t)KTOT * GOUT * 4));
  float* Wcomb = (float*)(ws + alloc((size_t)KP * 64 * 4));
  float* tab_p = (float*)(ws + alloc((size_t)4 * 64 * 4));
  float* tab_s = (float*)(ws + alloc((size_t)50 * 64 * 4));
  float* bias2 = (float*)(ws + alloc((size_t)64 * 4));
  float* agg   = (float*)(ws + alloc((size_t)N * KDIM * 4));
  float* gates = (float*)(ws + alloc((size_t)N * GOUT * 4));
  float* mem_new = (float*)(ws + alloc((size_t)N * H * 4));
  float* hout  = agg;  // alias: agg dead after gru_gemm; hout = E*32 floats
  (void)ws_size;

  hipMemsetAsync(cnt, 0, (size_t)N * 4, stream);

  build_weights<<<(KTOT * GOUT + 255) / 256, 256, 0, stream>>>(gWih, gWhh, Wcat);
  prep_pred<<<1, 256, 0, stream>>>(W1, b1, static_W, static_b, price_W, price_b,
                                   party_emb, state_emb, Wcomb, tab_p, tab_s, bias2);
  count_kernel<<<(E + 255) / 256, 256, 0, stream>>>(src, dst, cnt, E);
  scan_kernel<<<1, 1024, 0, stream>>>(cnt, offs, cursor, N);
  fill_kernel<<<(E + 255) / 256, 256, 0, stream>>>(src, dst, cursor, other, eid, E);
  agg_kernel<<<N, 256, 0, stream>>>(offs, other, eid, memory, msg, t, last_update,
                                    time_w, time_b, cnt, agg, N);
  dim3 g3((N + 63) / 64, GOUT / 64);
  gru_gemm<<<g3, 256, 0, stream>>>(agg, memory, Wcat, gates, N);
  gru_finalize<<<(N * H + 255) / 256, 256, 0, stream>>>(gates, memory, cnt, gbih, gbhh, mem_new, N);
  // lstm writes hout over agg -> must come after gru_gemm (stream-ordered)
  lstm_kernel<<<(E + 3) / 4, 256, 0, stream>>>(price_seq, lWih, lWhh, lbih, lbhh, hout, E);
  pred_gemm<<<(E + 63) / 64, 256, 0, stream>>>(src, dst, x_static, mem_new, hout,
      Wcomb, tab_p, tab_s, bias2, W2, b2, out, E);
}

// Round 4
// 1081.526 us; speedup vs baseline: 2.7642x; 1.4049x over previous
//
#include <hip/hip_runtime.h>

#define H 128
#define EF 32
#define TT 14
#define LH 32
#define KDIM 416   // 3H+EF
#define GOUT 512   // [r_pre, z_pre, i_n, h_n] each 128
#define KTOT 544   // 416 (agg) + 128 (memory)
#define KP 288     // pred GEMM K: 128 ms + 128 md + 32 h

typedef __attribute__((ext_vector_type(8))) short bf16x8;
typedef __attribute__((ext_vector_type(4))) float f32x4;

__device__ __forceinline__ float sigmoidf_(float x) { return 1.0f / (1.0f + __expf(-x)); }
__device__ __forceinline__ float tanhfast_(float x) { float e = __expf(2.0f * x); return 1.0f - 2.0f / (e + 1.0f); }

// ---------------- K1: build Wcat [544][512] ----------------
__global__ __launch_bounds__(256) void build_weights(
    const float* __restrict__ Wih, const float* __restrict__ Whh,
    float* __restrict__ Wcat) {
  int i = blockIdx.x * 256 + threadIdx.x;
  const int tot1 = KTOT * GOUT;
  if (i < tot1) {
    int k = i >> 9;        // / 512
    int o = i & 511;
    int j = o & 127;
    float v = 0.f;
    if (o < 256) {  // r (o<128) and z (o<256): gi+gh fused
      int row = (o < 128) ? j : (128 + j);
      v = (k < KDIM) ? Wih[row * KDIM + k] : Whh[row * H + (k - KDIM)];
    } else if (o < 384) {  // i_n
      v = (k < KDIM) ? Wih[(256 + j) * KDIM + k] : 0.f;
    } else {               // h_n
      v = (k < KDIM) ? 0.f : Whh[(256 + j) * H + (k - KDIM)];
    }
    Wcat[i] = v;
  }
}

// ---------------- K1b: predictor algebra collapse ----------------
__global__ __launch_bounds__(256) void prep_pred(
    const float* __restrict__ W1, const float* __restrict__ b1,
    const float* __restrict__ static_W, const float* __restrict__ static_b,
    const float* __restrict__ price_W, const float* __restrict__ price_b,
    const float* __restrict__ party_emb, const float* __restrict__ state_emb,
    float* __restrict__ Wcomb, float* __restrict__ tab_p, float* __restrict__ tab_s,
    float* __restrict__ bias2) {
  __shared__ float G1[64][32];
  int tid = threadIdx.x;
  for (int idx = tid; idx < 2048; idx += 256) {
    int o = idx >> 5, k = idx & 31;
    float g = 0.f, m = 0.f;
    for (int j = 0; j < 128; j++) {
      g = fmaf(W1[o * 384 + j], static_W[j * 32 + k], g);
      m = fmaf(W1[o * 384 + 128 + j] + W1[o * 384 + 256 + j], price_W[j * 32 + k], m);
    }
    G1[o][k] = g;
    Wcomb[(256 + k) * 64 + o] = m;
  }
  for (int idx = tid; idx < 256 * 64; idx += 256) {
    int j = idx >> 6, o = idx & 63;
    Wcomb[idx] = W1[o * 384 + j];
  }
  __syncthreads();
  for (int idx = tid; idx < 4 * 64; idx += 256) {
    int p = idx >> 6, o = idx & 63;
    float s = 0.f;
    for (int k = 0; k < 16; k++) s = fmaf(G1[o][k], party_emb[p * 16 + k], s);
    tab_p[idx] = s;
  }
  for (int idx = tid; idx < 50 * 64; idx += 256) {
    int si = idx >> 6, o = idx & 63;
    float s = 0.f;
    for (int k = 0; k < 16; k++) s = fmaf(G1[o][16 + k], state_emb[si * 16 + k], s);
    tab_s[idx] = s;
  }
  if (tid < 64) {
    float s = b1[tid];
    for (int j = 0; j < 128; j++) {
      s = fmaf(W1[tid * 384 + j], static_b[j], s);
      s = fmaf(W1[tid * 384 + 128 + j] + W1[tid * 384 + 256 + j], price_b[j], s);
    }
    bias2[tid] = s;
  }
}

// ---------------- K2a: degree count ----------------
__global__ void count_kernel(const int* __restrict__ src, const int* __restrict__ dst,
                             int* cnt, int E) {
  int e = blockIdx.x * blockDim.x + threadIdx.x;
  if (e < E) {
    atomicAdd(&cnt[dst[e]], 1);
    atomicAdd(&cnt[src[e]], 1);
  }
}

// ---------------- K2b: exclusive scan (single block) ----------------
__global__ __launch_bounds__(1024) void scan_kernel(const int* __restrict__ cnt,
                                                    int* __restrict__ offs,
                                                    int* __restrict__ cursor, int N) {
  __shared__ int part[1024];
  int tid = threadIdx.x;
  int chunk = (N + 1023) / 1024;
  int beg = tid * chunk;
  int end = min(beg + chunk, N);
  int s = 0;
  for (int i = beg; i < end; i++) s += cnt[i];
  part[tid] = s;
  __syncthreads();
  for (int d = 1; d < 1024; d <<= 1) {
    int v = (tid >= d) ? part[tid - d] : 0;
    __syncthreads();
    part[tid] += v;
    __syncthreads();
  }
  int run = (tid > 0) ? part[tid - 1] : 0;
  for (int i = beg; i < end; i++) {
    offs[i] = run;
    cursor[i] = run;
    run += cnt[i];
  }
  if (tid == 1023) offs[N] = part[1023];
}

// ---------------- K2c: CSR fill ----------------
__global__ void fill_kernel(const int* __restrict__ src, const int* __restrict__ dst,
                            int* cursor, int* __restrict__ other, int* __restrict__ eid, int E) {
  int e = blockIdx.x * blockDim.x + threadIdx.x;
  if (e >= E) return;
  int s = src[e], d = dst[e];
  int p1 = atomicAdd(&cursor[d], 1);
  other[p1] = s; eid[p1] = e;
  int p2 = atomicAdd(&cursor[s], 1);
  other[p2] = d; eid[p2] = e;
}

// ---------------- K2d: per-node aggregation -> agg [N][416] ----------------
__global__ __launch_bounds__(256) void agg_kernel(
    const int* __restrict__ offs, const int* __restrict__ other, const int* __restrict__ eid,
    const float* __restrict__ mem, const float* __restrict__ msg,
    const float* __restrict__ t, const float* __restrict__ lu,
    const float* __restrict__ tw, const float* __restrict__ tb,
    const int* __restrict__ cnt, float* __restrict__ agg, int N) {
  int v = blockIdx.x;
  int tid = threadIdx.x;
  int beg = offs[v], end = offs[v + 1];
  float lupd = lu[v];
  float w = 0.f, b = 0.f;
  if (tid >= 32 && tid < 160) { w = tw[tid - 32]; b = tb[tid - 32]; }
  float a0 = 0.f, a1 = 0.f;
  for (int p = beg; p < end; p++) {
    int u = other[p];
    int e = eid[p];
    if (tid < 128) a0 += mem[u * H + tid];
    if (tid < 32) a1 += msg[e * EF + tid];
    else if (tid < 160) a1 += cosf(fmaf(t[e] - lupd, w, b));
  }
  int cv = cnt[v];
  float inv = 1.f / (float)max(cv, 1);
  float* arow = agg + (size_t)v * KDIM;
  if (tid < 128) arow[tid] = a0 * inv;
  else arow[tid] = (cv > 0) ? mem[v * H + (tid - 128)] : 0.f;
  if (tid < 160) arow[256 + tid] = a1 * inv;
}

// ---------------- K3: GEMM gates[N][512] = A[N][544] @ Wcat[544][512] ----------------
__global__ __launch_bounds__(256) void gru_gemm(
    const float* __restrict__ agg, const float* __restrict__ mem,
    const float* __restrict__ Wcat, float* __restrict__ gates, int N) {
  __shared__ float As[64][33];
  __shared__ float Bs[32][65];
  int tid = threadIdx.x;
  int row0 = blockIdx.x * 64;
  int col0 = blockIdx.y * 64;
  int tx = tid & 15, ty = tid >> 4;
  float acc[4][4] = {};
  for (int k0 = 0; k0 < KTOT; k0 += 32) {
#pragma unroll
    for (int i = 0; i < 8; i++) {
      int idx = tid + i * 256;
      int r = idx >> 5, cc = idx & 31;
      int gr = row0 + r, gc = k0 + cc;
      float v = 0.f;
      if (gr < N) v = (gc < KDIM) ? agg[(size_t)gr * KDIM + gc] : mem[(size_t)gr * H + gc - KDIM];
      As[r][cc] = v;
    }
#pragma unroll
    for (int i = 0; i < 8; i++) {
      int idx = tid + i * 256;
      int r = idx >> 6, cc = idx & 63;
      Bs[r][cc] = Wcat[(size_t)(k0 + r) * GOUT + col0 + cc];
    }
    __syncthreads();
#pragma unroll
    for (int kk = 0; kk < 32; kk++) {
      float a[4], bb[4];
#pragma unroll
      for (int i = 0; i < 4; i++) a[i] = As[ty * 4 + i][kk];
#pragma unroll
      for (int j = 0; j < 4; j++) bb[j] = Bs[kk][tx * 4 + j];
#pragma unroll
      for (int i = 0; i < 4; i++)
#pragma unroll
        for (int j = 0; j < 4; j++) acc[i][j] = fmaf(a[i], bb[j], acc[i][j]);
    }
    __syncthreads();
  }
#pragma unroll
  for (int i = 0; i < 4; i++) {
    int gr = row0 + ty * 4 + i;
    if (gr < N) {
#pragma unroll
      for (int j = 0; j < 4; j++) gates[(size_t)gr * GOUT + col0 + tx * 4 + j] = acc[i][j];
    }
  }
}

// ---------------- K4: GRU nonlinearity -> mem_new [N][128] ----------------
__global__ __launch_bounds__(256) void gru_finalize(
    const float* __restrict__ gates, const float* __restrict__ mem, const int* __restrict__ cnt,
    const float* __restrict__ bih, const float* __restrict__ bhh,
    float* __restrict__ mem_new, int N) {
  int i = blockIdx.x * 256 + threadIdx.x;
  if (i >= N * H) return;
  int n = i >> 7, j = i & 127;
  float m = mem[i];
  float o;
  if (cnt[n] > 0) {
    const float* g = gates + (size_t)n * GOUT;
    float r = sigmoidf_(g[j] + bih[j] + bhh[j]);
    float z = sigmoidf_(g[128 + j] + bih[128 + j] + bhh[128 + j]);
    float nn = tanhfast_(g[256 + j] + bih[256 + j] + r * (g[384 + j] + bhh[256 + j]));
    o = (1.f - z) * nn + z * m;
  } else {
    o = m;
  }
  mem_new[i] = o;
}

// ---------------- K5a: price LSTM, MFMA-batched, 16 edges per wave ----------------
// Per step: G^T[128 gates][16 edges] = Whh[128,32]@H^T[32,16] via 8x mfma 16x16x32 bf16.
// C-init = bias + x_t * Wih (rank-1 input folded into accumulator).
// Lane l: edge el=l&15, group g=l>>4. C rows for mfma b: 16b + 4g + reg.
// Hidden unit m: i=row m, f=32+m, g=64+m, o=96+m -> blocks b1,2+b1,4+b1,6+b1 share (lane,reg):
// lane-local nonlinearity for m in {4g+r, 16+4g+r}.
// Next-step B frag (k=g*8+0..7 of edge el) built with 8 ds_bpermute + 4 selects.
__global__ __launch_bounds__(256) void lstm_mfma_kernel(
    const float* __restrict__ price_seq,
    const float* __restrict__ lWih, const float* __restrict__ lWhh,
    const float* __restrict__ lbih, const float* __restrict__ lbhh,
    float* __restrict__ hout, int E) {
  int lane = threadIdx.x & 63;
  int el = lane & 15;
  int g = lane >> 4;
  int wave = blockIdx.x * 4 + (threadIdx.x >> 6);
  int e = wave * 16 + el;
  bool valid = (e < E);
  int eload = valid ? e : (E - 1);

  // A fragments: Whh rows in bf16. mfma b: row = 16b+el, k = g*8..g*8+7
  union { uint u[4]; bf16x8 v; } afr[8];
#pragma unroll
  for (int b = 0; b < 8; b++) {
    const float* wr = lWhh + (16 * b + el) * LH + g * 8;
#pragma unroll
    for (int q = 0; q < 4; q++) {
      float lo = wr[2 * q], hi = wr[2 * q + 1];
      asm("v_cvt_pk_bf16_f32 %0, %1, %2" : "=v"(afr[b].u[q]) : "v"(lo), "v"(hi));
    }
  }

  // per-lane Wih / fused bias for its 32 gate rows: row(b,r) = 16b + 4g + r
  float wih_r[32], bias_r[32];
#pragma unroll
  for (int b = 0; b < 8; b++)
#pragma unroll
    for (int r = 0; r < 4; r++) {
      int row = 16 * b + 4 * g + r;
      wih_r[4 * b + r] = lWih[row];
      bias_r[4 * b + r] = lbih[row] + lbhh[row];
    }

  // price inputs for this lane's edge
  float xv[TT];
#pragma unroll
  for (int t = 0; t < TT; t++) xv[t] = price_seq[(size_t)eload * TT + t];

  // bpermute setup: B dword i pulls from lane el + 16*((g&1)*2 + (i>>1)),
  // value = hpk[(i&1) + 2*(g>>1)]
  int addr_i[4];
#pragma unroll
  for (int i = 0; i < 4; i++) addr_i[i] = (el + 16 * ((g & 1) * 2 + (i >> 1))) << 2;
  bool hi_sel = (g >> 1) != 0;

  float cst[8], hval[8];
#pragma unroll
  for (int i = 0; i < 8; i++) { cst[i] = 0.f; hval[i] = 0.f; }
  uint hpk[4] = {0u, 0u, 0u, 0u};

#pragma unroll
  for (int t = 0; t < TT; t++) {
    // assemble B fragment from packed h (zeros at t=0)
    union { uint u[4]; bf16x8 v; } bfr;
#pragma unroll
    for (int i = 0; i < 4; i++) {
      uint lo = (uint)__builtin_amdgcn_ds_bpermute(addr_i[i], (int)hpk[i & 1]);
      uint hi = (uint)__builtin_amdgcn_ds_bpermute(addr_i[i], (int)hpk[2 + (i & 1)]);
      bfr.u[i] = hi_sel ? hi : lo;
    }
    float x = xv[t];
    f32x4 acc0, acc1, acc2, acc3, acc4, acc5, acc6, acc7;
#define INITACC(b, A) \
    { A[0] = fmaf(x, wih_r[4*b+0], bias_r[4*b+0]); A[1] = fmaf(x, wih_r[4*b+1], bias_r[4*b+1]); \
      A[2] = fmaf(x, wih_r[4*b+2], bias_r[4*b+2]); A[3] = fmaf(x, wih_r[4*b+3], bias_r[4*b+3]); \
      A = __builtin_amdgcn_mfma_f32_16x16x32_bf16(afr[b].v, bfr.v, A, 0, 0, 0); }
    INITACC(0, acc0) INITACC(1, acc1) INITACC(2, acc2) INITACC(3, acc3)
    INITACC(4, acc4) INITACC(5, acc5) INITACC(6, acc6) INITACC(7, acc7)
#undef INITACC
    // nonlinearity: m-local gates: i=acc[b1], f=acc[2+b1], g=acc[4+b1], o=acc[6+b1]
#define NONLIN(b1, AI, AF, AG, AO) \
    { _Pragma("unroll") for (int r = 0; r < 4; r++) { \
        int mi = 4 * b1 + r; \
        float ig = sigmoidf_(AI[r]); \
        float fg = sigmoidf_(AF[r]); \
        float gg = tanhfast_(AG[r]); \
        float og = sigmoidf_(AO[r]); \
        float cv = fmaf(fg, cst[mi], ig * gg); \
        cst[mi] = cv; \
        hval[mi] = og * tanhfast_(cv); } }
    NONLIN(0, acc0, acc2, acc4, acc6)
    NONLIN(1, acc1, acc3, acc5, acc7)
#undef NONLIN
    // pack h -> bf16 pairs: d0=(h0,h1), d1=(h2,h3), d2=(h4,h5), d3=(h6,h7)
#pragma unroll
    for (int i = 0; i < 4; i++)
      asm("v_cvt_pk_bf16_f32 %0, %1, %2" : "=v"(hpk[i]) : "v"(hval[2 * i]), "v"(hval[2 * i + 1]));
  }

  if (valid) {
    float* hp = hout + (size_t)e * LH;
#pragma unroll
    for (int b1 = 0; b1 < 2; b1++)
#pragma unroll
      for (int r2 = 0; r2 < 4; r2 += 2) {
        int m = 16 * b1 + 4 * g + r2;
        float2 v2 = make_float2(hval[4 * b1 + r2], hval[4 * b1 + r2 + 1]);
        *reinterpret_cast<float2*>(hp + m) = v2;
      }
  }
}

// ---------------- K5b: pred GEMM out[E] from X[E][288] @ Wcomb[288][64] ----------------
__global__ __launch_bounds__(256) void pred_gemm(
    const int* __restrict__ src, const int* __restrict__ dst,
    const int* __restrict__ x_static,
    const float* __restrict__ mem_new, const float* __restrict__ hout,
    const float* __restrict__ Wcomb, const float* __restrict__ tab_p,
    const float* __restrict__ tab_s, const float* __restrict__ bias2,
    const float* __restrict__ W2, const float* __restrict__ b2,
    float* __restrict__ out, int E) {
  __shared__ float As[64][33];
  __shared__ float Bs[32][65];
  __shared__ int sidx[64], didx[64], pidx[64], stix[64];
  int tid = threadIdx.x;
  int row0 = blockIdx.x * 64;
  if (tid < 64) {
    int e = row0 + tid;
    int s = (e < E) ? src[e] : 0;
    int d = (e < E) ? dst[e] : 0;
    sidx[tid] = s; didx[tid] = d;
    pidx[tid] = x_static[s * 2]; stix[tid] = x_static[s * 2 + 1];
  }
  __syncthreads();
  int tx = tid & 15, ty = tid >> 4;
  float acc[4][4] = {};
  for (int k0 = 0; k0 < KP; k0 += 32) {
#pragma unroll
    for (int i = 0; i < 8; i++) {
      int idx = tid + i * 256;
      int r = idx >> 5, cc = idx & 31;
      int e = row0 + r;
      int k = k0 + cc;
      float v = 0.f;
      if (e < E) {
        if (k < 128) v = mem_new[(size_t)sidx[r] * H + k];
        else if (k < 256) v = mem_new[(size_t)didx[r] * H + (k - 128)];
        else v = hout[(size_t)e * LH + (k - 256)];
      }
      As[r][cc] = v;
    }
#pragma unroll
    for (int i = 0; i < 8; i++) {
      int idx = tid + i * 256;
      int r = idx >> 6, cc = idx & 63;
      Bs[r][cc] = Wcomb[(k0 + r) * 64 + cc];
    }
    __syncthreads();
#pragma unroll
    for (int kk = 0; kk < 32; kk++) {
      float a[4], bb[4];
#pragma unroll
      for (int i = 0; i < 4; i++) a[i] = As[ty * 4 + i][kk];
#pragma unroll
      for (int j = 0; j < 4; j++) bb[j] = Bs[kk][tx * 4 + j];
#pragma unroll
      for (int i = 0; i < 4; i++)
#pragma unroll
        for (int j = 0; j < 4; j++) acc[i][j] = fmaf(a[i], bb[j], acc[i][j]);
    }
    __syncthreads();
  }
  float part[4];
#pragma unroll
  for (int i = 0; i < 4; i++) {
    int r = ty * 4 + i;
    int p = pidx[r], st = stix[r];
    float s = 0.f;
#pragma unroll
    for (int jj = 0; jj < 4; jj++) {
      int cidx = tx * 4 + jj;
      float hv = acc[i][jj] + bias2[cidx] + tab_p[p * 64 + cidx] + tab_s[st * 64 + cidx];
      s = fmaf(fmaxf(hv, 0.f), W2[cidx], s);
    }
    part[i] = s;
  }
#pragma unroll
  for (int d = 1; d < 16; d <<= 1) {
#pragma unroll
    for (int i = 0; i < 4; i++) part[i] += __shfl_xor(part[i], d);
  }
  if (tx == 0) {
    float bb2 = b2[0];
#pragma unroll
    for (int i = 0; i < 4; i++) {
      int e = row0 + ty * 4 + i;
      if (e < E) out[e] = part[i] + bb2;
    }
  }
}

// ---------------- launch ----------------
extern "C" void kernel_launch(void* const* d_in, const int* in_sizes, int n_in,
                              void* d_out, int out_size, void* d_ws, size_t ws_size,
                              hipStream_t stream) {
  const int* src = (const int*)d_in[0];
  const int* dst = (const int*)d_in[1];
  const float* t = (const float*)d_in[2];
  const float* msg = (const float*)d_in[3];
  const float* price_seq = (const float*)d_in[4];
  const int* x_static = (const int*)d_in[6];
  const float* memory = (const float*)d_in[7];
  const float* last_update = (const float*)d_in[8];
  const float* time_w = (const float*)d_in[9];
  const float* time_b = (const float*)d_in[10];
  const float* gWih = (const float*)d_in[11];
  const float* gWhh = (const float*)d_in[12];
  const float* gbih = (const float*)d_in[13];
  const float* gbhh = (const float*)d_in[14];
  const float* party_emb = (const float*)d_in[15];
  const float* state_emb = (const float*)d_in[16];
  const float* static_W = (const float*)d_in[17];
  const float* static_b = (const float*)d_in[18];
  const float* lWih = (const float*)d_in[19];
  const float* lWhh = (const float*)d_in[20];
  const float* lbih = (const float*)d_in[21];
  const float* lbhh = (const float*)d_in[22];
  const float* price_W = (const float*)d_in[23];
  const float* price_b = (const float*)d_in[24];
  const float* W1 = (const float*)d_in[25];
  const float* b1 = (const float*)d_in[26];
  const float* W2 = (const float*)d_in[27];
  const float* b2 = (const float*)d_in[28];
  float* out = (float*)d_out;

  const int E = in_sizes[0];
  const int N = in_sizes[8];

  char* ws = (char*)d_ws;
  size_t off = 0;
  auto alloc = [&](size_t bytes) { size_t o = off; off += (bytes + 255) & ~(size_t)255; return o; };
  int* cnt     = (int*)(ws + alloc((size_t)N * 4));
  int* offs    = (int*)(ws + alloc((size_t)(N + 1) * 4));
  int* cursor  = (int*)(ws + alloc((size_t)N * 4));
  int* other   = (int*)(ws + alloc((size_t)2 * E * 4));
  int* eid     = (int*)(ws + alloc((size_t)2 * E * 4));
  float* Wcat  = (float*)(ws + alloc((size_t)KTOT * GOUT * 4));
  float* Wcomb = (float*)(ws + alloc((size_t)KP * 64 * 4));
  float* tab_p = (float*)(ws + alloc((size_t)4 * 64 * 4));
  float* tab_s = (float*)(ws + alloc((size_t)50 * 64 * 4));
  float* bias2 = (float*)(ws + alloc((size_t)64 * 4));
  float* agg   = (float*)(ws + alloc((size_t)N * KDIM * 4));
  float* gates = (float*)(ws + alloc((size_t)N * GOUT * 4));
  float* mem_new = (float*)(ws + alloc((size_t)N * H * 4));
  float* hout  = agg;  // alias: agg dead after gru_gemm; hout = E*32 floats
  (void)ws_size;

  hipMemsetAsync(cnt, 0, (size_t)N * 4, stream);

  build_weights<<<(KTOT * GOUT + 255) / 256, 256, 0, stream>>>(gWih, gWhh, Wcat);
  prep_pred<<<1, 256, 0, stream>>>(W1, b1, static_W, static_b, price_W, price_b,
                                   party_emb, state_emb, Wcomb, tab_p, tab_s, bias2);
  count_kernel<<<(E + 255) / 256, 256, 0, stream>>>(src, dst, cnt, E);
  scan_kernel<<<1, 1024, 0, stream>>>(cnt, offs, cursor, N);
  fill_kernel<<<(E + 255) / 256, 256, 0, stream>>>(src, dst, cursor, other, eid, E);
  agg_kernel<<<N, 256, 0, stream>>>(offs, other, eid, memory, msg, t, last_update,
                                    time_w, time_b, cnt, agg, N);
  dim3 g3((N + 63) / 64, GOUT / 64);
  gru_gemm<<<g3, 256, 0, stream>>>(agg, memory, Wcat, gates, N);
  gru_finalize<<<(N * H + 255) / 256, 256, 0, stream>>>(gates, memory, cnt, gbih, gbhh, mem_new, N);
  // lstm writes hout over agg -> must come after gru_gemm (stream-ordered)
  int nwaves = (E + 15) / 16;
  lstm_mfma_kernel<<<(nwaves + 3) / 4, 256, 0, stream>>>(price_seq, lWih, lWhh, lbih, lbhh, hout, E);
  pred_gemm<<<(E + 63) / 64, 256, 0, stream>>>(src, dst, x_static, mem_new, hout,
      Wcomb, tab_p, tab_s, bias2, W2, b2, out, E);
}

// Round 5
// 837.287 us; speedup vs baseline: 3.5705x; 1.2917x over previous
//
#include <hip/hip_runtime.h>

#define H 128
#define EF 32
#define TT 14
#define LH 32
#define KDIM 416   // 3H+EF
#define GOUT 512   // [r_pre, z_pre, i_n, h_n] each 128
#define KTOT 544   // 416 (agg) + 128 (memory)
#define KP 288     // pred GEMM K: 128 ms + 128 md + 32 h

typedef __attribute__((ext_vector_type(8))) short bf16x8;
typedef __attribute__((ext_vector_type(4))) float f32x4;

__device__ __forceinline__ float sigmoidf_(float x) { return 1.0f / (1.0f + __expf(-x)); }
__device__ __forceinline__ float tanhfast_(float x) { float e = __expf(2.0f * x); return 1.0f - 2.0f / (e + 1.0f); }
__device__ __forceinline__ ushort f2bf(float x) {
  uint u = __float_as_uint(x);
  u += 0x7fff + ((u >> 16) & 1);   // RTNE
  return (ushort)(u >> 16);
}

// ---------------- K1: build WcatT bf16 [512][544] (o-major) ----------------
__global__ __launch_bounds__(256) void build_weights(
    const float* __restrict__ Wih, const float* __restrict__ Whh,
    ushort* __restrict__ WcatT) {
  int i = blockIdx.x * 256 + threadIdx.x;
  if (i >= GOUT * KTOT) return;
  int o = i / KTOT, k = i % KTOT;
  int j = o & 127;
  float v = 0.f;
  if (o < 256) {  // r (o<128) and z (o<256): gi+gh fused
    int row = (o < 128) ? j : (128 + j);
    v = (k < KDIM) ? Wih[row * KDIM + k] : Whh[row * H + (k - KDIM)];
  } else if (o < 384) {  // i_n
    v = (k < KDIM) ? Wih[(256 + j) * KDIM + k] : 0.f;
  } else {               // h_n
    v = (k < KDIM) ? 0.f : Whh[(256 + j) * H + (k - KDIM)];
  }
  WcatT[i] = f2bf(v);
}

// ---------------- K1b: predictor algebra collapse ----------------
__global__ __launch_bounds__(256) void prep_pred(
    const float* __restrict__ W1, const float* __restrict__ b1,
    const float* __restrict__ static_W, const float* __restrict__ static_b,
    const float* __restrict__ price_W, const float* __restrict__ price_b,
    const float* __restrict__ party_emb, const float* __restrict__ state_emb,
    float* __restrict__ Wcomb, float* __restrict__ tab_p, float* __restrict__ tab_s,
    float* __restrict__ bias2) {
  __shared__ float G1[64][32];
  int tid = threadIdx.x;
  for (int idx = tid; idx < 2048; idx += 256) {
    int o = idx >> 5, k = idx & 31;
    float g = 0.f, m = 0.f;
    for (int j = 0; j < 128; j++) {
      g = fmaf(W1[o * 384 + j], static_W[j * 32 + k], g);
      m = fmaf(W1[o * 384 + 128 + j] + W1[o * 384 + 256 + j], price_W[j * 32 + k], m);
    }
    G1[o][k] = g;
    Wcomb[(256 + k) * 64 + o] = m;
  }
  for (int idx = tid; idx < 256 * 64; idx += 256) {
    int j = idx >> 6, o = idx & 63;
    Wcomb[idx] = W1[o * 384 + j];
  }
  __syncthreads();
  for (int idx = tid; idx < 4 * 64; idx += 256) {
    int p = idx >> 6, o = idx & 63;
    float s = 0.f;
    for (int k = 0; k < 16; k++) s = fmaf(G1[o][k], party_emb[p * 16 + k], s);
    tab_p[idx] = s;
  }
  for (int idx = tid; idx < 50 * 64; idx += 256) {
    int si = idx >> 6, o = idx & 63;
    float s = 0.f;
    for (int k = 0; k < 16; k++) s = fmaf(G1[o][16 + k], state_emb[si * 16 + k], s);
    tab_s[idx] = s;
  }
  if (tid < 64) {
    float s = b1[tid];
    for (int j = 0; j < 128; j++) {
      s = fmaf(W1[tid * 384 + j], static_b[j], s);
      s = fmaf(W1[tid * 384 + 128 + j] + W1[tid * 384 + 256 + j], price_b[j], s);
    }
    bias2[tid] = s;
  }
}

// ---------------- K2a: degree count ----------------
__global__ void count_kernel(const int* __restrict__ src, const int* __restrict__ dst,
                             int* cnt, int E) {
  int e = blockIdx.x * blockDim.x + threadIdx.x;
  if (e < E) {
    atomicAdd(&cnt[dst[e]], 1);
    atomicAdd(&cnt[src[e]], 1);
  }
}

// ---------------- K2b: exclusive scan (single block) ----------------
__global__ __launch_bounds__(1024) void scan_kernel(const int* __restrict__ cnt,
                                                    int* __restrict__ offs,
                                                    int* __restrict__ cursor, int N) {
  __shared__ int part[1024];
  int tid = threadIdx.x;
  int chunk = (N + 1023) / 1024;
  int beg = tid * chunk;
  int end = min(beg + chunk, N);
  int s = 0;
  for (int i = beg; i < end; i++) s += cnt[i];
  part[tid] = s;
  __syncthreads();
  for (int d = 1; d < 1024; d <<= 1) {
    int v = (tid >= d) ? part[tid - d] : 0;
    __syncthreads();
    part[tid] += v;
    __syncthreads();
  }
  int run = (tid > 0) ? part[tid - 1] : 0;
  for (int i = beg; i < end; i++) {
    offs[i] = run;
    cursor[i] = run;
    run += cnt[i];
  }
  if (tid == 1023) offs[N] = part[1023];
}

// ---------------- K2c: CSR fill ----------------
__global__ void fill_kernel(const int* __restrict__ src, const int* __restrict__ dst,
                            int* cursor, int* __restrict__ other, int* __restrict__ eid, int E) {
  int e = blockIdx.x * blockDim.x + threadIdx.x;
  if (e >= E) return;
  int s = src[e], d = dst[e];
  int p1 = atomicAdd(&cursor[d], 1);
  other[p1] = s; eid[p1] = e;
  int p2 = atomicAdd(&cursor[s], 1);
  other[p2] = d; eid[p2] = e;
}

// ---------------- K2d: per-node aggregation -> agg_b bf16 [N][544] ----------------
// cols [0:416) = GRU agg input; cols [416:544) = mem[v] (the Whh operand)
__global__ __launch_bounds__(256) void agg_kernel(
    const int* __restrict__ offs, const int* __restrict__ other, const int* __restrict__ eid,
    const float* __restrict__ mem, const float* __restrict__ msg,
    const float* __restrict__ t, const float* __restrict__ lu,
    const float* __restrict__ tw, const float* __restrict__ tb,
    const int* __restrict__ cnt, ushort* __restrict__ agg_b, int N) {
  int v = blockIdx.x;
  int tid = threadIdx.x;
  int beg = offs[v], end = offs[v + 1];
  float lupd = lu[v];
  float w = 0.f, b = 0.f;
  if (tid >= 32 && tid < 160) { w = tw[tid - 32]; b = tb[tid - 32]; }
  float a0 = 0.f, a1 = 0.f;
  for (int p = beg; p < end; p++) {
    int u = other[p];
    int e = eid[p];
    if (tid < 128) a0 += mem[u * H + tid];
    if (tid < 32) a1 += msg[e * EF + tid];
    else if (tid < 160) a1 += cosf(fmaf(t[e] - lupd, w, b));
  }
  int cv = cnt[v];
  float inv = 1.f / (float)max(cv, 1);
  ushort* arow = agg_b + (size_t)v * KTOT;
  if (tid < 128) {
    arow[tid] = f2bf(a0 * inv);
  } else {
    float mv = mem[v * H + (tid - 128)];
    arow[tid] = f2bf((cv > 0) ? mv : 0.f);  // mean of cv copies of mem[v]
    arow[288 + tid] = f2bf(mv);             // cols 416..543: Whh operand
  }
  if (tid < 160) arow[256 + tid] = f2bf(a1 * inv);
}

// ---------------- K3: MFMA GEMM + fused GRU finalize -> mem_new [N][128] ----------------
// Per block: 32 rows x full 512 gate cols. Wave w owns cols [w*128,(w+1)*128) = gate group w.
// A bf16 staged in LDS (stride 552); B read from L2-resident WcatT.
__global__ __launch_bounds__(256) void gru_gemm_mfma(
    const ushort* __restrict__ aggb, const ushort* __restrict__ WcatT,
    const float* __restrict__ mem, const int* __restrict__ cnt,
    const float* __restrict__ bih, const float* __restrict__ bhh,
    float* __restrict__ mem_new, int N) {
  __shared__ union {
    ushort a[32 * 552];       // 35.3 KB
    float g[4][32][132];      // 67.6 KB
  } sm;
  int tid = threadIdx.x;
  int lane = tid & 63;
  int w = tid >> 6;
  int n0 = blockIdx.x * 32;

  // stage A tile: 32 rows x 544 bf16 (68 x 16B chunks per row)
#pragma unroll
  for (int i = 0; i < 8; i++) {
    int row = w * 8 + i;
    int gr = min(n0 + row, N - 1);
    const uint4* srcp = reinterpret_cast<const uint4*>(aggb + (size_t)gr * KTOT);
    uint4* dstp = reinterpret_cast<uint4*>(sm.a + row * 552);
    dstp[lane] = srcp[lane];
    if (lane < 4) dstp[64 + lane] = srcp[64 + lane];
  }
  __syncthreads();

  f32x4 acc[2][8] = {};
  int arow_b = (lane & 15);
  int koff = (lane >> 4) * 8;
  for (int ks = 0; ks < 17; ks++) {
    int k = ks * 32 + koff;
    bf16x8 afr0 = *reinterpret_cast<const bf16x8*>(sm.a + (arow_b) * 552 + k);
    bf16x8 afr1 = *reinterpret_cast<const bf16x8*>(sm.a + (16 + arow_b) * 552 + k);
#pragma unroll
    for (int nt = 0; nt < 8; nt++) {
      int o = w * 128 + nt * 16 + (lane & 15);
      bf16x8 bfr = *reinterpret_cast<const bf16x8*>(WcatT + (size_t)o * KTOT + k);
      acc[0][nt] = __builtin_amdgcn_mfma_f32_16x16x32_bf16(afr0, bfr, acc[0][nt], 0, 0, 0);
      acc[1][nt] = __builtin_amdgcn_mfma_f32_16x16x32_bf16(afr1, bfr, acc[1][nt], 0, 0, 0);
    }
  }
  __syncthreads();  // A reads done; reuse LDS

  // scatter C to LDS: element (row_local=(l>>4)*4+r, col=l&15)
#pragma unroll
  for (int mt = 0; mt < 2; mt++)
#pragma unroll
    for (int nt = 0; nt < 8; nt++)
#pragma unroll
      for (int r = 0; r < 4; r++)
        sm.g[w][mt * 16 + (lane >> 4) * 4 + r][nt * 16 + (lane & 15)] = acc[mt][nt][r];
  __syncthreads();

  // fused GRU finalize: thread t -> row t>>3, j-range (t&7)*16..+15
  int row = tid >> 3, j0 = (tid & 7) * 16;
  int n = n0 + row;
  if (n < N) {
    int cv = cnt[n];
#pragma unroll
    for (int jj = 0; jj < 16; jj++) {
      int j = j0 + jj;
      float m = mem[(size_t)n * H + j];
      float o;
      if (cv > 0) {
        float rp = sm.g[0][row][j] + bih[j] + bhh[j];
        float zp = sm.g[1][row][j] + bih[128 + j] + bhh[128 + j];
        float ip = sm.g[2][row][j] + bih[256 + j];
        float hp = sm.g[3][row][j] + bhh[256 + j];
        float r = sigmoidf_(rp), z = sigmoidf_(zp);
        float nn = tanhfast_(ip + r * hp);
        o = (1.f - z) * nn + z * m;
      } else {
        o = m;
      }
      mem_new[(size_t)n * H + j] = o;
    }
  }
}

// ---------------- K5a: price LSTM, MFMA-batched, 16 edges per wave ----------------
__global__ __launch_bounds__(256) void lstm_mfma_kernel(
    const float* __restrict__ price_seq,
    const float* __restrict__ lWih, const float* __restrict__ lWhh,
    const float* __restrict__ lbih, const float* __restrict__ lbhh,
    float* __restrict__ hout, int E) {
  int lane = threadIdx.x & 63;
  int el = lane & 15;
  int g = lane >> 4;
  int wave = blockIdx.x * 4 + (threadIdx.x >> 6);
  int e = wave * 16 + el;
  bool valid = (e < E);
  int eload = valid ? e : (E - 1);

  union { uint u[4]; bf16x8 v; } afr[8];
#pragma unroll
  for (int b = 0; b < 8; b++) {
    const float* wr = lWhh + (16 * b + el) * LH + g * 8;
#pragma unroll
    for (int q = 0; q < 4; q++) {
      float lo = wr[2 * q], hi = wr[2 * q + 1];
      asm("v_cvt_pk_bf16_f32 %0, %1, %2" : "=v"(afr[b].u[q]) : "v"(lo), "v"(hi));
    }
  }

  float wih_r[32], bias_r[32];
#pragma unroll
  for (int b = 0; b < 8; b++)
#pragma unroll
    for (int r = 0; r < 4; r++) {
      int row = 16 * b + 4 * g + r;
      wih_r[4 * b + r] = lWih[row];
      bias_r[4 * b + r] = lbih[row] + lbhh[row];
    }

  float xv[TT];
#pragma unroll
  for (int t = 0; t < TT; t++) xv[t] = price_seq[(size_t)eload * TT + t];

  int addr_i[4];
#pragma unroll
  for (int i = 0; i < 4; i++) addr_i[i] = (el + 16 * ((g & 1) * 2 + (i >> 1))) << 2;
  bool hi_sel = (g >> 1) != 0;

  float cst[8], hval[8];
#pragma unroll
  for (int i = 0; i < 8; i++) { cst[i] = 0.f; hval[i] = 0.f; }
  uint hpk[4] = {0u, 0u, 0u, 0u};

#pragma unroll
  for (int t = 0; t < TT; t++) {
    union { uint u[4]; bf16x8 v; } bfr;
#pragma unroll
    for (int i = 0; i < 4; i++) {
      uint lo = (uint)__builtin_amdgcn_ds_bpermute(addr_i[i], (int)hpk[i & 1]);
      uint hi = (uint)__builtin_amdgcn_ds_bpermute(addr_i[i], (int)hpk[2 + (i & 1)]);
      bfr.u[i] = hi_sel ? hi : lo;
    }
    float x = xv[t];
    f32x4 acc0, acc1, acc2, acc3, acc4, acc5, acc6, acc7;
#define INITACC(b, A) \
    { A[0] = fmaf(x, wih_r[4*b+0], bias_r[4*b+0]); A[1] = fmaf(x, wih_r[4*b+1], bias_r[4*b+1]); \
      A[2] = fmaf(x, wih_r[4*b+2], bias_r[4*b+2]); A[3] = fmaf(x, wih_r[4*b+3], bias_r[4*b+3]); \
      A = __builtin_amdgcn_mfma_f32_16x16x32_bf16(afr[b].v, bfr.v, A, 0, 0, 0); }
    INITACC(0, acc0) INITACC(1, acc1) INITACC(2, acc2) INITACC(3, acc3)
    INITACC(4, acc4) INITACC(5, acc5) INITACC(6, acc6) INITACC(7, acc7)
#undef INITACC
#define NONLIN(b1, AI, AF, AG, AO) \
    { _Pragma("unroll") for (int r = 0; r < 4; r++) { \
        int mi = 4 * b1 + r; \
        float ig = sigmoidf_(AI[r]); \
        float fg = sigmoidf_(AF[r]); \
        float gg = tanhfast_(AG[r]); \
        float og = sigmoidf_(AO[r]); \
        float cv = fmaf(fg, cst[mi], ig * gg); \
        cst[mi] = cv; \
        hval[mi] = og * tanhfast_(cv); } }
    NONLIN(0, acc0, acc2, acc4, acc6)
    NONLIN(1, acc1, acc3, acc5, acc7)
#undef NONLIN
#pragma unroll
    for (int i = 0; i < 4; i++)
      asm("v_cvt_pk_bf16_f32 %0, %1, %2" : "=v"(hpk[i]) : "v"(hval[2 * i]), "v"(hval[2 * i + 1]));
  }

  if (valid) {
    float* hp = hout + (size_t)e * LH;
#pragma unroll
    for (int b1 = 0; b1 < 2; b1++)
#pragma unroll
      for (int r2 = 0; r2 < 4; r2 += 2) {
        int m = 16 * b1 + 4 * g + r2;
        float2 v2 = make_float2(hval[4 * b1 + r2], hval[4 * b1 + r2 + 1]);
        *reinterpret_cast<float2*>(hp + m) = v2;
      }
  }
}

// ---------------- K5b: pred GEMM out[E] from X[E][288] @ Wcomb[288][64] ----------------
__global__ __launch_bounds__(256) void pred_gemm(
    const int* __restrict__ src, const int* __restrict__ dst,
    const int* __restrict__ x_static,
    const float* __restrict__ mem_new, const float* __restrict__ hout,
    const float* __restrict__ Wcomb, const float* __restrict__ tab_p,
    const float* __restrict__ tab_s, const float* __restrict__ bias2,
    const float* __restrict__ W2, const float* __restrict__ b2,
    float* __restrict__ out, int E) {
  __shared__ float As[64][33];
  __shared__ float Bs[32][65];
  __shared__ int sidx[64], didx[64], pidx[64], stix[64];
  int tid = threadIdx.x;
  int row0 = blockIdx.x * 64;
  if (tid < 64) {
    int e = row0 + tid;
    int s = (e < E) ? src[e] : 0;
    int d = (e < E) ? dst[e] : 0;
    sidx[tid] = s; didx[tid] = d;
    pidx[tid] = x_static[s * 2]; stix[tid] = x_static[s * 2 + 1];
  }
  __syncthreads();
  int tx = tid & 15, ty = tid >> 4;
  float acc[4][4] = {};
  for (int k0 = 0; k0 < KP; k0 += 32) {
#pragma unroll
    for (int i = 0; i < 8; i++) {
      int idx = tid + i * 256;
      int r = idx >> 5, cc = idx & 31;
      int e = row0 + r;
      int k = k0 + cc;
      float v = 0.f;
      if (e < E) {
        if (k < 128) v = mem_new[(size_t)sidx[r] * H + k];
        else if (k < 256) v = mem_new[(size_t)didx[r] * H + (k - 128)];
        else v = hout[(size_t)e * LH + (k - 256)];
      }
      As[r][cc] = v;
    }
#pragma unroll
    for (int i = 0; i < 8; i++) {
      int idx = tid + i * 256;
      int r = idx >> 6, cc = idx & 63;
      Bs[r][cc] = Wcomb[(k0 + r) * 64 + cc];
    }
    __syncthreads();
#pragma unroll
    for (int kk = 0; kk < 32; kk++) {
      float a[4], bb[4];
#pragma unroll
      for (int i = 0; i < 4; i++) a[i] = As[ty * 4 + i][kk];
#pragma unroll
      for (int j = 0; j < 4; j++) bb[j] = Bs[kk][tx * 4 + j];
#pragma unroll
      for (int i = 0; i < 4; i++)
#pragma unroll
        for (int j = 0; j < 4; j++) acc[i][j] = fmaf(a[i], bb[j], acc[i][j]);
    }
    __syncthreads();
  }
  float part[4];
#pragma unroll
  for (int i = 0; i < 4; i++) {
    int r = ty * 4 + i;
    int p = pidx[r], st = stix[r];
    float s = 0.f;
#pragma unroll
    for (int jj = 0; jj < 4; jj++) {
      int cidx = tx * 4 + jj;
      float hv = acc[i][jj] + bias2[cidx] + tab_p[p * 64 + cidx] + tab_s[st * 64 + cidx];
      s = fmaf(fmaxf(hv, 0.f), W2[cidx], s);
    }
    part[i] = s;
  }
#pragma unroll
  for (int d = 1; d < 16; d <<= 1) {
#pragma unroll
    for (int i = 0; i < 4; i++) part[i] += __shfl_xor(part[i], d);
  }
  if (tx == 0) {
    float bb2 = b2[0];
#pragma unroll
    for (int i = 0; i < 4; i++) {
      int e = row0 + ty * 4 + i;
      if (e < E) out[e] = part[i] + bb2;
    }
  }
}

// ---------------- launch ----------------
extern "C" void kernel_launch(void* const* d_in, const int* in_sizes, int n_in,
                              void* d_out, int out_size, void* d_ws, size_t ws_size,
                              hipStream_t stream) {
  const int* src = (const int*)d_in[0];
  const int* dst = (const int*)d_in[1];
  const float* t = (const float*)d_in[2];
  const float* msg = (const float*)d_in[3];
  const float* price_seq = (const float*)d_in[4];
  const int* x_static = (const int*)d_in[6];
  const float* memory = (const float*)d_in[7];
  const float* last_update = (const float*)d_in[8];
  const float* time_w = (const float*)d_in[9];
  const float* time_b = (const float*)d_in[10];
  const float* gWih = (const float*)d_in[11];
  const float* gWhh = (const float*)d_in[12];
  const float* gbih = (const float*)d_in[13];
  const float* gbhh = (const float*)d_in[14];
  const float* party_emb = (const float*)d_in[15];
  const float* state_emb = (const float*)d_in[16];
  const float* static_W = (const float*)d_in[17];
  const float* static_b = (const float*)d_in[18];
  const float* lWih = (const float*)d_in[19];
  const float* lWhh = (const float*)d_in[20];
  const float* lbih = (const float*)d_in[21];
  const float* lbhh = (const float*)d_in[22];
  const float* price_W = (const float*)d_in[23];
  const float* price_b = (const float*)d_in[24];
  const float* W1 = (const float*)d_in[25];
  const float* b1 = (const float*)d_in[26];
  const float* W2 = (const float*)d_in[27];
  const float* b2 = (const float*)d_in[28];
  float* out = (float*)d_out;

  const int E = in_sizes[0];
  const int N = in_sizes[8];

  char* ws = (char*)d_ws;
  size_t off = 0;
  auto alloc = [&](size_t bytes) { size_t o = off; off += (bytes + 255) & ~(size_t)255; return o; };
  int* cnt      = (int*)(ws + alloc((size_t)N * 4));
  int* offs     = (int*)(ws + alloc((size_t)(N + 1) * 4));
  int* cursor   = (int*)(ws + alloc((size_t)N * 4));
  int* other    = (int*)(ws + alloc((size_t)2 * E * 4));
  int* eid      = (int*)(ws + alloc((size_t)2 * E * 4));
  ushort* WcatT = (ushort*)(ws + alloc((size_t)GOUT * KTOT * 2));
  float* Wcomb  = (float*)(ws + alloc((size_t)KP * 64 * 4));
  float* tab_p  = (float*)(ws + alloc((size_t)4 * 64 * 4));
  float* tab_s  = (float*)(ws + alloc((size_t)50 * 64 * 4));
  float* bias2  = (float*)(ws + alloc((size_t)64 * 4));
  ushort* agg_b = (ushort*)(ws + alloc((size_t)N * KTOT * 2));
  float* mem_new = (float*)(ws + alloc((size_t)N * H * 4));
  float* hout   = (float*)(ws + alloc((size_t)E * LH * 4));
  (void)ws_size;

  hipMemsetAsync(cnt, 0, (size_t)N * 4, stream);

  build_weights<<<(GOUT * KTOT + 255) / 256, 256, 0, stream>>>(gWih, gWhh, WcatT);
  prep_pred<<<1, 256, 0, stream>>>(W1, b1, static_W, static_b, price_W, price_b,
                                   party_emb, state_emb, Wcomb, tab_p, tab_s, bias2);
  count_kernel<<<(E + 255) / 256, 256, 0, stream>>>(src, dst, cnt, E);
  scan_kernel<<<1, 1024, 0, stream>>>(cnt, offs, cursor, N);
  fill_kernel<<<(E + 255) / 256, 256, 0, stream>>>(src, dst, cursor, other, eid, E);
  agg_kernel<<<N, 256, 0, stream>>>(offs, other, eid, memory, msg, t, last_update,
                                    time_w, time_b, cnt, agg_b, N);
  gru_gemm_mfma<<<(N + 31) / 32, 256, 0, stream>>>(agg_b, WcatT, memory, cnt,
                                                   gbih, gbhh, mem_new, N);
  int nwaves = (E + 15) / 16;
  lstm_mfma_kernel<<<(nwaves + 3) / 4, 256, 0, stream>>>(price_seq, lWih, lWhh, lbih, lbhh, hout, E);
  pred_gemm<<<(E + 63) / 64, 256, 0, stream>>>(src, dst, x_static, mem_new, hout,
      Wcomb, tab_p, tab_s, bias2, W2, b2, out, E);
}

// Round 6
// 645.729 us; speedup vs baseline: 4.6298x; 1.2967x over previous
//
#include <hip/hip_runtime.h>

#define H 128
#define EF 32
#define TT 14
#define LH 32
#define KDIM 416   // 3H+EF
#define GOUT 512   // [r_pre, z_pre, i_n, h_n] each 128
#define KTOT 544   // 416 (agg) + 128 (memory)
#define KP 288     // pred GEMM K: 128 ms + 128 md + 32 h

typedef __attribute__((ext_vector_type(8))) short bf16x8;
typedef __attribute__((ext_vector_type(4))) float f32x4;

__device__ __forceinline__ float sigmoidf_(float x) { return 1.0f / (1.0f + __expf(-x)); }
__device__ __forceinline__ float tanhfast_(float x) { float e = __expf(2.0f * x); return 1.0f - 2.0f / (e + 1.0f); }
__device__ __forceinline__ ushort f2bf(float x) {
  uint u = __float_as_uint(x);
  u += 0x7fff + ((u >> 16) & 1);   // RTNE
  return (ushort)(u >> 16);
}

// ---------------- K1: build WcatT bf16 [512][544] (o-major) ----------------
__global__ __launch_bounds__(256) void build_weights(
    const float* __restrict__ Wih, const float* __restrict__ Whh,
    ushort* __restrict__ WcatT) {
  int i = blockIdx.x * 256 + threadIdx.x;
  if (i >= GOUT * KTOT) return;
  int o = i / KTOT, k = i % KTOT;
  int j = o & 127;
  float v = 0.f;
  if (o < 256) {  // r (o<128) and z (o<256): gi+gh fused
    int row = (o < 128) ? j : (128 + j);
    v = (k < KDIM) ? Wih[row * KDIM + k] : Whh[row * H + (k - KDIM)];
  } else if (o < 384) {  // i_n
    v = (k < KDIM) ? Wih[(256 + j) * KDIM + k] : 0.f;
  } else {               // h_n
    v = (k < KDIM) ? 0.f : Whh[(256 + j) * H + (k - KDIM)];
  }
  WcatT[i] = f2bf(v);
}

// ---------------- K1b: predictor algebra collapse (bf16 Wcombb [64][288]) ----------------
__global__ __launch_bounds__(256) void prep_pred(
    const float* __restrict__ W1, const float* __restrict__ b1,
    const float* __restrict__ static_W, const float* __restrict__ static_b,
    const float* __restrict__ price_W, const float* __restrict__ price_b,
    const float* __restrict__ party_emb, const float* __restrict__ state_emb,
    ushort* __restrict__ Wcombb, float* __restrict__ tab_p, float* __restrict__ tab_s,
    float* __restrict__ bias2) {
  __shared__ float G1[64][32];
  int tid = threadIdx.x;
  for (int idx = tid; idx < 2048; idx += 256) {
    int o = idx >> 5, k = idx & 31;
    float g = 0.f, m = 0.f;
    for (int j = 0; j < 128; j++) {
      g = fmaf(W1[o * 384 + j], static_W[j * 32 + k], g);
      m = fmaf(W1[o * 384 + 128 + j] + W1[o * 384 + 256 + j], price_W[j * 32 + k], m);
    }
    G1[o][k] = g;
    Wcombb[o * KP + 256 + k] = f2bf(m);
  }
  for (int idx = tid; idx < 64 * 256; idx += 256) {
    int o = idx >> 8, j = idx & 255;
    Wcombb[o * KP + j] = f2bf(W1[o * 384 + j]);
  }
  __syncthreads();
  for (int idx = tid; idx < 4 * 64; idx += 256) {
    int p = idx >> 6, o = idx & 63;
    float s = 0.f;
    for (int k = 0; k < 16; k++) s = fmaf(G1[o][k], party_emb[p * 16 + k], s);
    tab_p[idx] = s;
  }
  for (int idx = tid; idx < 50 * 64; idx += 256) {
    int si = idx >> 6, o = idx & 63;
    float s = 0.f;
    for (int k = 0; k < 16; k++) s = fmaf(G1[o][16 + k], state_emb[si * 16 + k], s);
    tab_s[idx] = s;
  }
  if (tid < 64) {
    float s = b1[tid];
    for (int j = 0; j < 128; j++) {
      s = fmaf(W1[tid * 384 + j], static_b[j], s);
      s = fmaf(W1[tid * 384 + 128 + j] + W1[tid * 384 + 256 + j], price_b[j], s);
    }
    bias2[tid] = s;
  }
}

// ---------------- K2a: degree count ----------------
__global__ void count_kernel(const int* __restrict__ src, const int* __restrict__ dst,
                             int* cnt, int E) {
  int e = blockIdx.x * blockDim.x + threadIdx.x;
  if (e < E) {
    atomicAdd(&cnt[dst[e]], 1);
    atomicAdd(&cnt[src[e]], 1);
  }
}

// ---------------- K2b: exclusive scan (single block) ----------------
__global__ __launch_bounds__(1024) void scan_kernel(const int* __restrict__ cnt,
                                                    int* __restrict__ offs,
                                                    int* __restrict__ cursor, int N) {
  __shared__ int part[1024];
  int tid = threadIdx.x;
  int chunk = (N + 1023) / 1024;
  int beg = tid * chunk;
  int end = min(beg + chunk, N);
  int s = 0;
  for (int i = beg; i < end; i++) s += cnt[i];
  part[tid] = s;
  __syncthreads();
  for (int d = 1; d < 1024; d <<= 1) {
    int v = (tid >= d) ? part[tid - d] : 0;
    __syncthreads();
    part[tid] += v;
    __syncthreads();
  }
  int run = (tid > 0) ? part[tid - 1] : 0;
  for (int i = beg; i < end; i++) {
    offs[i] = run;
    cursor[i] = run;
    run += cnt[i];
  }
  if (tid == 1023) offs[N] = part[1023];
}

// ---------------- K2c: CSR fill ----------------
__global__ void fill_kernel(const int* __restrict__ src, const int* __restrict__ dst,
                            int* cursor, int* __restrict__ other, int* __restrict__ eid, int E) {
  int e = blockIdx.x * blockDim.x + threadIdx.x;
  if (e >= E) return;
  int s = src[e], d = dst[e];
  int p1 = atomicAdd(&cursor[d], 1);
  other[p1] = s; eid[p1] = e;
  int p2 = atomicAdd(&cursor[s], 1);
  other[p2] = d; eid[p2] = e;
}

// ---------------- K2d: per-node aggregation -> agg_b bf16 [N][544] ----------------
__global__ __launch_bounds__(256) void agg_kernel(
    const int* __restrict__ offs, const int* __restrict__ other, const int* __restrict__ eid,
    const float* __restrict__ mem, const float* __restrict__ msg,
    const float* __restrict__ t, const float* __restrict__ lu,
    const float* __restrict__ tw, const float* __restrict__ tb,
    const int* __restrict__ cnt, ushort* __restrict__ agg_b, int N) {
  int v = blockIdx.x;
  int tid = threadIdx.x;
  int beg = offs[v], end = offs[v + 1];
  float lupd = lu[v];
  float w = 0.f, b = 0.f;
  if (tid >= 32 && tid < 160) { w = tw[tid - 32]; b = tb[tid - 32]; }
  float a0 = 0.f, a1 = 0.f;
  for (int p = beg; p < end; p++) {
    int u = other[p];
    int e = eid[p];
    if (tid < 128) a0 += mem[u * H + tid];
    if (tid < 32) a1 += msg[e * EF + tid];
    else if (tid < 160) a1 += cosf(fmaf(t[e] - lupd, w, b));
  }
  int cv = cnt[v];
  float inv = 1.f / (float)max(cv, 1);
  ushort* arow = agg_b + (size_t)v * KTOT;
  if (tid < 128) {
    arow[tid] = f2bf(a0 * inv);
  } else {
    float mv = mem[v * H + (tid - 128)];
    arow[tid] = f2bf((cv > 0) ? mv : 0.f);  // mean of cv copies of mem[v]
    arow[288 + tid] = f2bf(mv);             // cols 416..543: Whh operand
  }
  if (tid < 160) arow[256 + tid] = f2bf(a1 * inv);
}

// ---------------- K3: MFMA GEMM + fused GRU finalize -> mem_newb bf16 [N][128] ----------------
__global__ __launch_bounds__(256) void gru_gemm_mfma(
    const ushort* __restrict__ aggb, const ushort* __restrict__ WcatT,
    const float* __restrict__ mem, const int* __restrict__ cnt,
    const float* __restrict__ bih, const float* __restrict__ bhh,
    ushort* __restrict__ mem_newb, int N) {
  __shared__ union {
    ushort a[32 * 552];       // 35.3 KB
    float g[4][32][132];      // 67.6 KB
  } sm;
  int tid = threadIdx.x;
  int lane = tid & 63;
  int w = tid >> 6;
  int n0 = blockIdx.x * 32;

#pragma unroll
  for (int i = 0; i < 8; i++) {
    int row = w * 8 + i;
    int gr = min(n0 + row, N - 1);
    const uint4* srcp = reinterpret_cast<const uint4*>(aggb + (size_t)gr * KTOT);
    uint4* dstp = reinterpret_cast<uint4*>(sm.a + row * 552);
    dstp[lane] = srcp[lane];
    if (lane < 4) dstp[64 + lane] = srcp[64 + lane];
  }
  __syncthreads();

  f32x4 acc[2][8] = {};
  int arow_b = (lane & 15);
  int koff = (lane >> 4) * 8;
  for (int ks = 0; ks < 17; ks++) {
    int k = ks * 32 + koff;
    bf16x8 afr0 = *reinterpret_cast<const bf16x8*>(sm.a + (arow_b) * 552 + k);
    bf16x8 afr1 = *reinterpret_cast<const bf16x8*>(sm.a + (16 + arow_b) * 552 + k);
#pragma unroll
    for (int nt = 0; nt < 8; nt++) {
      int o = w * 128 + nt * 16 + (lane & 15);
      bf16x8 bfr = *reinterpret_cast<const bf16x8*>(WcatT + (size_t)o * KTOT + k);
      acc[0][nt] = __builtin_amdgcn_mfma_f32_16x16x32_bf16(afr0, bfr, acc[0][nt], 0, 0, 0);
      acc[1][nt] = __builtin_amdgcn_mfma_f32_16x16x32_bf16(afr1, bfr, acc[1][nt], 0, 0, 0);
    }
  }
  __syncthreads();  // A reads done; reuse LDS

#pragma unroll
  for (int mt = 0; mt < 2; mt++)
#pragma unroll
    for (int nt = 0; nt < 8; nt++)
#pragma unroll
      for (int r = 0; r < 4; r++)
        sm.g[w][mt * 16 + (lane >> 4) * 4 + r][nt * 16 + (lane & 15)] = acc[mt][nt][r];
  __syncthreads();

  int row = tid >> 3, j0 = (tid & 7) * 16;
  int n = n0 + row;
  if (n < N) {
    int cv = cnt[n];
#pragma unroll
    for (int jj = 0; jj < 16; jj++) {
      int j = j0 + jj;
      float m = mem[(size_t)n * H + j];
      float o;
      if (cv > 0) {
        float rp = sm.g[0][row][j] + bih[j] + bhh[j];
        float zp = sm.g[1][row][j] + bih[128 + j] + bhh[128 + j];
        float ip = sm.g[2][row][j] + bih[256 + j];
        float hp = sm.g[3][row][j] + bhh[256 + j];
        float r = sigmoidf_(rp), z = sigmoidf_(zp);
        float nn = tanhfast_(ip + r * hp);
        o = (1.f - z) * nn + z * m;
      } else {
        o = m;
      }
      mem_newb[(size_t)n * H + j] = f2bf(o);
    }
  }
}

// ---------------- K5a: price LSTM, MFMA-batched, extended-K (h,x,1) ----------------
// Augmented K=64: k 0..31 = h, k 32 = x_t, k 33 = 1 (folds Wih & bias into MFMA).
// 16 edges per wave; D col=lane&15=edge, row=(lane>>4)*4+r = gate row in block b.
__global__ __launch_bounds__(256) void lstm_mfma_kernel(
    const float* __restrict__ price_seq,
    const float* __restrict__ lWih, const float* __restrict__ lWhh,
    const float* __restrict__ lbih, const float* __restrict__ lbhh,
    ushort* __restrict__ houtb, int E) {
  int lane = threadIdx.x & 63;
  int el = lane & 15;
  int g = lane >> 4;
  int wave = blockIdx.x * 4 + (threadIdx.x >> 6);
  int e = wave * 16 + el;
  bool valid = (e < E);
  int eload = valid ? e : (E - 1);

  // A fragments (h part): Whh[16b+el][g*8..g*8+7] in bf16
  union { uint u[4]; bf16x8 v; } afr[8];
#pragma unroll
  for (int b = 0; b < 8; b++) {
    const float* wr = lWhh + (16 * b + el) * LH + g * 8;
#pragma unroll
    for (int q = 0; q < 4; q++) {
      float lo = wr[2 * q], hi = wr[2 * q + 1];
      asm("v_cvt_pk_bf16_f32 %0, %1, %2" : "=v"(afr[b].u[q]) : "v"(lo), "v"(hi));
    }
  }
  // A2 fragments (x,1 part): k'=0 -> Wih[row], k'=1 -> bias[row]; only g==0 nonzero
  union { uint u[4]; bf16x8 v; } afr2[8];
#pragma unroll
  for (int b = 0; b < 8; b++) {
    float wv = lWih[16 * b + el];
    float bv = lbih[16 * b + el] + lbhh[16 * b + el];
    uint pk;
    asm("v_cvt_pk_bf16_f32 %0, %1, %2" : "=v"(pk) : "v"(wv), "v"(bv));
    afr2[b].u[0] = (g == 0) ? pk : 0u;
    afr2[b].u[1] = 0u; afr2[b].u[2] = 0u; afr2[b].u[3] = 0u;
  }

  float xv[TT];
#pragma unroll
  for (int t = 0; t < TT; t++) xv[t] = price_seq[(size_t)eload * TT + t];

  int addr_i[4];
#pragma unroll
  for (int i = 0; i < 4; i++) addr_i[i] = (el + 16 * ((g & 1) * 2 + (i >> 1))) << 2;
  bool hi_sel = (g >> 1) != 0;

  float cst[8], hval[8];
#pragma unroll
  for (int i = 0; i < 8; i++) { cst[i] = 0.f; hval[i] = 0.f; }
  uint hpk[4] = {0u, 0u, 0u, 0u};
  const f32x4 zero4 = {0.f, 0.f, 0.f, 0.f};

#pragma unroll
  for (int t = 0; t < TT; t++) {
    union { uint u[4]; bf16x8 v; } bfr;
#pragma unroll
    for (int i = 0; i < 4; i++) {
      uint lo = (uint)__builtin_amdgcn_ds_bpermute(addr_i[i], (int)hpk[i & 1]);
      uint hi = (uint)__builtin_amdgcn_ds_bpermute(addr_i[i], (int)hpk[2 + (i & 1)]);
      bfr.u[i] = hi_sel ? hi : lo;
    }
    union { uint u[4]; bf16x8 v; } bfr2;
    uint xp;
    asm("v_cvt_pk_bf16_f32 %0, %1, %2" : "=v"(xp) : "v"(xv[t]), "v"(1.0f));
    bfr2.u[0] = (g == 0) ? xp : 0u;
    bfr2.u[1] = 0u; bfr2.u[2] = 0u; bfr2.u[3] = 0u;

    f32x4 acc0, acc1, acc2, acc3, acc4, acc5, acc6, acc7;
#define STEPACC(b, A) \
    { A = __builtin_amdgcn_mfma_f32_16x16x32_bf16(afr2[b].v, bfr2.v, zero4, 0, 0, 0); \
      A = __builtin_amdgcn_mfma_f32_16x16x32_bf16(afr[b].v, bfr.v, A, 0, 0, 0); }
    STEPACC(0, acc0) STEPACC(1, acc1) STEPACC(2, acc2) STEPACC(3, acc3)
    STEPACC(4, acc4) STEPACC(5, acc5) STEPACC(6, acc6) STEPACC(7, acc7)
#undef STEPACC
#define NONLIN(b1, AI, AF, AG, AO) \
    { _Pragma("unroll") for (int r = 0; r < 4; r++) { \
        int mi = 4 * b1 + r; \
        float ig = sigmoidf_(AI[r]); \
        float fg = sigmoidf_(AF[r]); \
        float gg = tanhfast_(AG[r]); \
        float og = sigmoidf_(AO[r]); \
        float cv = fmaf(fg, cst[mi], ig * gg); \
        cst[mi] = cv; \
        hval[mi] = og * tanhfast_(cv); } }
    NONLIN(0, acc0, acc2, acc4, acc6)
    NONLIN(1, acc1, acc3, acc5, acc7)
#undef NONLIN
#pragma unroll
    for (int i = 0; i < 4; i++)
      asm("v_cvt_pk_bf16_f32 %0, %1, %2" : "=v"(hpk[i]) : "v"(hval[2 * i]), "v"(hval[2 * i + 1]));
  }

  // hpk holds final h in bf16: hpk[0..1] -> m=4g..4g+3, hpk[2..3] -> m=16+4g..16+4g+3
  if (valid) {
    uint2* rowp = reinterpret_cast<uint2*>(houtb + (size_t)e * LH);
    rowp[g] = make_uint2(hpk[0], hpk[1]);
    rowp[4 + g] = make_uint2(hpk[2], hpk[3]);
  }
}

// ---------------- K5b: pred bf16 MFMA: out[E] from X[E][288] @ Wcombb^T ----------------
// Block: 64 edges; A gathered to LDS bf16 [64][296]. Wave w: rows w*16..+15, 4 out-blocks.
__global__ __launch_bounds__(256) void pred_mfma(
    const int* __restrict__ src, const int* __restrict__ dst,
    const int* __restrict__ x_static,
    const ushort* __restrict__ mem_newb, const ushort* __restrict__ houtb,
    const ushort* __restrict__ Wcombb, const float* __restrict__ tab_p,
    const float* __restrict__ tab_s, const float* __restrict__ bias2,
    const float* __restrict__ W2, const float* __restrict__ b2,
    float* __restrict__ out, int E) {
  __shared__ ushort Asm[64 * 296];
  __shared__ int pidx[64], stix[64];
  __shared__ int sidx[64], didx[64];
  int tid = threadIdx.x;
  int row0 = blockIdx.x * 64;
  if (tid < 64) {
    int e = min(row0 + tid, E - 1);
    int s = src[e], d = dst[e];
    sidx[tid] = s; didx[tid] = d;
    pidx[tid] = x_static[s * 2]; stix[tid] = x_static[s * 2 + 1];
  }
  __syncthreads();
  // stage A: 64 rows x 36 16B-chunks (16 ms + 16 md + 4 h)
#pragma unroll
  for (int i = 0; i < 9; i++) {
    int idx = tid + i * 256;
    int row = idx / 36, c = idx % 36;
    int e = min(row0 + row, E - 1);
    uint4 v;
    if (c < 16) v = reinterpret_cast<const uint4*>(mem_newb + (size_t)sidx[row] * H)[c];
    else if (c < 32) v = reinterpret_cast<const uint4*>(mem_newb + (size_t)didx[row] * H)[c - 16];
    else v = reinterpret_cast<const uint4*>(houtb + (size_t)e * LH)[c - 32];
    *reinterpret_cast<uint4*>(Asm + row * 296 + c * 8) = v;
  }
  __syncthreads();

  int lane = tid & 63;
  int w = tid >> 6;
  f32x4 acc[4] = {};
  int arow = w * 16 + (lane & 15);
  int koff = (lane >> 4) * 8;
  for (int ks = 0; ks < 9; ks++) {
    int k = ks * 32 + koff;
    bf16x8 afr = *reinterpret_cast<const bf16x8*>(Asm + arow * 296 + k);
#pragma unroll
    for (int nt = 0; nt < 4; nt++) {
      int o = nt * 16 + (lane & 15);
      bf16x8 bfr = *reinterpret_cast<const bf16x8*>(Wcombb + (size_t)o * KP + k);
      acc[nt] = __builtin_amdgcn_mfma_f32_16x16x32_bf16(afr, bfr, acc[nt], 0, 0, 0);
    }
  }
  // epilogue: lane holds D[edge=(lane>>4)*4+r][o=nt*16+(lane&15)]
  int ocol = lane & 15;
  float bb2 = b2[0];
#pragma unroll
  for (int r = 0; r < 4; r++) {
    int rl = w * 16 + (lane >> 4) * 4 + r;
    int p = pidx[rl], st = stix[rl];
    float s = 0.f;
#pragma unroll
    for (int nt = 0; nt < 4; nt++) {
      int o = nt * 16 + ocol;
      float hv = acc[nt][r] + bias2[o] + tab_p[p * 64 + o] + tab_s[st * 64 + o];
      s = fmaf(fmaxf(hv, 0.f), W2[o], s);
    }
#pragma unroll
    for (int d = 1; d < 16; d <<= 1) s += __shfl_xor(s, d);
    int e = row0 + rl;
    if (ocol == 0 && e < E) out[e] = s + bb2;
  }
}

// ---------------- launch ----------------
extern "C" void kernel_launch(void* const* d_in, const int* in_sizes, int n_in,
                              void* d_out, int out_size, void* d_ws, size_t ws_size,
                              hipStream_t stream) {
  const int* src = (const int*)d_in[0];
  const int* dst = (const int*)d_in[1];
  const float* t = (const float*)d_in[2];
  const float* msg = (const float*)d_in[3];
  const float* price_seq = (const float*)d_in[4];
  const int* x_static = (const int*)d_in[6];
  const float* memory = (const float*)d_in[7];
  const float* last_update = (const float*)d_in[8];
  const float* time_w = (const float*)d_in[9];
  const float* time_b = (const float*)d_in[10];
  const float* gWih = (const float*)d_in[11];
  const float* gWhh = (const float*)d_in[12];
  const float* gbih = (const float*)d_in[13];
  const float* gbhh = (const float*)d_in[14];
  const float* party_emb = (const float*)d_in[15];
  const float* state_emb = (const float*)d_in[16];
  const float* static_W = (const float*)d_in[17];
  const float* static_b = (const float*)d_in[18];
  const float* lWih = (const float*)d_in[19];
  const float* lWhh = (const float*)d_in[20];
  const float* lbih = (const float*)d_in[21];
  const float* lbhh = (const float*)d_in[22];
  const float* price_W = (const float*)d_in[23];
  const float* price_b = (const float*)d_in[24];
  const float* W1 = (const float*)d_in[25];
  const float* b1 = (const float*)d_in[26];
  const float* W2 = (const float*)d_in[27];
  const float* b2 = (const float*)d_in[28];
  float* out = (float*)d_out;

  const int E = in_sizes[0];
  const int N = in_sizes[8];

  char* ws = (char*)d_ws;
  size_t off = 0;
  auto alloc = [&](size_t bytes) { size_t o = off; off += (bytes + 255) & ~(size_t)255; return o; };
  int* cnt       = (int*)(ws + alloc((size_t)N * 4));
  int* offs      = (int*)(ws + alloc((size_t)(N + 1) * 4));
  int* cursor    = (int*)(ws + alloc((size_t)N * 4));
  int* other     = (int*)(ws + alloc((size_t)2 * E * 4));
  int* eid       = (int*)(ws + alloc((size_t)2 * E * 4));
  ushort* WcatT  = (ushort*)(ws + alloc((size_t)GOUT * KTOT * 2));
  ushort* Wcombb = (ushort*)(ws + alloc((size_t)64 * KP * 2));
  float* tab_p   = (float*)(ws + alloc((size_t)4 * 64 * 4));
  float* tab_s   = (float*)(ws + alloc((size_t)50 * 64 * 4));
  float* bias2   = (float*)(ws + alloc((size_t)64 * 4));
  ushort* agg_b  = (ushort*)(ws + alloc((size_t)N * KTOT * 2));
  ushort* mem_newb = (ushort*)(ws + alloc((size_t)N * H * 2));
  ushort* houtb  = (ushort*)(ws + alloc((size_t)E * LH * 2));
  (void)ws_size;

  hipMemsetAsync(cnt, 0, (size_t)N * 4, stream);

  build_weights<<<(GOUT * KTOT + 255) / 256, 256, 0, stream>>>(gWih, gWhh, WcatT);
  prep_pred<<<1, 256, 0, stream>>>(W1, b1, static_W, static_b, price_W, price_b,
                                   party_emb, state_emb, Wcombb, tab_p, tab_s, bias2);
  count_kernel<<<(E + 255) / 256, 256, 0, stream>>>(src, dst, cnt, E);
  scan_kernel<<<1, 1024, 0, stream>>>(cnt, offs, cursor, N);
  fill_kernel<<<(E + 255) / 256, 256, 0, stream>>>(src, dst, cursor, other, eid, E);
  agg_kernel<<<N, 256, 0, stream>>>(offs, other, eid, memory, msg, t, last_update,
                                    time_w, time_b, cnt, agg_b, N);
  gru_gemm_mfma<<<(N + 31) / 32, 256, 0, stream>>>(agg_b, WcatT, memory, cnt,
                                                   gbih, gbhh, mem_newb, N);
  int nwaves = (E + 15) / 16;
  lstm_mfma_kernel<<<(nwaves + 3) / 4, 256, 0, stream>>>(price_seq, lWih, lWhh, lbih, lbhh, houtb, E);
  pred_mfma<<<(E + 63) / 64, 256, 0, stream>>>(src, dst, x_static, mem_newb, houtb,
      Wcombb, tab_p, tab_s, bias2, W2, b2, out, E);
}

// Round 7
// 632.715 us; speedup vs baseline: 4.7250x; 1.0206x over previous
//
#include <hip/hip_runtime.h>

#define H 128
#define EF 32
#define TT 14
#define LH 32
#define KDIM 416   // 3H+EF
#define GOUT 512   // [r_pre, z_pre, i_n, h_n] each 128
#define KTOT 544   // 416 (agg) + 128 (memory)
#define KP 288     // pred GEMM K: 128 ms + 128 md + 32 h

typedef __attribute__((ext_vector_type(8))) short bf16x8;
typedef __attribute__((ext_vector_type(4))) float f32x4;

__device__ __forceinline__ float sigmoidf_(float x) { return 1.0f / (1.0f + __expf(-x)); }
__device__ __forceinline__ float tanhfast_(float x) { float e = __expf(2.0f * x); return 1.0f - 2.0f / (e + 1.0f); }
__device__ __forceinline__ ushort f2bf(float x) {
  uint u = __float_as_uint(x);
  u += 0x7fff + ((u >> 16) & 1);   // RTNE
  return (ushort)(u >> 16);
}

// ---------------- K1: build WcatT bf16 [512][544] (o-major) ----------------
__global__ __launch_bounds__(256) void build_weights(
    const float* __restrict__ Wih, const float* __restrict__ Whh,
    ushort* __restrict__ WcatT) {
  int i = blockIdx.x * 256 + threadIdx.x;
  if (i >= GOUT * KTOT) return;
  int o = i / KTOT, k = i % KTOT;
  int j = o & 127;
  float v = 0.f;
  if (o < 256) {  // r (o<128) and z (o<256): gi+gh fused
    int row = (o < 128) ? j : (128 + j);
    v = (k < KDIM) ? Wih[row * KDIM + k] : Whh[row * H + (k - KDIM)];
  } else if (o < 384) {  // i_n
    v = (k < KDIM) ? Wih[(256 + j) * KDIM + k] : 0.f;
  } else {               // h_n
    v = (k < KDIM) ? 0.f : Whh[(256 + j) * H + (k - KDIM)];
  }
  WcatT[i] = f2bf(v);
}

// ---------------- K1b: predictor algebra collapse (bf16 Wcombb [64][288]) ----------------
__global__ __launch_bounds__(256) void prep_pred(
    const float* __restrict__ W1, const float* __restrict__ b1,
    const float* __restrict__ static_W, const float* __restrict__ static_b,
    const float* __restrict__ price_W, const float* __restrict__ price_b,
    const float* __restrict__ party_emb, const float* __restrict__ state_emb,
    ushort* __restrict__ Wcombb, float* __restrict__ tab_p, float* __restrict__ tab_s,
    float* __restrict__ bias2) {
  __shared__ float G1[64][32];
  int tid = threadIdx.x;
  for (int idx = tid; idx < 2048; idx += 256) {
    int o = idx >> 5, k = idx & 31;
    float g = 0.f, m = 0.f;
    for (int j = 0; j < 128; j++) {
      g = fmaf(W1[o * 384 + j], static_W[j * 32 + k], g);
      m = fmaf(W1[o * 384 + 128 + j] + W1[o * 384 + 256 + j], price_W[j * 32 + k], m);
    }
    G1[o][k] = g;
    Wcombb[o * KP + 256 + k] = f2bf(m);
  }
  for (int idx = tid; idx < 64 * 256; idx += 256) {
    int o = idx >> 8, j = idx & 255;
    Wcombb[o * KP + j] = f2bf(W1[o * 384 + j]);
  }
  __syncthreads();
  for (int idx = tid; idx < 4 * 64; idx += 256) {
    int p = idx >> 6, o = idx & 63;
    float s = 0.f;
    for (int k = 0; k < 16; k++) s = fmaf(G1[o][k], party_emb[p * 16 + k], s);
    tab_p[idx] = s;
  }
  for (int idx = tid; idx < 50 * 64; idx += 256) {
    int si = idx >> 6, o = idx & 63;
    float s = 0.f;
    for (int k = 0; k < 16; k++) s = fmaf(G1[o][16 + k], state_emb[si * 16 + k], s);
    tab_s[idx] = s;
  }
  if (tid < 64) {
    float s = b1[tid];
    for (int j = 0; j < 128; j++) {
      s = fmaf(W1[tid * 384 + j], static_b[j], s);
      s = fmaf(W1[tid * 384 + 128 + j] + W1[tid * 384 + 256 + j], price_b[j], s);
    }
    bias2[tid] = s;
  }
}

// ---------------- K2a: degree count ----------------
__global__ void count_kernel(const int* __restrict__ src, const int* __restrict__ dst,
                             int* cnt, int E) {
  int e = blockIdx.x * blockDim.x + threadIdx.x;
  if (e < E) {
    atomicAdd(&cnt[dst[e]], 1);
    atomicAdd(&cnt[src[e]], 1);
  }
}

// ---------------- K2b: exclusive scan (single block) ----------------
__global__ __launch_bounds__(1024) void scan_kernel(const int* __restrict__ cnt,
                                                    int* __restrict__ offs,
                                                    int* __restrict__ cursor, int N) {
  __shared__ int part[1024];
  int tid = threadIdx.x;
  int chunk = (N + 1023) / 1024;
  int beg = tid * chunk;
  int end = min(beg + chunk, N);
  int s = 0;
  for (int i = beg; i < end; i++) s += cnt[i];
  part[tid] = s;
  __syncthreads();
  for (int d = 1; d < 1024; d <<= 1) {
    int v = (tid >= d) ? part[tid - d] : 0;
    __syncthreads();
    part[tid] += v;
    __syncthreads();
  }
  int run = (tid > 0) ? part[tid - 1] : 0;
  for (int i = beg; i < end; i++) {
    offs[i] = run;
    cursor[i] = run;
    run += cnt[i];
  }
  if (tid == 1023) offs[N] = part[1023];
}

// ---------------- K2c: CSR fill ----------------
__global__ void fill_kernel(const int* __restrict__ src, const int* __restrict__ dst,
                            int* cursor, int* __restrict__ other, int* __restrict__ eid, int E) {
  int e = blockIdx.x * blockDim.x + threadIdx.x;
  if (e >= E) return;
  int s = src[e], d = dst[e];
  int p1 = atomicAdd(&cursor[d], 1);
  other[p1] = s; eid[p1] = e;
  int p2 = atomicAdd(&cursor[s], 1);
  other[p2] = d; eid[p2] = e;
}

// ---------------- K2d: per-node aggregation -> agg_b bf16 [N][544] ----------------
__global__ __launch_bounds__(256) void agg_kernel(
    const int* __restrict__ offs, const int* __restrict__ other, const int* __restrict__ eid,
    const float* __restrict__ mem, const float* __restrict__ msg,
    const float* __restrict__ t, const float* __restrict__ lu,
    const float* __restrict__ tw, const float* __restrict__ tb,
    const int* __restrict__ cnt, ushort* __restrict__ agg_b, int N) {
  int v = blockIdx.x;
  int tid = threadIdx.x;
  int beg = offs[v], end = offs[v + 1];
  float lupd = lu[v];
  float w = 0.f, b = 0.f;
  if (tid >= 32 && tid < 160) { w = tw[tid - 32]; b = tb[tid - 32]; }
  float a0 = 0.f, a1 = 0.f;
  for (int p = beg; p < end; p++) {
    int u = other[p];
    int e = eid[p];
    if (tid < 128) a0 += mem[u * H + tid];
    if (tid < 32) a1 += msg[e * EF + tid];
    else if (tid < 160) a1 += cosf(fmaf(t[e] - lupd, w, b));
  }
  int cv = cnt[v];
  float inv = 1.f / (float)max(cv, 1);
  ushort* arow = agg_b + (size_t)v * KTOT;
  if (tid < 128) {
    arow[tid] = f2bf(a0 * inv);
  } else {
    float mv = mem[v * H + (tid - 128)];
    arow[tid] = f2bf((cv > 0) ? mv : 0.f);  // mean of cv copies of mem[v]
    arow[288 + tid] = f2bf(mv);             // cols 416..543: Whh operand
  }
  if (tid < 160) arow[256 + tid] = f2bf(a1 * inv);
}

// ---------------- K3: MFMA GEMM + fused GRU finalize -> mem_newb bf16 [N][128] ----------------
__global__ __launch_bounds__(256) void gru_gemm_mfma(
    const ushort* __restrict__ aggb, const ushort* __restrict__ WcatT,
    const float* __restrict__ mem, const int* __restrict__ cnt,
    const float* __restrict__ bih, const float* __restrict__ bhh,
    ushort* __restrict__ mem_newb, int N) {
  __shared__ union {
    ushort a[32 * 552];       // 35.3 KB
    float g[4][32][132];      // 67.6 KB
  } sm;
  int tid = threadIdx.x;
  int lane = tid & 63;
  int w = tid >> 6;
  int n0 = blockIdx.x * 32;

#pragma unroll
  for (int i = 0; i < 8; i++) {
    int row = w * 8 + i;
    int gr = min(n0 + row, N - 1);
    const uint4* srcp = reinterpret_cast<const uint4*>(aggb + (size_t)gr * KTOT);
    uint4* dstp = reinterpret_cast<uint4*>(sm.a + row * 552);
    dstp[lane] = srcp[lane];
    if (lane < 4) dstp[64 + lane] = srcp[64 + lane];
  }
  __syncthreads();

  f32x4 acc[2][8] = {};
  int arow_b = (lane & 15);
  int koff = (lane >> 4) * 8;
  for (int ks = 0; ks < 17; ks++) {
    int k = ks * 32 + koff;
    bf16x8 afr0 = *reinterpret_cast<const bf16x8*>(sm.a + (arow_b) * 552 + k);
    bf16x8 afr1 = *reinterpret_cast<const bf16x8*>(sm.a + (16 + arow_b) * 552 + k);
#pragma unroll
    for (int nt = 0; nt < 8; nt++) {
      int o = w * 128 + nt * 16 + (lane & 15);
      bf16x8 bfr = *reinterpret_cast<const bf16x8*>(WcatT + (size_t)o * KTOT + k);
      acc[0][nt] = __builtin_amdgcn_mfma_f32_16x16x32_bf16(afr0, bfr, acc[0][nt], 0, 0, 0);
      acc[1][nt] = __builtin_amdgcn_mfma_f32_16x16x32_bf16(afr1, bfr, acc[1][nt], 0, 0, 0);
    }
  }
  __syncthreads();  // A reads done; reuse LDS

#pragma unroll
  for (int mt = 0; mt < 2; mt++)
#pragma unroll
    for (int nt = 0; nt < 8; nt++)
#pragma unroll
      for (int r = 0; r < 4; r++)
        sm.g[w][mt * 16 + (lane >> 4) * 4 + r][nt * 16 + (lane & 15)] = acc[mt][nt][r];
  __syncthreads();

  int row = tid >> 3, j0 = (tid & 7) * 16;
  int n = n0 + row;
  if (n < N) {
    int cv = cnt[n];
#pragma unroll
    for (int jj = 0; jj < 16; jj++) {
      int j = j0 + jj;
      float m = mem[(size_t)n * H + j];
      float o;
      if (cv > 0) {
        float rp = sm.g[0][row][j] + bih[j] + bhh[j];
        float zp = sm.g[1][row][j] + bih[128 + j] + bhh[128 + j];
        float ip = sm.g[2][row][j] + bih[256 + j];
        float hp = sm.g[3][row][j] + bhh[256 + j];
        float r = sigmoidf_(rp), z = sigmoidf_(zp);
        float nn = tanhfast_(ip + r * hp);
        o = (1.f - z) * nn + z * m;
      } else {
        o = m;
      }
      mem_newb[(size_t)n * H + j] = f2bf(o);
    }
  }
}

// ---------------- K5a: price LSTM, MFMA-batched, extended-K, ROLLED t-loop ----------------
// Augmented K=64: k 0..31 = h, k 32 = x_t, k 33 = 1 (folds Wih & bias into MFMA).
// 16 edges per wave; rolled loop keeps afr/afr2/hpk/cst as loop-carried registers
// (full unroll made the compiler rematerialize the weight loads every step).
__global__ __launch_bounds__(256) void lstm_mfma_kernel(
    const float* __restrict__ price_seq,
    const float* __restrict__ lWih, const float* __restrict__ lWhh,
    const float* __restrict__ lbih, const float* __restrict__ lbhh,
    ushort* __restrict__ houtb, int E) {
  __shared__ float ps[64][15];  // block's 64 edges x 14 steps (pad 15)
  int tid = threadIdx.x;
  int lane = tid & 63;
  int el = lane & 15;
  int g = lane >> 4;
  int wv = tid >> 6;
  int row0 = blockIdx.x * 64;
  int el_local = wv * 16 + el;
  int e = row0 + el_local;
  bool valid = (e < E);

  // stage price rows
  for (int idx = tid; idx < 64 * TT; idx += 256) {
    int row = idx / TT, col = idx % TT;
    int ee = min(row0 + row, E - 1);
    ps[row][col] = price_seq[(size_t)ee * TT + col];
  }
  __syncthreads();

  // A fragments (h part): Whh[16b+el][g*8..g*8+7] in bf16
  union { uint u[4]; bf16x8 v; } afr[8];
#pragma unroll
  for (int b = 0; b < 8; b++) {
    const float* wr = lWhh + (16 * b + el) * LH + g * 8;
#pragma unroll
    for (int q = 0; q < 4; q++) {
      float lo = wr[2 * q], hi = wr[2 * q + 1];
      asm("v_cvt_pk_bf16_f32 %0, %1, %2" : "=v"(afr[b].u[q]) : "v"(lo), "v"(hi));
    }
  }
  // A2 fragments (x,1 part): k'=0 -> Wih[row], k'=1 -> bias[row]; only g==0 nonzero
  uint afr2w[8];
#pragma unroll
  for (int b = 0; b < 8; b++) {
    float wvv = lWih[16 * b + el];
    float bv = lbih[16 * b + el] + lbhh[16 * b + el];
    uint pk;
    asm("v_cvt_pk_bf16_f32 %0, %1, %2" : "=v"(pk) : "v"(wvv), "v"(bv));
    afr2w[b] = (g == 0) ? pk : 0u;
  }

  int addr_i[4];
#pragma unroll
  for (int i = 0; i < 4; i++) addr_i[i] = (el + 16 * ((g & 1) * 2 + (i >> 1))) << 2;
  bool hi_sel = (g >> 1) != 0;

  float cst[8];
#pragma unroll
  for (int i = 0; i < 8; i++) cst[i] = 0.f;
  uint hpk[4] = {0u, 0u, 0u, 0u};
  const f32x4 zero4 = {0.f, 0.f, 0.f, 0.f};

#pragma unroll 1
  for (int t = 0; t < TT; t++) {
    union { uint u[4]; bf16x8 v; } bfr;
#pragma unroll
    for (int i = 0; i < 4; i++) {
      uint lo = (uint)__builtin_amdgcn_ds_bpermute(addr_i[i], (int)hpk[i & 1]);
      uint hi = (uint)__builtin_amdgcn_ds_bpermute(addr_i[i], (int)hpk[2 + (i & 1)]);
      bfr.u[i] = hi_sel ? hi : lo;
    }
    float x = ps[el_local][t];
    union { uint u[4]; bf16x8 v; } bfr2;
    uint xp;
    asm("v_cvt_pk_bf16_f32 %0, %1, %2" : "=v"(xp) : "v"(x), "v"(1.0f));
    bfr2.u[0] = (g == 0) ? xp : 0u;
    bfr2.u[1] = 0u; bfr2.u[2] = 0u; bfr2.u[3] = 0u;

    float hval[8];
    f32x4 acc0, acc1, acc2, acc3, acc4, acc5, acc6, acc7;
#define STEPACC(b, A) \
    { union { uint u[4]; bf16x8 v; } a2; a2.u[0] = afr2w[b]; a2.u[1] = 0u; a2.u[2] = 0u; a2.u[3] = 0u; \
      A = __builtin_amdgcn_mfma_f32_16x16x32_bf16(a2.v, bfr2.v, zero4, 0, 0, 0); \
      A = __builtin_amdgcn_mfma_f32_16x16x32_bf16(afr[b].v, bfr.v, A, 0, 0, 0); }
    STEPACC(0, acc0) STEPACC(1, acc1) STEPACC(2, acc2) STEPACC(3, acc3)
    STEPACC(4, acc4) STEPACC(5, acc5) STEPACC(6, acc6) STEPACC(7, acc7)
#undef STEPACC
#define NONLIN(b1, AI, AF, AG, AO) \
    { _Pragma("unroll") for (int r = 0; r < 4; r++) { \
        int mi = 4 * b1 + r; \
        float ig = sigmoidf_(AI[r]); \
        float fg = sigmoidf_(AF[r]); \
        float gg = tanhfast_(AG[r]); \
        float og = sigmoidf_(AO[r]); \
        float cv = fmaf(fg, cst[mi], ig * gg); \
        cst[mi] = cv; \
        hval[mi] = og * tanhfast_(cv); } }
    NONLIN(0, acc0, acc2, acc4, acc6)
    NONLIN(1, acc1, acc3, acc5, acc7)
#undef NONLIN
#pragma unroll
    for (int i = 0; i < 4; i++)
      asm("v_cvt_pk_bf16_f32 %0, %1, %2" : "=v"(hpk[i]) : "v"(hval[2 * i]), "v"(hval[2 * i + 1]));
  }

  // hpk holds final h in bf16: hpk[0..1] -> m=4g..4g+3, hpk[2..3] -> m=16+4g..16+4g+3
  if (valid) {
    uint2* rowp = reinterpret_cast<uint2*>(houtb + (size_t)e * LH);
    rowp[g] = make_uint2(hpk[0], hpk[1]);
    rowp[4 + g] = make_uint2(hpk[2], hpk[3]);
  }
}

// ---------------- K5b: pred bf16 MFMA: out[E] from X[E][288] @ Wcombb^T ----------------
__global__ __launch_bounds__(256) void pred_mfma(
    const int* __restrict__ src, const int* __restrict__ dst,
    const int* __restrict__ x_static,
    const ushort* __restrict__ mem_newb, const ushort* __restrict__ houtb,
    const ushort* __restrict__ Wcombb, const float* __restrict__ tab_p,
    const float* __restrict__ tab_s, const float* __restrict__ bias2,
    const float* __restrict__ W2, const float* __restrict__ b2,
    float* __restrict__ out, int E) {
  __shared__ ushort Asm[64 * 296];
  __shared__ int pidx[64], stix[64];
  __shared__ int sidx[64], didx[64];
  int tid = threadIdx.x;
  int row0 = blockIdx.x * 64;
  if (tid < 64) {
    int e = min(row0 + tid, E - 1);
    int s = src[e], d = dst[e];
    sidx[tid] = s; didx[tid] = d;
    pidx[tid] = x_static[s * 2]; stix[tid] = x_static[s * 2 + 1];
  }
  __syncthreads();
  // stage A: 64 rows x 36 16B-chunks (16 ms + 16 md + 4 h)
#pragma unroll
  for (int i = 0; i < 9; i++) {
    int idx = tid + i * 256;
    int row = idx / 36, c = idx % 36;
    int e = min(row0 + row, E - 1);
    uint4 v;
    if (c < 16) v = reinterpret_cast<const uint4*>(mem_newb + (size_t)sidx[row] * H)[c];
    else if (c < 32) v = reinterpret_cast<const uint4*>(mem_newb + (size_t)didx[row] * H)[c - 16];
    else v = reinterpret_cast<const uint4*>(houtb + (size_t)e * LH)[c - 32];
    *reinterpret_cast<uint4*>(Asm + row * 296 + c * 8) = v;
  }
  __syncthreads();

  int lane = tid & 63;
  int w = tid >> 6;
  f32x4 acc[4] = {};
  int arow = w * 16 + (lane & 15);
  int koff = (lane >> 4) * 8;
  for (int ks = 0; ks < 9; ks++) {
    int k = ks * 32 + koff;
    bf16x8 afr = *reinterpret_cast<const bf16x8*>(Asm + arow * 296 + k);
#pragma unroll
    for (int nt = 0; nt < 4; nt++) {
      int o = nt * 16 + (lane & 15);
      bf16x8 bfr = *reinterpret_cast<const bf16x8*>(Wcombb + (size_t)o * KP + k);
      acc[nt] = __builtin_amdgcn_mfma_f32_16x16x32_bf16(afr, bfr, acc[nt], 0, 0, 0);
    }
  }
  // epilogue: lane holds D[edge=(lane>>4)*4+r][o=nt*16+(lane&15)]
  int ocol = lane & 15;
  float bb2 = b2[0];
#pragma unroll
  for (int r = 0; r < 4; r++) {
    int rl = w * 16 + (lane >> 4) * 4 + r;
    int p = pidx[rl], st = stix[rl];
    float s = 0.f;
#pragma unroll
    for (int nt = 0; nt < 4; nt++) {
      int o = nt * 16 + ocol;
      float hv = acc[nt][r] + bias2[o] + tab_p[p * 64 + o] + tab_s[st * 64 + o];
      s = fmaf(fmaxf(hv, 0.f), W2[o], s);
    }
#pragma unroll
    for (int d = 1; d < 16; d <<= 1) s += __shfl_xor(s, d);
    int e = row0 + rl;
    if (ocol == 0 && e < E) out[e] = s + bb2;
  }
}

// ---------------- launch ----------------
extern "C" void kernel_launch(void* const* d_in, const int* in_sizes, int n_in,
                              void* d_out, int out_size, void* d_ws, size_t ws_size,
                              hipStream_t stream) {
  const int* src = (const int*)d_in[0];
  const int* dst = (const int*)d_in[1];
  const float* t = (const float*)d_in[2];
  const float* msg = (const float*)d_in[3];
  const float* price_seq = (const float*)d_in[4];
  const int* x_static = (const int*)d_in[6];
  const float* memory = (const float*)d_in[7];
  const float* last_update = (const float*)d_in[8];
  const float* time_w = (const float*)d_in[9];
  const float* time_b = (const float*)d_in[10];
  const float* gWih = (const float*)d_in[11];
  const float* gWhh = (const float*)d_in[12];
  const float* gbih = (const float*)d_in[13];
  const float* gbhh = (const float*)d_in[14];
  const float* party_emb = (const float*)d_in[15];
  const float* state_emb = (const float*)d_in[16];
  const float* static_W = (const float*)d_in[17];
  const float* static_b = (const float*)d_in[18];
  const float* lWih = (const float*)d_in[19];
  const float* lWhh = (const float*)d_in[20];
  const float* lbih = (const float*)d_in[21];
  const float* lbhh = (const float*)d_in[22];
  const float* price_W = (const float*)d_in[23];
  const float* price_b = (const float*)d_in[24];
  const float* W1 = (const float*)d_in[25];
  const float* b1 = (const float*)d_in[26];
  const float* W2 = (const float*)d_in[27];
  const float* b2 = (const float*)d_in[28];
  float* out = (float*)d_out;

  const int E = in_sizes[0];
  const int N = in_sizes[8];

  char* ws = (char*)d_ws;
  size_t off = 0;
  auto alloc = [&](size_t bytes) { size_t o = off; off += (bytes + 255) & ~(size_t)255; return o; };
  int* cnt       = (int*)(ws + alloc((size_t)N * 4));
  int* offs      = (int*)(ws + alloc((size_t)(N + 1) * 4));
  int* cursor    = (int*)(ws + alloc((size_t)N * 4));
  int* other     = (int*)(ws + alloc((size_t)2 * E * 4));
  int* eid       = (int*)(ws + alloc((size_t)2 * E * 4));
  ushort* WcatT  = (ushort*)(ws + alloc((size_t)GOUT * KTOT * 2));
  ushort* Wcombb = (ushort*)(ws + alloc((size_t)64 * KP * 2));
  float* tab_p   = (float*)(ws + alloc((size_t)4 * 64 * 4));
  float* tab_s   = (float*)(ws + alloc((size_t)50 * 64 * 4));
  float* bias2   = (float*)(ws + alloc((size_t)64 * 4));
  ushort* agg_b  = (ushort*)(ws + alloc((size_t)N * KTOT * 2));
  ushort* mem_newb = (ushort*)(ws + alloc((size_t)N * H * 2));
  ushort* houtb  = (ushort*)(ws + alloc((size_t)E * LH * 2));
  (void)ws_size;

  hipMemsetAsync(cnt, 0, (size_t)N * 4, stream);

  build_weights<<<(GOUT * KTOT + 255) / 256, 256, 0, stream>>>(gWih, gWhh, WcatT);
  prep_pred<<<1, 256, 0, stream>>>(W1, b1, static_W, static_b, price_W, price_b,
                                   party_emb, state_emb, Wcombb, tab_p, tab_s, bias2);
  count_kernel<<<(E + 255) / 256, 256, 0, stream>>>(src, dst, cnt, E);
  scan_kernel<<<1, 1024, 0, stream>>>(cnt, offs, cursor, N);
  fill_kernel<<<(E + 255) / 256, 256, 0, stream>>>(src, dst, cursor, other, eid, E);
  agg_kernel<<<N, 256, 0, stream>>>(offs, other, eid, memory, msg, t, last_update,
                                    time_w, time_b, cnt, agg_b, N);
  gru_gemm_mfma<<<(N + 31) / 32, 256, 0, stream>>>(agg_b, WcatT, memory, cnt,
                                                   gbih, gbhh, mem_newb, N);
  lstm_mfma_kernel<<<(E + 63) / 64, 256, 0, stream>>>(price_seq, lWih, lWhh, lbih, lbhh, houtb, E);
  pred_mfma<<<(E + 63) / 64, 256, 0, stream>>>(src, dst, x_static, mem_newb, houtb,
      Wcombb, tab_p, tab_s, bias2, W2, b2, out, E);
}

// Round 8
// 514.943 us; speedup vs baseline: 5.8056x; 1.2287x over previous
//
#include <hip/hip_runtime.h>

#define H 128
#define EF 32
#define TT 14
#define LH 32
#define KDIM 416   // 3H+EF
#define GOUT 512   // [r_pre, z_pre, i_n, h_n] each 128
#define KTOT 544   // 416 (agg) + 128 (memory)
#define KP 288     // pred GEMM K: 128 ms + 128 md + 32 h

typedef __attribute__((ext_vector_type(8))) short bf16x8;
typedef __attribute__((ext_vector_type(4))) float f32x4;

// native-HW nonlinearities: v_exp_f32 computes 2^x; v_rcp_f32 is ~1ulp.
// plain "1.0f/x" emits the full IEEE div sequence (~11 VALU ops) — 40 of
// those per LSTM wave-step was the round-7 bottleneck.
__device__ __forceinline__ float sigmoidf_(float x) {
  float e = __builtin_amdgcn_exp2f(x * -1.442695041f);   // exp(-x)
  return __builtin_amdgcn_rcpf(1.0f + e);
}
__device__ __forceinline__ float tanhfast_(float x) {
  float e = __builtin_amdgcn_exp2f(x * 2.885390082f);    // exp(2x)
  return 1.0f - 2.0f * __builtin_amdgcn_rcpf(e + 1.0f);
}
__device__ __forceinline__ ushort f2bf(float x) {
  uint u = __float_as_uint(x);
  u += 0x7fff + ((u >> 16) & 1);   // RTNE
  return (ushort)(u >> 16);
}

// ---------------- K1: build WcatT bf16 [512][544] (o-major) ----------------
__global__ __launch_bounds__(256) void build_weights(
    const float* __restrict__ Wih, const float* __restrict__ Whh,
    ushort* __restrict__ WcatT) {
  int i = blockIdx.x * 256 + threadIdx.x;
  if (i >= GOUT * KTOT) return;
  int o = i / KTOT, k = i % KTOT;
  int j = o & 127;
  float v = 0.f;
  if (o < 256) {  // r (o<128) and z (o<256): gi+gh fused
    int row = (o < 128) ? j : (128 + j);
    v = (k < KDIM) ? Wih[row * KDIM + k] : Whh[row * H + (k - KDIM)];
  } else if (o < 384) {  // i_n
    v = (k < KDIM) ? Wih[(256 + j) * KDIM + k] : 0.f;
  } else {               // h_n
    v = (k < KDIM) ? 0.f : Whh[(256 + j) * H + (k - KDIM)];
  }
  WcatT[i] = f2bf(v);
}

// ---------------- K1b: predictor algebra collapse (bf16 Wcombb [64][288]) ----------------
__global__ __launch_bounds__(256) void prep_pred(
    const float* __restrict__ W1, const float* __restrict__ b1,
    const float* __restrict__ static_W, const float* __restrict__ static_b,
    const float* __restrict__ price_W, const float* __restrict__ price_b,
    const float* __restrict__ party_emb, const float* __restrict__ state_emb,
    ushort* __restrict__ Wcombb, float* __restrict__ tab_p, float* __restrict__ tab_s,
    float* __restrict__ bias2) {
  __shared__ float G1[64][32];
  int tid = threadIdx.x;
  for (int idx = tid; idx < 2048; idx += 256) {
    int o = idx >> 5, k = idx & 31;
    float g = 0.f, m = 0.f;
    for (int j = 0; j < 128; j++) {
      g = fmaf(W1[o * 384 + j], static_W[j * 32 + k], g);
      m = fmaf(W1[o * 384 + 128 + j] + W1[o * 384 + 256 + j], price_W[j * 32 + k], m);
    }
    G1[o][k] = g;
    Wcombb[o * KP + 256 + k] = f2bf(m);
  }
  for (int idx = tid; idx < 64 * 256; idx += 256) {
    int o = idx >> 8, j = idx & 255;
    Wcombb[o * KP + j] = f2bf(W1[o * 384 + j]);
  }
  __syncthreads();
  for (int idx = tid; idx < 4 * 64; idx += 256) {
    int p = idx >> 6, o = idx & 63;
    float s = 0.f;
    for (int k = 0; k < 16; k++) s = fmaf(G1[o][k], party_emb[p * 16 + k], s);
    tab_p[idx] = s;
  }
  for (int idx = tid; idx < 50 * 64; idx += 256) {
    int si = idx >> 6, o = idx & 63;
    float s = 0.f;
    for (int k = 0; k < 16; k++) s = fmaf(G1[o][16 + k], state_emb[si * 16 + k], s);
    tab_s[idx] = s;
  }
  if (tid < 64) {
    float s = b1[tid];
    for (int j = 0; j < 128; j++) {
      s = fmaf(W1[tid * 384 + j], static_b[j], s);
      s = fmaf(W1[tid * 384 + 128 + j] + W1[tid * 384 + 256 + j], price_b[j], s);
    }
    bias2[tid] = s;
  }
}

// ---------------- K2a: degree count ----------------
__global__ void count_kernel(const int* __restrict__ src, const int* __restrict__ dst,
                             int* cnt, int E) {
  int e = blockIdx.x * blockDim.x + threadIdx.x;
  if (e < E) {
    atomicAdd(&cnt[dst[e]], 1);
    atomicAdd(&cnt[src[e]], 1);
  }
}

// ---------------- K2b: exclusive scan (single block) ----------------
__global__ __launch_bounds__(1024) void scan_kernel(const int* __restrict__ cnt,
                                                    int* __restrict__ offs,
                                                    int* __restrict__ cursor, int N) {
  __shared__ int part[1024];
  int tid = threadIdx.x;
  int chunk = (N + 1023) / 1024;
  int beg = tid * chunk;
  int end = min(beg + chunk, N);
  int s = 0;
  for (int i = beg; i < end; i++) s += cnt[i];
  part[tid] = s;
  __syncthreads();
  for (int d = 1; d < 1024; d <<= 1) {
    int v = (tid >= d) ? part[tid - d] : 0;
    __syncthreads();
    part[tid] += v;
    __syncthreads();
  }
  int run = (tid > 0) ? part[tid - 1] : 0;
  for (int i = beg; i < end; i++) {
    offs[i] = run;
    cursor[i] = run;
    run += cnt[i];
  }
  if (tid == 1023) offs[N] = part[1023];
}

// ---------------- K2c: CSR fill ----------------
__global__ void fill_kernel(const int* __restrict__ src, const int* __restrict__ dst,
                            int* cursor, int* __restrict__ other, int* __restrict__ eid, int E) {
  int e = blockIdx.x * blockDim.x + threadIdx.x;
  if (e >= E) return;
  int s = src[e], d = dst[e];
  int p1 = atomicAdd(&cursor[d], 1);
  other[p1] = s; eid[p1] = e;
  int p2 = atomicAdd(&cursor[s], 1);
  other[p2] = d; eid[p2] = e;
}

// ---------------- K2d: per-node aggregation -> agg_b bf16 [N][544] ----------------
__global__ __launch_bounds__(256) void agg_kernel(
    const int* __restrict__ offs, const int* __restrict__ other, const int* __restrict__ eid,
    const float* __restrict__ mem, const float* __restrict__ msg,
    const float* __restrict__ t, const float* __restrict__ lu,
    const float* __restrict__ tw, const float* __restrict__ tb,
    const int* __restrict__ cnt, ushort* __restrict__ agg_b, int N) {
  int v = blockIdx.x;
  int tid = threadIdx.x;
  int beg = offs[v], end = offs[v + 1];
  float lupd = lu[v];
  float w = 0.f, b = 0.f;
  if (tid >= 32 && tid < 160) { w = tw[tid - 32]; b = tb[tid - 32]; }
  float a0 = 0.f, a1 = 0.f;
  for (int p = beg; p < end; p++) {
    int u = other[p];
    int e = eid[p];
    if (tid < 128) a0 += mem[u * H + tid];
    if (tid < 32) a1 += msg[e * EF + tid];
    else if (tid < 160) a1 += __cosf(fmaf(t[e] - lupd, w, b));   // native v_cos
  }
  int cv = cnt[v];
  float inv = 1.f / (float)max(cv, 1);
  ushort* arow = agg_b + (size_t)v * KTOT;
  if (tid < 128) {
    arow[tid] = f2bf(a0 * inv);
  } else {
    float mv = mem[v * H + (tid - 128)];
    arow[tid] = f2bf((cv > 0) ? mv : 0.f);  // mean of cv copies of mem[v]
    arow[288 + tid] = f2bf(mv);             // cols 416..543: Whh operand
  }
  if (tid < 160) arow[256 + tid] = f2bf(a1 * inv);
}

// ---------------- K3: MFMA GEMM + fused GRU finalize -> mem_newb bf16 [N][128] ----------------
__global__ __launch_bounds__(256) void gru_gemm_mfma(
    const ushort* __restrict__ aggb, const ushort* __restrict__ WcatT,
    const float* __restrict__ mem, const int* __restrict__ cnt,
    const float* __restrict__ bih, const float* __restrict__ bhh,
    ushort* __restrict__ mem_newb, int N) {
  __shared__ union {
    ushort a[32 * 552];       // 35.3 KB
    float g[4][32][132];      // 67.6 KB
  } sm;
  int tid = threadIdx.x;
  int lane = tid & 63;
  int w = tid >> 6;
  int n0 = blockIdx.x * 32;

#pragma unroll
  for (int i = 0; i < 8; i++) {
    int row = w * 8 + i;
    int gr = min(n0 + row, N - 1);
    const uint4* srcp = reinterpret_cast<const uint4*>(aggb + (size_t)gr * KTOT);
    uint4* dstp = reinterpret_cast<uint4*>(sm.a + row * 552);
    dstp[lane] = srcp[lane];
    if (lane < 4) dstp[64 + lane] = srcp[64 + lane];
  }
  __syncthreads();

  f32x4 acc[2][8] = {};
  int arow_b = (lane & 15);
  int koff = (lane >> 4) * 8;
  for (int ks = 0; ks < 17; ks++) {
    int k = ks * 32 + koff;
    bf16x8 afr0 = *reinterpret_cast<const bf16x8*>(sm.a + (arow_b) * 552 + k);
    bf16x8 afr1 = *reinterpret_cast<const bf16x8*>(sm.a + (16 + arow_b) * 552 + k);
#pragma unroll
    for (int nt = 0; nt < 8; nt++) {
      int o = w * 128 + nt * 16 + (lane & 15);
      bf16x8 bfr = *reinterpret_cast<const bf16x8*>(WcatT + (size_t)o * KTOT + k);
      acc[0][nt] = __builtin_amdgcn_mfma_f32_16x16x32_bf16(afr0, bfr, acc[0][nt], 0, 0, 0);
      acc[1][nt] = __builtin_amdgcn_mfma_f32_16x16x32_bf16(afr1, bfr, acc[1][nt], 0, 0, 0);
    }
  }
  __syncthreads();  // A reads done; reuse LDS

#pragma unroll
  for (int mt = 0; mt < 2; mt++)
#pragma unroll
    for (int nt = 0; nt < 8; nt++)
#pragma unroll
      for (int r = 0; r < 4; r++)
        sm.g[w][mt * 16 + (lane >> 4) * 4 + r][nt * 16 + (lane & 15)] = acc[mt][nt][r];
  __syncthreads();

  int row = tid >> 3, j0 = (tid & 7) * 16;
  int n = n0 + row;
  if (n < N) {
    int cv = cnt[n];
#pragma unroll
    for (int jj = 0; jj < 16; jj++) {
      int j = j0 + jj;
      float m = mem[(size_t)n * H + j];
      float o;
      if (cv > 0) {
        float rp = sm.g[0][row][j] + bih[j] + bhh[j];
        float zp = sm.g[1][row][j] + bih[128 + j] + bhh[128 + j];
        float ip = sm.g[2][row][j] + bih[256 + j];
        float hp = sm.g[3][row][j] + bhh[256 + j];
        float r = sigmoidf_(rp), z = sigmoidf_(zp);
        float nn = tanhfast_(ip + r * hp);
        o = (1.f - z) * nn + z * m;
      } else {
        o = m;
      }
      mem_newb[(size_t)n * H + j] = f2bf(o);
    }
  }
}

// ---------------- K5a: price LSTM, MFMA-batched, extended-K, ROLLED t-loop ----------------
__global__ __launch_bounds__(256) void lstm_mfma_kernel(
    const float* __restrict__ price_seq,
    const float* __restrict__ lWih, const float* __restrict__ lWhh,
    const float* __restrict__ lbih, const float* __restrict__ lbhh,
    ushort* __restrict__ houtb, int E) {
  __shared__ float ps[64][15];  // block's 64 edges x 14 steps (pad 15)
  int tid = threadIdx.x;
  int lane = tid & 63;
  int el = lane & 15;
  int g = lane >> 4;
  int wv = tid >> 6;
  int row0 = blockIdx.x * 64;
  int el_local = wv * 16 + el;
  int e = row0 + el_local;
  bool valid = (e < E);

  // stage price rows
  for (int idx = tid; idx < 64 * TT; idx += 256) {
    int row = idx / TT, col = idx % TT;
    int ee = min(row0 + row, E - 1);
    ps[row][col] = price_seq[(size_t)ee * TT + col];
  }
  __syncthreads();

  // A fragments (h part): Whh[16b+el][g*8..g*8+7] in bf16
  union { uint u[4]; bf16x8 v; } afr[8];
#pragma unroll
  for (int b = 0; b < 8; b++) {
    const float* wr = lWhh + (16 * b + el) * LH + g * 8;
#pragma unroll
    for (int q = 0; q < 4; q++) {
      float lo = wr[2 * q], hi = wr[2 * q + 1];
      asm("v_cvt_pk_bf16_f32 %0, %1, %2" : "=v"(afr[b].u[q]) : "v"(lo), "v"(hi));
    }
  }
  // A2 fragments (x,1 part): k'=0 -> Wih[row], k'=1 -> bias[row]; only g==0 nonzero
  uint afr2w[8];
#pragma unroll
  for (int b = 0; b < 8; b++) {
    float wvv = lWih[16 * b + el];
    float bv = lbih[16 * b + el] + lbhh[16 * b + el];
    uint pk;
    asm("v_cvt_pk_bf16_f32 %0, %1, %2" : "=v"(pk) : "v"(wvv), "v"(bv));
    afr2w[b] = (g == 0) ? pk : 0u;
  }

  int addr_i[4];
#pragma unroll
  for (int i = 0; i < 4; i++) addr_i[i] = (el + 16 * ((g & 1) * 2 + (i >> 1))) << 2;
  bool hi_sel = (g >> 1) != 0;

  float cst[8];
#pragma unroll
  for (int i = 0; i < 8; i++) cst[i] = 0.f;
  uint hpk[4] = {0u, 0u, 0u, 0u};
  const f32x4 zero4 = {0.f, 0.f, 0.f, 0.f};

#pragma unroll 1
  for (int t = 0; t < TT; t++) {
    union { uint u[4]; bf16x8 v; } bfr;
#pragma unroll
    for (int i = 0; i < 4; i++) {
      uint lo = (uint)__builtin_amdgcn_ds_bpermute(addr_i[i], (int)hpk[i & 1]);
      uint hi = (uint)__builtin_amdgcn_ds_bpermute(addr_i[i], (int)hpk[2 + (i & 1)]);
      bfr.u[i] = hi_sel ? hi : lo;
    }
    float x = ps[el_local][t];
    union { uint u[4]; bf16x8 v; } bfr2;
    uint xp;
    asm("v_cvt_pk_bf16_f32 %0, %1, %2" : "=v"(xp) : "v"(x), "v"(1.0f));
    bfr2.u[0] = (g == 0) ? xp : 0u;
    bfr2.u[1] = 0u; bfr2.u[2] = 0u; bfr2.u[3] = 0u;

    float hval[8];
    f32x4 acc0, acc1, acc2, acc3, acc4, acc5, acc6, acc7;
#define STEPACC(b, A) \
    { union { uint u[4]; bf16x8 v; } a2; a2.u[0] = afr2w[b]; a2.u[1] = 0u; a2.u[2] = 0u; a2.u[3] = 0u; \
      A = __builtin_amdgcn_mfma_f32_16x16x32_bf16(a2.v, bfr2.v, zero4, 0, 0, 0); \
      A = __builtin_amdgcn_mfma_f32_16x16x32_bf16(afr[b].v, bfr.v, A, 0, 0, 0); }
    STEPACC(0, acc0) STEPACC(1, acc1) STEPACC(2, acc2) STEPACC(3, acc3)
    STEPACC(4, acc4) STEPACC(5, acc5) STEPACC(6, acc6) STEPACC(7, acc7)
#undef STEPACC
#define NONLIN(b1, AI, AF, AG, AO) \
    { _Pragma("unroll") for (int r = 0; r < 4; r++) { \
        int mi = 4 * b1 + r; \
        float ig = sigmoidf_(AI[r]); \
        float fg = sigmoidf_(AF[r]); \
        float gg = tanhfast_(AG[r]); \
        float og = sigmoidf_(AO[r]); \
        float cv = fmaf(fg, cst[mi], ig * gg); \
        cst[mi] = cv; \
        hval[mi] = og * tanhfast_(cv); } }
    NONLIN(0, acc0, acc2, acc4, acc6)
    NONLIN(1, acc1, acc3, acc5, acc7)
#undef NONLIN
#pragma unroll
    for (int i = 0; i < 4; i++)
      asm("v_cvt_pk_bf16_f32 %0, %1, %2" : "=v"(hpk[i]) : "v"(hval[2 * i]), "v"(hval[2 * i + 1]));
  }

  // hpk holds final h in bf16: hpk[0..1] -> m=4g..4g+3, hpk[2..3] -> m=16+4g..16+4g+3
  if (valid) {
    uint2* rowp = reinterpret_cast<uint2*>(houtb + (size_t)e * LH);
    rowp[g] = make_uint2(hpk[0], hpk[1]);
    rowp[4 + g] = make_uint2(hpk[2], hpk[3]);
  }
}

// ---------------- K5b: pred bf16 MFMA: out[E] from X[E][288] @ Wcombb^T ----------------
__global__ __launch_bounds__(256) void pred_mfma(
    const int* __restrict__ src, const int* __restrict__ dst,
    const int* __restrict__ x_static,
    const ushort* __restrict__ mem_newb, const ushort* __restrict__ houtb,
    const ushort* __restrict__ Wcombb, const float* __restrict__ tab_p,
    const float* __restrict__ tab_s, const float* __restrict__ bias2,
    const float* __restrict__ W2, const float* __restrict__ b2,
    float* __restrict__ out, int E) {
  __shared__ ushort Asm[64 * 296];
  __shared__ int pidx[64], stix[64];
  __shared__ int sidx[64], didx[64];
  int tid = threadIdx.x;
  int row0 = blockIdx.x * 64;
  if (tid < 64) {
    int e = min(row0 + tid, E - 1);
    int s = src[e], d = dst[e];
    sidx[tid] = s; didx[tid] = d;
    pidx[tid] = x_static[s * 2]; stix[tid] = x_static[s * 2 + 1];
  }
  __syncthreads();
  // stage A: 64 rows x 36 16B-chunks (16 ms + 16 md + 4 h)
#pragma unroll
  for (int i = 0; i < 9; i++) {
    int idx = tid + i * 256;
    int row = idx / 36, c = idx % 36;
    int e = min(row0 + row, E - 1);
    uint4 v;
    if (c < 16) v = reinterpret_cast<const uint4*>(mem_newb + (size_t)sidx[row] * H)[c];
    else if (c < 32) v = reinterpret_cast<const uint4*>(mem_newb + (size_t)didx[row] * H)[c - 16];
    else v = reinterpret_cast<const uint4*>(houtb + (size_t)e * LH)[c - 32];
    *reinterpret_cast<uint4*>(Asm + row * 296 + c * 8) = v;
  }
  __syncthreads();

  int lane = tid & 63;
  int w = tid >> 6;
  f32x4 acc[4] = {};
  int arow = w * 16 + (lane & 15);
  int koff = (lane >> 4) * 8;
  for (int ks = 0; ks < 9; ks++) {
    int k = ks * 32 + koff;
    bf16x8 afr = *reinterpret_cast<const bf16x8*>(Asm + arow * 296 + k);
#pragma unroll
    for (int nt = 0; nt < 4; nt++) {
      int o = nt * 16 + (lane & 15);
      bf16x8 bfr = *reinterpret_cast<const bf16x8*>(Wcombb + (size_t)o * KP + k);
      acc[nt] = __builtin_amdgcn_mfma_f32_16x16x32_bf16(afr, bfr, acc[nt], 0, 0, 0);
    }
  }
  // epilogue: lane holds D[edge=(lane>>4)*4+r][o=nt*16+(lane&15)]
  int ocol = lane & 15;
  float bb2 = b2[0];
#pragma unroll
  for (int r = 0; r < 4; r++) {
    int rl = w * 16 + (lane >> 4) * 4 + r;
    int p = pidx[rl], st = stix[rl];
    float s = 0.f;
#pragma unroll
    for (int nt = 0; nt < 4; nt++) {
      int o = nt * 16 + ocol;
      float hv = acc[nt][r] + bias2[o] + tab_p[p * 64 + o] + tab_s[st * 64 + o];
      s = fmaf(fmaxf(hv, 0.f), W2[o], s);
    }
#pragma unroll
    for (int d = 1; d < 16; d <<= 1) s += __shfl_xor(s, d);
    int e = row0 + rl;
    if (ocol == 0 && e < E) out[e] = s + bb2;
  }
}

// ---------------- launch ----------------
extern "C" void kernel_launch(void* const* d_in, const int* in_sizes, int n_in,
                              void* d_out, int out_size, void* d_ws, size_t ws_size,
                              hipStream_t stream) {
  const int* src = (const int*)d_in[0];
  const int* dst = (const int*)d_in[1];
  const float* t = (const float*)d_in[2];
  const float* msg = (const float*)d_in[3];
  const float* price_seq = (const float*)d_in[4];
  const int* x_static = (const int*)d_in[6];
  const float* memory = (const float*)d_in[7];
  const float* last_update = (const float*)d_in[8];
  const float* time_w = (const float*)d_in[9];
  const float* time_b = (const float*)d_in[10];
  const float* gWih = (const float*)d_in[11];
  const float* gWhh = (const float*)d_in[12];
  const float* gbih = (const float*)d_in[13];
  const float* gbhh = (const float*)d_in[14];
  const float* party_emb = (const float*)d_in[15];
  const float* state_emb = (const float*)d_in[16];
  const float* static_W = (const float*)d_in[17];
  const float* static_b = (const float*)d_in[18];
  const float* lWih = (const float*)d_in[19];
  const float* lWhh = (const float*)d_in[20];
  const float* lbih = (const float*)d_in[21];
  const float* lbhh = (const float*)d_in[22];
  const float* price_W = (const float*)d_in[23];
  const float* price_b = (const float*)d_in[24];
  const float* W1 = (const float*)d_in[25];
  const float* b1 = (const float*)d_in[26];
  const float* W2 = (const float*)d_in[27];
  const float* b2 = (const float*)d_in[28];
  float* out = (float*)d_out;

  const int E = in_sizes[0];
  const int N = in_sizes[8];

  char* ws = (char*)d_ws;
  size_t off = 0;
  auto alloc = [&](size_t bytes) { size_t o = off; off += (bytes + 255) & ~(size_t)255; return o; };
  int* cnt       = (int*)(ws + alloc((size_t)N * 4));
  int* offs      = (int*)(ws + alloc((size_t)(N + 1) * 4));
  int* cursor    = (int*)(ws + alloc((size_t)N * 4));
  int* other     = (int*)(ws + alloc((size_t)2 * E * 4));
  int* eid       = (int*)(ws + alloc((size_t)2 * E * 4));
  ushort* WcatT  = (ushort*)(ws + alloc((size_t)GOUT * KTOT * 2));
  ushort* Wcombb = (ushort*)(ws + alloc((size_t)64 * KP * 2));
  float* tab_p   = (float*)(ws + alloc((size_t)4 * 64 * 4));
  float* tab_s   = (float*)(ws + alloc((size_t)50 * 64 * 4));
  float* bias2   = (float*)(ws + alloc((size_t)64 * 4));
  ushort* agg_b  = (ushort*)(ws + alloc((size_t)N * KTOT * 2));
  ushort* mem_newb = (ushort*)(ws + alloc((size_t)N * H * 2));
  ushort* houtb  = (ushort*)(ws + alloc((size_t)E * LH * 2));
  (void)ws_size;

  hipMemsetAsync(cnt, 0, (size_t)N * 4, stream);

  build_weights<<<(GOUT * KTOT + 255) / 256, 256, 0, stream>>>(gWih, gWhh, WcatT);
  prep_pred<<<1, 256, 0, stream>>>(W1, b1, static_W, static_b, price_W, price_b,
                                   party_emb, state_emb, Wcombb, tab_p, tab_s, bias2);
  count_kernel<<<(E + 255) / 256, 256, 0, stream>>>(src, dst, cnt, E);
  scan_kernel<<<1, 1024, 0, stream>>>(cnt, offs, cursor, N);
  fill_kernel<<<(E + 255) / 256, 256, 0, stream>>>(src, dst, cursor, other, eid, E);
  agg_kernel<<<N, 256, 0, stream>>>(offs, other, eid, memory, msg, t, last_update,
                                    time_w, time_b, cnt, agg_b, N);
  gru_gemm_mfma<<<(N + 31) / 32, 256, 0, stream>>>(agg_b, WcatT, memory, cnt,
                                                   gbih, gbhh, mem_newb, N);
  lstm_mfma_kernel<<<(E + 63) / 64, 256, 0, stream>>>(price_seq, lWih, lWhh, lbih, lbhh, houtb, E);
  pred_mfma<<<(E + 63) / 64, 256, 0, stream>>>(src, dst, x_static, mem_newb, houtb,
      Wcombb, tab_p, tab_s, bias2, W2, b2, out, E);
}

// Round 9
// 512.809 us; speedup vs baseline: 5.8298x; 1.0042x over previous
//
#include <hip/hip_runtime.h>

#define H 128
#define EF 32
#define TT 14
#define LH 32
#define KDIM 416   // 3H+EF
#define GOUT 512   // [r_pre, z_pre, i_n, h_n] each 128
#define KTOT 544   // 416 (agg) + 128 (memory)
#define KP 288     // pred GEMM K: 128 ms + 128 md + 32 h

typedef __attribute__((ext_vector_type(8))) short bf16x8;
typedef __attribute__((ext_vector_type(4))) float f32x4;

// native-HW nonlinearities: v_exp_f32 computes 2^x; v_rcp_f32 is ~1ulp.
__device__ __forceinline__ float sigmoidf_(float x) {
  float e = __builtin_amdgcn_exp2f(x * -1.442695041f);   // exp(-x)
  return __builtin_amdgcn_rcpf(1.0f + e);
}
__device__ __forceinline__ float tanhfast_(float x) {
  float e = __builtin_amdgcn_exp2f(x * 2.885390082f);    // exp(2x)
  return 1.0f - 2.0f * __builtin_amdgcn_rcpf(e + 1.0f);
}
__device__ __forceinline__ ushort f2bf(float x) {
  uint u = __float_as_uint(x);
  u += 0x7fff + ((u >> 16) & 1);   // RTNE
  return (ushort)(u >> 16);
}

// ---------------- K1: build WcatT bf16 [512][544] (o-major) ----------------
__global__ __launch_bounds__(256) void build_weights(
    const float* __restrict__ Wih, const float* __restrict__ Whh,
    ushort* __restrict__ WcatT) {
  int i = blockIdx.x * 256 + threadIdx.x;
  if (i >= GOUT * KTOT) return;
  int o = i / KTOT, k = i % KTOT;
  int j = o & 127;
  float v = 0.f;
  if (o < 256) {  // r (o<128) and z (o<256): gi+gh fused
    int row = (o < 128) ? j : (128 + j);
    v = (k < KDIM) ? Wih[row * KDIM + k] : Whh[row * H + (k - KDIM)];
  } else if (o < 384) {  // i_n
    v = (k < KDIM) ? Wih[(256 + j) * KDIM + k] : 0.f;
  } else {               // h_n
    v = (k < KDIM) ? 0.f : Whh[(256 + j) * H + (k - KDIM)];
  }
  WcatT[i] = f2bf(v);
}

// ---------------- K1b: predictor algebra collapse (bf16 Wcombb [64][288]) ----------------
__global__ __launch_bounds__(256) void prep_pred(
    const float* __restrict__ W1, const float* __restrict__ b1,
    const float* __restrict__ static_W, const float* __restrict__ static_b,
    const float* __restrict__ price_W, const float* __restrict__ price_b,
    const float* __restrict__ party_emb, const float* __restrict__ state_emb,
    ushort* __restrict__ Wcombb, float* __restrict__ tab_p, float* __restrict__ tab_s,
    float* __restrict__ bias2) {
  __shared__ float G1[64][32];
  int tid = threadIdx.x;
  for (int idx = tid; idx < 2048; idx += 256) {
    int o = idx >> 5, k = idx & 31;
    float g = 0.f, m = 0.f;
    for (int j = 0; j < 128; j++) {
      g = fmaf(W1[o * 384 + j], static_W[j * 32 + k], g);
      m = fmaf(W1[o * 384 + 128 + j] + W1[o * 384 + 256 + j], price_W[j * 32 + k], m);
    }
    G1[o][k] = g;
    Wcombb[o * KP + 256 + k] = f2bf(m);
  }
  for (int idx = tid; idx < 64 * 256; idx += 256) {
    int o = idx >> 8, j = idx & 255;
    Wcombb[o * KP + j] = f2bf(W1[o * 384 + j]);
  }
  __syncthreads();
  for (int idx = tid; idx < 4 * 64; idx += 256) {
    int p = idx >> 6, o = idx & 63;
    float s = 0.f;
    for (int k = 0; k < 16; k++) s = fmaf(G1[o][k], party_emb[p * 16 + k], s);
    tab_p[idx] = s;
  }
  for (int idx = tid; idx < 50 * 64; idx += 256) {
    int si = idx >> 6, o = idx & 63;
    float s = 0.f;
    for (int k = 0; k < 16; k++) s = fmaf(G1[o][16 + k], state_emb[si * 16 + k], s);
    tab_s[idx] = s;
  }
  if (tid < 64) {
    float s = b1[tid];
    for (int j = 0; j < 128; j++) {
      s = fmaf(W1[tid * 384 + j], static_b[j], s);
      s = fmaf(W1[tid * 384 + 128 + j] + W1[tid * 384 + 256 + j], price_b[j], s);
    }
    bias2[tid] = s;
  }
}

// ---------------- K2a: degree count ----------------
__global__ void count_kernel(const int* __restrict__ src, const int* __restrict__ dst,
                             int* cnt, int E) {
  int e = blockIdx.x * blockDim.x + threadIdx.x;
  if (e < E) {
    atomicAdd(&cnt[dst[e]], 1);
    atomicAdd(&cnt[src[e]], 1);
  }
}

// ---------------- K2b: exclusive scan (single block) ----------------
__global__ __launch_bounds__(1024) void scan_kernel(const int* __restrict__ cnt,
                                                    int* __restrict__ offs,
                                                    int* __restrict__ cursor, int N) {
  __shared__ int part[1024];
  int tid = threadIdx.x;
  int chunk = (N + 1023) / 1024;
  int beg = tid * chunk;
  int end = min(beg + chunk, N);
  int s = 0;
  for (int i = beg; i < end; i++) s += cnt[i];
  part[tid] = s;
  __syncthreads();
  for (int d = 1; d < 1024; d <<= 1) {
    int v = (tid >= d) ? part[tid - d] : 0;
    __syncthreads();
    part[tid] += v;
    __syncthreads();
  }
  int run = (tid > 0) ? part[tid - 1] : 0;
  for (int i = beg; i < end; i++) {
    offs[i] = run;
    cursor[i] = run;
    run += cnt[i];
  }
  if (tid == 1023) offs[N] = part[1023];
}

// ---------------- K2c: CSR fill ----------------
__global__ void fill_kernel(const int* __restrict__ src, const int* __restrict__ dst,
                            int* cursor, int* __restrict__ other, int* __restrict__ eid, int E) {
  int e = blockIdx.x * blockDim.x + threadIdx.x;
  if (e >= E) return;
  int s = src[e], d = dst[e];
  int p1 = atomicAdd(&cursor[d], 1);
  other[p1] = s; eid[p1] = e;
  int p2 = atomicAdd(&cursor[s], 1);
  other[p2] = d; eid[p2] = e;
}

// ---------------- K2d: per-node aggregation -> agg_b bf16 [N][544] ----------------
// 512 threads = 4 groups x 128 lanes; group g handles entries beg+g, beg+g+4, ...
// 4 gather chains in flight per block (round-8 version was 1 -> latency-bound).
__global__ __launch_bounds__(512) void agg_kernel(
    const int* __restrict__ offs, const int* __restrict__ other, const int* __restrict__ eid,
    const float* __restrict__ mem, const float* __restrict__ msg,
    const float* __restrict__ t, const float* __restrict__ lu,
    const float* __restrict__ tw, const float* __restrict__ tb,
    const int* __restrict__ cnt, ushort* __restrict__ agg_b, int N) {
  __shared__ float red[3 * 288];   // groups 1..3 partials: a0[128], acos[128], amsg[32]
  int tid = threadIdx.x;
  int grp = tid >> 7;
  int l = tid & 127;
  int v = blockIdx.x;
  int beg = offs[v], end = offs[v + 1];
  float lupd = lu[v];
  float w = tw[l], b = tb[l];
  float a0 = 0.f, amsg = 0.f, acos = 0.f;
  for (int p = beg + grp; p < end; p += 4) {
    int u = other[p];
    int e = eid[p];
    a0 += mem[u * H + l];
    if (l < 32) amsg += msg[e * EF + l];
    acos += __cosf(fmaf(t[e] - lupd, w, b));
  }
  if (grp > 0) {
    float* r = red + (grp - 1) * 288;
    r[l] = a0;
    r[128 + l] = acos;
    if (l < 32) r[256 + l] = amsg;
  }
  __syncthreads();
  if (grp == 0) {
#pragma unroll
    for (int g2 = 0; g2 < 3; g2++) {
      const float* r = red + g2 * 288;
      a0 += r[l];
      acos += r[128 + l];
      if (l < 32) amsg += r[256 + l];
    }
    int cv = cnt[v];
    float inv = 1.f / (float)max(cv, 1);
    ushort* arow = agg_b + (size_t)v * KTOT;
    float mv = mem[v * H + l];
    arow[l] = f2bf(a0 * inv);
    arow[128 + l] = f2bf((cv > 0) ? mv : 0.f);  // mean of cv copies of mem[v]
    arow[288 + l] = f2bf(acos * inv);
    arow[416 + l] = f2bf(mv);                   // Whh operand
    if (l < 32) arow[256 + l] = f2bf(amsg * inv);
  }
}

// ---------------- K3: MFMA GEMM + fused GRU finalize -> mem_newb bf16 [N][128] ----------------
__global__ __launch_bounds__(256) void gru_gemm_mfma(
    const ushort* __restrict__ aggb, const ushort* __restrict__ WcatT,
    const float* __restrict__ mem, const int* __restrict__ cnt,
    const float* __restrict__ bih, const float* __restrict__ bhh,
    ushort* __restrict__ mem_newb, int N) {
  __shared__ union {
    ushort a[32 * 552];       // 35.3 KB
    float g[4][32][132];      // 67.6 KB
  } sm;
  int tid = threadIdx.x;
  int lane = tid & 63;
  int w = tid >> 6;
  int n0 = blockIdx.x * 32;

#pragma unroll
  for (int i = 0; i < 8; i++) {
    int row = w * 8 + i;
    int gr = min(n0 + row, N - 1);
    const uint4* srcp = reinterpret_cast<const uint4*>(aggb + (size_t)gr * KTOT);
    uint4* dstp = reinterpret_cast<uint4*>(sm.a + row * 552);
    dstp[lane] = srcp[lane];
    if (lane < 4) dstp[64 + lane] = srcp[64 + lane];
  }
  __syncthreads();

  f32x4 acc[2][8] = {};
  int arow_b = (lane & 15);
  int koff = (lane >> 4) * 8;
  for (int ks = 0; ks < 17; ks++) {
    int k = ks * 32 + koff;
    bf16x8 afr0 = *reinterpret_cast<const bf16x8*>(sm.a + (arow_b) * 552 + k);
    bf16x8 afr1 = *reinterpret_cast<const bf16x8*>(sm.a + (16 + arow_b) * 552 + k);
#pragma unroll
    for (int nt = 0; nt < 8; nt++) {
      int o = w * 128 + nt * 16 + (lane & 15);
      bf16x8 bfr = *reinterpret_cast<const bf16x8*>(WcatT + (size_t)o * KTOT + k);
      acc[0][nt] = __builtin_amdgcn_mfma_f32_16x16x32_bf16(afr0, bfr, acc[0][nt], 0, 0, 0);
      acc[1][nt] = __builtin_amdgcn_mfma_f32_16x16x32_bf16(afr1, bfr, acc[1][nt], 0, 0, 0);
    }
  }
  __syncthreads();  // A reads done; reuse LDS

#pragma unroll
  for (int mt = 0; mt < 2; mt++)
#pragma unroll
    for (int nt = 0; nt < 8; nt++)
#pragma unroll
      for (int r = 0; r < 4; r++)
        sm.g[w][mt * 16 + (lane >> 4) * 4 + r][nt * 16 + (lane & 15)] = acc[mt][nt][r];
  __syncthreads();

  int row = tid >> 3, j0 = (tid & 7) * 16;
  int n = n0 + row;
  if (n < N) {
    int cv = cnt[n];
#pragma unroll
    for (int jj = 0; jj < 16; jj++) {
      int j = j0 + jj;
      float m = mem[(size_t)n * H + j];
      float o;
      if (cv > 0) {
        float rp = sm.g[0][row][j] + bih[j] + bhh[j];
        float zp = sm.g[1][row][j] + bih[128 + j] + bhh[128 + j];
        float ip = sm.g[2][row][j] + bih[256 + j];
        float hp = sm.g[3][row][j] + bhh[256 + j];
        float r = sigmoidf_(rp), z = sigmoidf_(zp);
        float nn = tanhfast_(ip + r * hp);
        o = (1.f - z) * nn + z * m;
      } else {
        o = m;
      }
      mem_newb[(size_t)n * H + j] = f2bf(o);
    }
  }
}

// ---------------- K5a: price LSTM, MFMA-batched, extended-K, ROLLED t-loop ----------------
__global__ __launch_bounds__(256) void lstm_mfma_kernel(
    const float* __restrict__ price_seq,
    const float* __restrict__ lWih, const float* __restrict__ lWhh,
    const float* __restrict__ lbih, const float* __restrict__ lbhh,
    ushort* __restrict__ houtb, int E) {
  __shared__ float ps[64][15];  // block's 64 edges x 14 steps (pad 15)
  int tid = threadIdx.x;
  int lane = tid & 63;
  int el = lane & 15;
  int g = lane >> 4;
  int wv = tid >> 6;
  int row0 = blockIdx.x * 64;
  int el_local = wv * 16 + el;
  int e = row0 + el_local;
  bool valid = (e < E);

  // stage price rows
  for (int idx = tid; idx < 64 * TT; idx += 256) {
    int row = idx / TT, col = idx % TT;
    int ee = min(row0 + row, E - 1);
    ps[row][col] = price_seq[(size_t)ee * TT + col];
  }
  __syncthreads();

  // A fragments (h part): Whh[16b+el][g*8..g*8+7] in bf16
  union { uint u[4]; bf16x8 v; } afr[8];
#pragma unroll
  for (int b = 0; b < 8; b++) {
    const float* wr = lWhh + (16 * b + el) * LH + g * 8;
#pragma unroll
    for (int q = 0; q < 4; q++) {
      float lo = wr[2 * q], hi = wr[2 * q + 1];
      asm("v_cvt_pk_bf16_f32 %0, %1, %2" : "=v"(afr[b].u[q]) : "v"(lo), "v"(hi));
    }
  }
  // A2 fragments (x,1 part): k'=0 -> Wih[row], k'=1 -> bias[row]; only g==0 nonzero
  uint afr2w[8];
#pragma unroll
  for (int b = 0; b < 8; b++) {
    float wvv = lWih[16 * b + el];
    float bv = lbih[16 * b + el] + lbhh[16 * b + el];
    uint pk;
    asm("v_cvt_pk_bf16_f32 %0, %1, %2" : "=v"(pk) : "v"(wvv), "v"(bv));
    afr2w[b] = (g == 0) ? pk : 0u;
  }

  int addr_i[4];
#pragma unroll
  for (int i = 0; i < 4; i++) addr_i[i] = (el + 16 * ((g & 1) * 2 + (i >> 1))) << 2;
  bool hi_sel = (g >> 1) != 0;

  float cst[8];
#pragma unroll
  for (int i = 0; i < 8; i++) cst[i] = 0.f;
  uint hpk[4] = {0u, 0u, 0u, 0u};
  const f32x4 zero4 = {0.f, 0.f, 0.f, 0.f};

#pragma unroll 1
  for (int t = 0; t < TT; t++) {
    union { uint u[4]; bf16x8 v; } bfr;
#pragma unroll
    for (int i = 0; i < 4; i++) {
      uint lo = (uint)__builtin_amdgcn_ds_bpermute(addr_i[i], (int)hpk[i & 1]);
      uint hi = (uint)__builtin_amdgcn_ds_bpermute(addr_i[i], (int)hpk[2 + (i & 1)]);
      bfr.u[i] = hi_sel ? hi : lo;
    }
    float x = ps[el_local][t];
    union { uint u[4]; bf16x8 v; } bfr2;
    uint xp;
    asm("v_cvt_pk_bf16_f32 %0, %1, %2" : "=v"(xp) : "v"(x), "v"(1.0f));
    bfr2.u[0] = (g == 0) ? xp : 0u;
    bfr2.u[1] = 0u; bfr2.u[2] = 0u; bfr2.u[3] = 0u;

    float hval[8];
    f32x4 acc0, acc1, acc2, acc3, acc4, acc5, acc6, acc7;
#define STEPACC(b, A) \
    { union { uint u[4]; bf16x8 v; } a2; a2.u[0] = afr2w[b]; a2.u[1] = 0u; a2.u[2] = 0u; a2.u[3] = 0u; \
      A = __builtin_amdgcn_mfma_f32_16x16x32_bf16(a2.v, bfr2.v, zero4, 0, 0, 0); \
      A = __builtin_amdgcn_mfma_f32_16x16x32_bf16(afr[b].v, bfr.v, A, 0, 0, 0); }
    STEPACC(0, acc0) STEPACC(1, acc1) STEPACC(2, acc2) STEPACC(3, acc3)
    STEPACC(4, acc4) STEPACC(5, acc5) STEPACC(6, acc6) STEPACC(7, acc7)
#undef STEPACC
#define NONLIN(b1, AI, AF, AG, AO) \
    { _Pragma("unroll") for (int r = 0; r < 4; r++) { \
        int mi = 4 * b1 + r; \
        float ig = sigmoidf_(AI[r]); \
        float fg = sigmoidf_(AF[r]); \
        float gg = tanhfast_(AG[r]); \
        float og = sigmoidf_(AO[r]); \
        float cv = fmaf(fg, cst[mi], ig * gg); \
        cst[mi] = cv; \
        hval[mi] = og * tanhfast_(cv); } }
    NONLIN(0, acc0, acc2, acc4, acc6)
    NONLIN(1, acc1, acc3, acc5, acc7)
#undef NONLIN
#pragma unroll
    for (int i = 0; i < 4; i++)
      asm("v_cvt_pk_bf16_f32 %0, %1, %2" : "=v"(hpk[i]) : "v"(hval[2 * i]), "v"(hval[2 * i + 1]));
  }

  // hpk holds final h in bf16: hpk[0..1] -> m=4g..4g+3, hpk[2..3] -> m=16+4g..16+4g+3
  if (valid) {
    uint2* rowp = reinterpret_cast<uint2*>(houtb + (size_t)e * LH);
    rowp[g] = make_uint2(hpk[0], hpk[1]);
    rowp[4 + g] = make_uint2(hpk[2], hpk[3]);
  }
}

// ---------------- K5b: pred bf16 MFMA: out[E] from X[E][288] @ Wcombb^T ----------------
__global__ __launch_bounds__(256) void pred_mfma(
    const int* __restrict__ src, const int* __restrict__ dst,
    const int* __restrict__ x_static,
    const ushort* __restrict__ mem_newb, const ushort* __restrict__ houtb,
    const ushort* __restrict__ Wcombb, const float* __restrict__ tab_p,
    const float* __restrict__ tab_s, const float* __restrict__ bias2,
    const float* __restrict__ W2, const float* __restrict__ b2,
    float* __restrict__ out, int E) {
  __shared__ ushort Asm[64 * 296];
  __shared__ int pidx[64], stix[64];
  __shared__ int sidx[64], didx[64];
  int tid = threadIdx.x;
  int row0 = blockIdx.x * 64;
  if (tid < 64) {
    int e = min(row0 + tid, E - 1);
    int s = src[e], d = dst[e];
    sidx[tid] = s; didx[tid] = d;
    pidx[tid] = x_static[s * 2]; stix[tid] = x_static[s * 2 + 1];
  }
  __syncthreads();
  // stage A: 64 rows x 36 16B-chunks (16 ms + 16 md + 4 h)
#pragma unroll
  for (int i = 0; i < 9; i++) {
    int idx = tid + i * 256;
    int row = idx / 36, c = idx % 36;
    int e = min(row0 + row, E - 1);
    uint4 v;
    if (c < 16) v = reinterpret_cast<const uint4*>(mem_newb + (size_t)sidx[row] * H)[c];
    else if (c < 32) v = reinterpret_cast<const uint4*>(mem_newb + (size_t)didx[row] * H)[c - 16];
    else v = reinterpret_cast<const uint4*>(houtb + (size_t)e * LH)[c - 32];
    *reinterpret_cast<uint4*>(Asm + row * 296 + c * 8) = v;
  }
  __syncthreads();

  int lane = tid & 63;
  int w = tid >> 6;
  f32x4 acc[4] = {};
  int arow = w * 16 + (lane & 15);
  int koff = (lane >> 4) * 8;
  for (int ks = 0; ks < 9; ks++) {
    int k = ks * 32 + koff;
    bf16x8 afr = *reinterpret_cast<const bf16x8*>(Asm + arow * 296 + k);
#pragma unroll
    for (int nt = 0; nt < 4; nt++) {
      int o = nt * 16 + (lane & 15);
      bf16x8 bfr = *reinterpret_cast<const bf16x8*>(Wcombb + (size_t)o * KP + k);
      acc[nt] = __builtin_amdgcn_mfma_f32_16x16x32_bf16(afr, bfr, acc[nt], 0, 0, 0);
    }
  }
  // epilogue: lane holds D[edge=(lane>>4)*4+r][o=nt*16+(lane&15)]
  int ocol = lane & 15;
  float bb2 = b2[0];
#pragma unroll
  for (int r = 0; r < 4; r++) {
    int rl = w * 16 + (lane >> 4) * 4 + r;
    int p = pidx[rl], st = stix[rl];
    float s = 0.f;
#pragma unroll
    for (int nt = 0; nt < 4; nt++) {
      int o = nt * 16 + ocol;
      float hv = acc[nt][r] + bias2[o] + tab_p[p * 64 + o] + tab_s[st * 64 + o];
      s = fmaf(fmaxf(hv, 0.f), W2[o], s);
    }
#pragma unroll
    for (int d = 1; d < 16; d <<= 1) s += __shfl_xor(s, d);
    int e = row0 + rl;
    if (ocol == 0 && e < E) out[e] = s + bb2;
  }
}

// ---------------- launch ----------------
extern "C" void kernel_launch(void* const* d_in, const int* in_sizes, int n_in,
                              void* d_out, int out_size, void* d_ws, size_t ws_size,
                              hipStream_t stream) {
  const int* src = (const int*)d_in[0];
  const int* dst = (const int*)d_in[1];
  const float* t = (const float*)d_in[2];
  const float* msg = (const float*)d_in[3];
  const float* price_seq = (const float*)d_in[4];
  const int* x_static = (const int*)d_in[6];
  const float* memory = (const float*)d_in[7];
  const float* last_update = (const float*)d_in[8];
  const float* time_w = (const float*)d_in[9];
  const float* time_b = (const float*)d_in[10];
  const float* gWih = (const float*)d_in[11];
  const float* gWhh = (const float*)d_in[12];
  const float* gbih = (const float*)d_in[13];
  const float* gbhh = (const float*)d_in[14];
  const float* party_emb = (const float*)d_in[15];
  const float* state_emb = (const float*)d_in[16];
  const float* static_W = (const float*)d_in[17];
  const float* static_b = (const float*)d_in[18];
  const float* lWih = (const float*)d_in[19];
  const float* lWhh = (const float*)d_in[20];
  const float* lbih = (const float*)d_in[21];
  const float* lbhh = (const float*)d_in[22];
  const float* price_W = (const float*)d_in[23];
  const float* price_b = (const float*)d_in[24];
  const float* W1 = (const float*)d_in[25];
  const float* b1 = (const float*)d_in[26];
  const float* W2 = (const float*)d_in[27];
  const float* b2 = (const float*)d_in[28];
  float* out = (float*)d_out;

  const int E = in_sizes[0];
  const int N = in_sizes[8];

  char* ws = (char*)d_ws;
  size_t off = 0;
  auto alloc = [&](size_t bytes) { size_t o = off; off += (bytes + 255) & ~(size_t)255; return o; };
  int* cnt       = (int*)(ws + alloc((size_t)N * 4));
  int* offs      = (int*)(ws + alloc((size_t)(N + 1) * 4));
  int* cursor    = (int*)(ws + alloc((size_t)N * 4));
  int* other     = (int*)(ws + alloc((size_t)2 * E * 4));
  int* eid       = (int*)(ws + alloc((size_t)2 * E * 4));
  ushort* WcatT  = (ushort*)(ws + alloc((size_t)GOUT * KTOT * 2));
  ushort* Wcombb = (ushort*)(ws + alloc((size_t)64 * KP * 2));
  float* tab_p   = (float*)(ws + alloc((size_t)4 * 64 * 4));
  float* tab_s   = (float*)(ws + alloc((size_t)50 * 64 * 4));
  float* bias2   = (float*)(ws + alloc((size_t)64 * 4));
  ushort* agg_b  = (ushort*)(ws + alloc((size_t)N * KTOT * 2));
  ushort* mem_newb = (ushort*)(ws + alloc((size_t)N * H * 2));
  ushort* houtb  = (ushort*)(ws + alloc((size_t)E * LH * 2));
  (void)ws_size;

  hipMemsetAsync(cnt, 0, (size_t)N * 4, stream);

  build_weights<<<(GOUT * KTOT + 255) / 256, 256, 0, stream>>>(gWih, gWhh, WcatT);
  prep_pred<<<1, 256, 0, stream>>>(W1, b1, static_W, static_b, price_W, price_b,
                                   party_emb, state_emb, Wcombb, tab_p, tab_s, bias2);
  count_kernel<<<(E + 255) / 256, 256, 0, stream>>>(src, dst, cnt, E);
  scan_kernel<<<1, 1024, 0, stream>>>(cnt, offs, cursor, N);
  fill_kernel<<<(E + 255) / 256, 256, 0, stream>>>(src, dst, cursor, other, eid, E);
  agg_kernel<<<N, 512, 0, stream>>>(offs, other, eid, memory, msg, t, last_update,
                                    time_w, time_b, cnt, agg_b, N);
  gru_gemm_mfma<<<(N + 31) / 32, 256, 0, stream>>>(agg_b, WcatT, memory, cnt,
                                                   gbih, gbhh, mem_newb, N);
  lstm_mfma_kernel<<<(E + 63) / 64, 256, 0, stream>>>(price_seq, lWih, lWhh, lbih, lbhh, houtb, E);
  pred_mfma<<<(E + 63) / 64, 256, 0, stream>>>(src, dst, x_static, mem_newb, houtb,
      Wcombb, tab_p, tab_s, bias2, W2, b2, out, E);
}

// Round 10
// 445.921 us; speedup vs baseline: 6.7043x; 1.1500x over previous
//
#include <hip/hip_runtime.h>

#define H 128
#define EF 32
#define TT 14
#define LH 32
#define KDIM 416   // 3H+EF
#define GOUT 512   // [r_pre, z_pre, i_n, h_n] each 128
#define KTOT 544   // 416 (agg) + 128 (memory)
#define KP 288     // pred GEMM K: 128 ms + 128 md + 32 h

typedef __attribute__((ext_vector_type(8))) short bf16x8;
typedef __attribute__((ext_vector_type(4))) float f32x4;

// native-HW nonlinearities: v_exp_f32 computes 2^x; v_rcp_f32 is ~1ulp.
__device__ __forceinline__ float sigmoidf_(float x) {
  float e = __builtin_amdgcn_exp2f(x * -1.442695041f);   // exp(-x)
  return __builtin_amdgcn_rcpf(1.0f + e);
}
__device__ __forceinline__ float tanhfast_(float x) {
  float e = __builtin_amdgcn_exp2f(x * 2.885390082f);    // exp(2x)
  return 1.0f - 2.0f * __builtin_amdgcn_rcpf(e + 1.0f);
}
__device__ __forceinline__ ushort f2bf(float x) {
  uint u = __float_as_uint(x);
  u += 0x7fff + ((u >> 16) & 1);   // RTNE
  return (ushort)(u >> 16);
}

// ---------------- K1: build WcatT bf16 [512][544] (o-major) ----------------
__global__ __launch_bounds__(256) void build_weights(
    const float* __restrict__ Wih, const float* __restrict__ Whh,
    ushort* __restrict__ WcatT) {
  int i = blockIdx.x * 256 + threadIdx.x;
  if (i >= GOUT * KTOT) return;
  int o = i / KTOT, k = i % KTOT;
  int j = o & 127;
  float v = 0.f;
  if (o < 256) {  // r (o<128) and z (o<256): gi+gh fused
    int row = (o < 128) ? j : (128 + j);
    v = (k < KDIM) ? Wih[row * KDIM + k] : Whh[row * H + (k - KDIM)];
  } else if (o < 384) {  // i_n
    v = (k < KDIM) ? Wih[(256 + j) * KDIM + k] : 0.f;
  } else {               // h_n
    v = (k < KDIM) ? 0.f : Whh[(256 + j) * H + (k - KDIM)];
  }
  WcatT[i] = f2bf(v);
}

// ---------------- K1b: predictor algebra collapse (bf16 Wcombb [64][288]) ----------------
__global__ __launch_bounds__(256) void prep_pred(
    const float* __restrict__ W1, const float* __restrict__ b1,
    const float* __restrict__ static_W, const float* __restrict__ static_b,
    const float* __restrict__ price_W, const float* __restrict__ price_b,
    const float* __restrict__ party_emb, const float* __restrict__ state_emb,
    ushort* __restrict__ Wcombb, float* __restrict__ tab_p, float* __restrict__ tab_s,
    float* __restrict__ bias2) {
  __shared__ float G1[64][32];
  int tid = threadIdx.x;
  for (int idx = tid; idx < 2048; idx += 256) {
    int o = idx >> 5, k = idx & 31;
    float g = 0.f, m = 0.f;
    for (int j = 0; j < 128; j++) {
      g = fmaf(W1[o * 384 + j], static_W[j * 32 + k], g);
      m = fmaf(W1[o * 384 + 128 + j] + W1[o * 384 + 256 + j], price_W[j * 32 + k], m);
    }
    G1[o][k] = g;
    Wcombb[o * KP + 256 + k] = f2bf(m);
  }
  for (int idx = tid; idx < 64 * 256; idx += 256) {
    int o = idx >> 8, j = idx & 255;
    Wcombb[o * KP + j] = f2bf(W1[o * 384 + j]);
  }
  __syncthreads();
  for (int idx = tid; idx < 4 * 64; idx += 256) {
    int p = idx >> 6, o = idx & 63;
    float s = 0.f;
    for (int k = 0; k < 16; k++) s = fmaf(G1[o][k], party_emb[p * 16 + k], s);
    tab_p[idx] = s;
  }
  for (int idx = tid; idx < 50 * 64; idx += 256) {
    int si = idx >> 6, o = idx & 63;
    float s = 0.f;
    for (int k = 0; k < 16; k++) s = fmaf(G1[o][16 + k], state_emb[si * 16 + k], s);
    tab_s[idx] = s;
  }
  if (tid < 64) {
    float s = b1[tid];
    for (int j = 0; j < 128; j++) {
      s = fmaf(W1[tid * 384 + j], static_b[j], s);
      s = fmaf(W1[tid * 384 + 128 + j] + W1[tid * 384 + 256 + j], price_b[j], s);
    }
    bias2[tid] = s;
  }
}

// ---------------- K2a: degree count ----------------
__global__ void count_kernel(const int* __restrict__ src, const int* __restrict__ dst,
                             int* cnt, int E) {
  int e = blockIdx.x * blockDim.x + threadIdx.x;
  if (e < E) {
    atomicAdd(&cnt[dst[e]], 1);
    atomicAdd(&cnt[src[e]], 1);
  }
}

// ---------------- K2b: exclusive scan (single block) ----------------
__global__ __launch_bounds__(1024) void scan_kernel(const int* __restrict__ cnt,
                                                    int* __restrict__ offs,
                                                    int* __restrict__ cursor, int N) {
  __shared__ int part[1024];
  int tid = threadIdx.x;
  int chunk = (N + 1023) / 1024;
  int beg = tid * chunk;
  int end = min(beg + chunk, N);
  int s = 0;
  for (int i = beg; i < end; i++) s += cnt[i];
  part[tid] = s;
  __syncthreads();
  for (int d = 1; d < 1024; d <<= 1) {
    int v = (tid >= d) ? part[tid - d] : 0;
    __syncthreads();
    part[tid] += v;
    __syncthreads();
  }
  int run = (tid > 0) ? part[tid - 1] : 0;
  for (int i = beg; i < end; i++) {
    offs[i] = run;
    cursor[i] = run;
    run += cnt[i];
  }
  if (tid == 1023) offs[N] = part[1023];
}

// ---------------- K2c: CSR fill ----------------
__global__ void fill_kernel(const int* __restrict__ src, const int* __restrict__ dst,
                            int* cursor, int* __restrict__ other, int* __restrict__ eid, int E) {
  int e = blockIdx.x * blockDim.x + threadIdx.x;
  if (e >= E) return;
  int s = src[e], d = dst[e];
  int p1 = atomicAdd(&cursor[d], 1);
  other[p1] = s; eid[p1] = e;
  int p2 = atomicAdd(&cursor[s], 1);
  other[p2] = d; eid[p2] = e;
}

// ---------------- K2d: per-node aggregation -> agg_b bf16 [N][544] ----------------
// 512 threads = 16 groups x 32 lanes. Group g handles entries beg+g, beg+g+16, ...
// Each lane: ONE float4 of the mem row (32x16B = full row), 4 cos, 1 msg float.
// Indices pre-staged in LDS so the chain head is a ds_read, not an L2 int load.
// 16 gather chains/block (round-9 had 4 -> latency-bound null).
__global__ __launch_bounds__(512) void agg_kernel(
    const int* __restrict__ offs, const int* __restrict__ other, const int* __restrict__ eid,
    const float* __restrict__ mem, const float* __restrict__ msg,
    const float* __restrict__ t, const float* __restrict__ lu,
    const float* __restrict__ tw, const float* __restrict__ tb,
    const int* __restrict__ cnt, ushort* __restrict__ agg_b, int N) {
  __shared__ int ld_oth[256];
  __shared__ int ld_eid[256];
  __shared__ float red[16 * 292];   // per-group partials: a0[128] acos[128] amsg[32], pad 292
  int tid = threadIdx.x;
  int grp = tid >> 5;   // 0..15
  int l = tid & 31;
  int v = blockIdx.x;
  int beg = offs[v], end = offs[v + 1];
  int deg = end - beg;
  int ndeg = min(deg, 256);
  for (int i = tid; i < ndeg; i += 512) {
    ld_oth[i] = other[beg + i];
    ld_eid[i] = eid[beg + i];
  }
  __syncthreads();

  float lupd = lu[v];
  float4 w4 = *reinterpret_cast<const float4*>(tw + 4 * l);
  float4 b4 = *reinterpret_cast<const float4*>(tb + 4 * l);
  float a0q0 = 0.f, a0q1 = 0.f, a0q2 = 0.f, a0q3 = 0.f;
  float ac0 = 0.f, ac1 = 0.f, ac2 = 0.f, ac3 = 0.f;
  float amsg = 0.f;
  for (int p = grp; p < deg; p += 16) {
    int u, e;
    if (p < 256) { u = ld_oth[p]; e = ld_eid[p]; }
    else { u = other[beg + p]; e = eid[beg + p]; }
    float4 mrow = *reinterpret_cast<const float4*>(mem + (size_t)u * H + 4 * l);
    float te = t[e];
    amsg += msg[e * EF + l];
    float dt = te - lupd;
    a0q0 += mrow.x; a0q1 += mrow.y; a0q2 += mrow.z; a0q3 += mrow.w;
    ac0 += __cosf(fmaf(dt, w4.x, b4.x));
    ac1 += __cosf(fmaf(dt, w4.y, b4.y));
    ac2 += __cosf(fmaf(dt, w4.z, b4.z));
    ac3 += __cosf(fmaf(dt, w4.w, b4.w));
  }
  float* r = red + grp * 292;
  r[4 * l + 0] = a0q0; r[4 * l + 1] = a0q1; r[4 * l + 2] = a0q2; r[4 * l + 3] = a0q3;
  r[128 + 4 * l + 0] = ac0; r[128 + 4 * l + 1] = ac1;
  r[128 + 4 * l + 2] = ac2; r[128 + 4 * l + 3] = ac3;
  r[256 + l] = amsg;
  __syncthreads();

  int cv = cnt[v];
  float inv = 1.f / (float)max(cv, 1);
  ushort* arow = agg_b + (size_t)v * KTOT;
  if (tid < 288) {
    float s = 0.f;
#pragma unroll
    for (int g2 = 0; g2 < 16; g2++) s += red[g2 * 292 + tid];
    s *= inv;
    if (tid < 128) arow[tid] = f2bf(s);              // mean neighbor mem
    else if (tid < 256) arow[288 + (tid - 128)] = f2bf(s);  // mean cos
    else arow[256 + (tid - 256)] = f2bf(s);          // mean msg
  } else if (tid < 416) {
    int c = tid - 288;
    float mv = mem[(size_t)v * H + c];
    arow[128 + c] = f2bf((cv > 0) ? mv : 0.f);       // mean of cv copies of mem[v]
    arow[416 + c] = f2bf(mv);                        // Whh operand
  }
}

// ---------------- K3: MFMA GEMM + fused GRU finalize -> mem_newb bf16 [N][128] ----------------
__global__ __launch_bounds__(256) void gru_gemm_mfma(
    const ushort* __restrict__ aggb, const ushort* __restrict__ WcatT,
    const float* __restrict__ mem, const int* __restrict__ cnt,
    const float* __restrict__ bih, const float* __restrict__ bhh,
    ushort* __restrict__ mem_newb, int N) {
  __shared__ union {
    ushort a[32 * 552];       // 35.3 KB
    float g[4][32][132];      // 67.6 KB
  } sm;
  int tid = threadIdx.x;
  int lane = tid & 63;
  int w = tid >> 6;
  int n0 = blockIdx.x * 32;

#pragma unroll
  for (int i = 0; i < 8; i++) {
    int row = w * 8 + i;
    int gr = min(n0 + row, N - 1);
    const uint4* srcp = reinterpret_cast<const uint4*>(aggb + (size_t)gr * KTOT);
    uint4* dstp = reinterpret_cast<uint4*>(sm.a + row * 552);
    dstp[lane] = srcp[lane];
    if (lane < 4) dstp[64 + lane] = srcp[64 + lane];
  }
  __syncthreads();

  f32x4 acc[2][8] = {};
  int arow_b = (lane & 15);
  int koff = (lane >> 4) * 8;
  for (int ks = 0; ks < 17; ks++) {
    int k = ks * 32 + koff;
    bf16x8 afr0 = *reinterpret_cast<const bf16x8*>(sm.a + (arow_b) * 552 + k);
    bf16x8 afr1 = *reinterpret_cast<const bf16x8*>(sm.a + (16 + arow_b) * 552 + k);
#pragma unroll
    for (int nt = 0; nt < 8; nt++) {
      int o = w * 128 + nt * 16 + (lane & 15);
      bf16x8 bfr = *reinterpret_cast<const bf16x8*>(WcatT + (size_t)o * KTOT + k);
      acc[0][nt] = __builtin_amdgcn_mfma_f32_16x16x32_bf16(afr0, bfr, acc[0][nt], 0, 0, 0);
      acc[1][nt] = __builtin_amdgcn_mfma_f32_16x16x32_bf16(afr1, bfr, acc[1][nt], 0, 0, 0);
    }
  }
  __syncthreads();  // A reads done; reuse LDS

#pragma unroll
  for (int mt = 0; mt < 2; mt++)
#pragma unroll
    for (int nt = 0; nt < 8; nt++)
#pragma unroll
      for (int r = 0; r < 4; r++)
        sm.g[w][mt * 16 + (lane >> 4) * 4 + r][nt * 16 + (lane & 15)] = acc[mt][nt][r];
  __syncthreads();

  int row = tid >> 3, j0 = (tid & 7) * 16;
  int n = n0 + row;
  if (n < N) {
    int cv = cnt[n];
#pragma unroll
    for (int jj = 0; jj < 16; jj++) {
      int j = j0 + jj;
      float m = mem[(size_t)n * H + j];
      float o;
      if (cv > 0) {
        float rp = sm.g[0][row][j] + bih[j] + bhh[j];
        float zp = sm.g[1][row][j] + bih[128 + j] + bhh[128 + j];
        float ip = sm.g[2][row][j] + bih[256 + j];
        float hp = sm.g[3][row][j] + bhh[256 + j];
        float r = sigmoidf_(rp), z = sigmoidf_(zp);
        float nn = tanhfast_(ip + r * hp);
        o = (1.f - z) * nn + z * m;
      } else {
        o = m;
      }
      mem_newb[(size_t)n * H + j] = f2bf(o);
    }
  }
}

// ---------------- K5a: price LSTM, MFMA-batched, extended-K, ROLLED t-loop ----------------
__global__ __launch_bounds__(256) void lstm_mfma_kernel(
    const float* __restrict__ price_seq,
    const float* __restrict__ lWih, const float* __restrict__ lWhh,
    const float* __restrict__ lbih, const float* __restrict__ lbhh,
    ushort* __restrict__ houtb, int E) {
  __shared__ float ps[64][15];  // block's 64 edges x 14 steps (pad 15)
  int tid = threadIdx.x;
  int lane = tid & 63;
  int el = lane & 15;
  int g = lane >> 4;
  int wv = tid >> 6;
  int row0 = blockIdx.x * 64;
  int el_local = wv * 16 + el;
  int e = row0 + el_local;
  bool valid = (e < E);

  // stage price rows
  for (int idx = tid; idx < 64 * TT; idx += 256) {
    int row = idx / TT, col = idx % TT;
    int ee = min(row0 + row, E - 1);
    ps[row][col] = price_seq[(size_t)ee * TT + col];
  }
  __syncthreads();

  // A fragments (h part): Whh[16b+el][g*8..g*8+7] in bf16
  union { uint u[4]; bf16x8 v; } afr[8];
#pragma unroll
  for (int b = 0; b < 8; b++) {
    const float* wr = lWhh + (16 * b + el) * LH + g * 8;
#pragma unroll
    for (int q = 0; q < 4; q++) {
      float lo = wr[2 * q], hi = wr[2 * q + 1];
      asm("v_cvt_pk_bf16_f32 %0, %1, %2" : "=v"(afr[b].u[q]) : "v"(lo), "v"(hi));
    }
  }
  // A2 fragments (x,1 part): k'=0 -> Wih[row], k'=1 -> bias[row]; only g==0 nonzero
  uint afr2w[8];
#pragma unroll
  for (int b = 0; b < 8; b++) {
    float wvv = lWih[16 * b + el];
    float bv = lbih[16 * b + el] + lbhh[16 * b + el];
    uint pk;
    asm("v_cvt_pk_bf16_f32 %0, %1, %2" : "=v"(pk) : "v"(wvv), "v"(bv));
    afr2w[b] = (g == 0) ? pk : 0u;
  }

  int addr_i[4];
#pragma unroll
  for (int i = 0; i < 4; i++) addr_i[i] = (el + 16 * ((g & 1) * 2 + (i >> 1))) << 2;
  bool hi_sel = (g >> 1) != 0;

  float cst[8];
#pragma unroll
  for (int i = 0; i < 8; i++) cst[i] = 0.f;
  uint hpk[4] = {0u, 0u, 0u, 0u};
  const f32x4 zero4 = {0.f, 0.f, 0.f, 0.f};

#pragma unroll 1
  for (int t = 0; t < TT; t++) {
    union { uint u[4]; bf16x8 v; } bfr;
#pragma unroll
    for (int i = 0; i < 4; i++) {
      uint lo = (uint)__builtin_amdgcn_ds_bpermute(addr_i[i], (int)hpk[i & 1]);
      uint hi = (uint)__builtin_amdgcn_ds_bpermute(addr_i[i], (int)hpk[2 + (i & 1)]);
      bfr.u[i] = hi_sel ? hi : lo;
    }
    float x = ps[el_local][t];
    union { uint u[4]; bf16x8 v; } bfr2;
    uint xp;
    asm("v_cvt_pk_bf16_f32 %0, %1, %2" : "=v"(xp) : "v"(x), "v"(1.0f));
    bfr2.u[0] = (g == 0) ? xp : 0u;
    bfr2.u[1] = 0u; bfr2.u[2] = 0u; bfr2.u[3] = 0u;

    float hval[8];
    f32x4 acc0, acc1, acc2, acc3, acc4, acc5, acc6, acc7;
#define STEPACC(b, A) \
    { union { uint u[4]; bf16x8 v; } a2; a2.u[0] = afr2w[b]; a2.u[1] = 0u; a2.u[2] = 0u; a2.u[3] = 0u; \
      A = __builtin_amdgcn_mfma_f32_16x16x32_bf16(a2.v, bfr2.v, zero4, 0, 0, 0); \
      A = __builtin_amdgcn_mfma_f32_16x16x32_bf16(afr[b].v, bfr.v, A, 0, 0, 0); }
    STEPACC(0, acc0) STEPACC(1, acc1) STEPACC(2, acc2) STEPACC(3, acc3)
    STEPACC(4, acc4) STEPACC(5, acc5) STEPACC(6, acc6) STEPACC(7, acc7)
#undef STEPACC
#define NONLIN(b1, AI, AF, AG, AO) \
    { _Pragma("unroll") for (int r = 0; r < 4; r++) { \
        int mi = 4 * b1 + r; \
        float ig = sigmoidf_(AI[r]); \
        float fg = sigmoidf_(AF[r]); \
        float gg = tanhfast_(AG[r]); \
        float og = sigmoidf_(AO[r]); \
        float cv = fmaf(fg, cst[mi], ig * gg); \
        cst[mi] = cv; \
        hval[mi] = og * tanhfast_(cv); } }
    NONLIN(0, acc0, acc2, acc4, acc6)
    NONLIN(1, acc1, acc3, acc5, acc7)
#undef NONLIN
#pragma unroll
    for (int i = 0; i < 4; i++)
      asm("v_cvt_pk_bf16_f32 %0, %1, %2" : "=v"(hpk[i]) : "v"(hval[2 * i]), "v"(hval[2 * i + 1]));
  }

  // hpk holds final h in bf16: hpk[0..1] -> m=4g..4g+3, hpk[2..3] -> m=16+4g..16+4g+3
  if (valid) {
    uint2* rowp = reinterpret_cast<uint2*>(houtb + (size_t)e * LH);
    rowp[g] = make_uint2(hpk[0], hpk[1]);
    rowp[4 + g] = make_uint2(hpk[2], hpk[3]);
  }
}

// ---------------- K5b: pred bf16 MFMA: out[E] from X[E][288] @ Wcombb^T ----------------
__global__ __launch_bounds__(256) void pred_mfma(
    const int* __restrict__ src, const int* __restrict__ dst,
    const int* __restrict__ x_static,
    const ushort* __restrict__ mem_newb, const ushort* __restrict__ houtb,
    const ushort* __restrict__ Wcombb, const float* __restrict__ tab_p,
    const float* __restrict__ tab_s, const float* __restrict__ bias2,
    const float* __restrict__ W2, const float* __restrict__ b2,
    float* __restrict__ out, int E) {
  __shared__ ushort Asm[64 * 296];
  __shared__ int pidx[64], stix[64];
  __shared__ int sidx[64], didx[64];
  int tid = threadIdx.x;
  int row0 = blockIdx.x * 64;
  if (tid < 64) {
    int e = min(row0 + tid, E - 1);
    int s = src[e], d = dst[e];
    sidx[tid] = s; didx[tid] = d;
    pidx[tid] = x_static[s * 2]; stix[tid] = x_static[s * 2 + 1];
  }
  __syncthreads();
  // stage A: 64 rows x 36 16B-chunks (16 ms + 16 md + 4 h)
#pragma unroll
  for (int i = 0; i < 9; i++) {
    int idx = tid + i * 256;
    int row = idx / 36, c = idx % 36;
    int e = min(row0 + row, E - 1);
    uint4 v;
    if (c < 16) v = reinterpret_cast<const uint4*>(mem_newb + (size_t)sidx[row] * H)[c];
    else if (c < 32) v = reinterpret_cast<const uint4*>(mem_newb + (size_t)didx[row] * H)[c - 16];
    else v = reinterpret_cast<const uint4*>(houtb + (size_t)e * LH)[c - 32];
    *reinterpret_cast<uint4*>(Asm + row * 296 + c * 8) = v;
  }
  __syncthreads();

  int lane = tid & 63;
  int w = tid >> 6;
  f32x4 acc[4] = {};
  int arow = w * 16 + (lane & 15);
  int koff = (lane >> 4) * 8;
  for (int ks = 0; ks < 9; ks++) {
    int k = ks * 32 + koff;
    bf16x8 afr = *reinterpret_cast<const bf16x8*>(Asm + arow * 296 + k);
#pragma unroll
    for (int nt = 0; nt < 4; nt++) {
      int o = nt * 16 + (lane & 15);
      bf16x8 bfr = *reinterpret_cast<const bf16x8*>(Wcombb + (size_t)o * KP + k);
      acc[nt] = __builtin_amdgcn_mfma_f32_16x16x32_bf16(afr, bfr, acc[nt], 0, 0, 0);
    }
  }
  // epilogue: lane holds D[edge=(lane>>4)*4+r][o=nt*16+(lane&15)]
  int ocol = lane & 15;
  float bb2 = b2[0];
#pragma unroll
  for (int r = 0; r < 4; r++) {
    int rl = w * 16 + (lane >> 4) * 4 + r;
    int p = pidx[rl], st = stix[rl];
    float s = 0.f;
#pragma unroll
    for (int nt = 0; nt < 4; nt++) {
      int o = nt * 16 + ocol;
      float hv = acc[nt][r] + bias2[o] + tab_p[p * 64 + o] + tab_s[st * 64 + o];
      s = fmaf(fmaxf(hv, 0.f), W2[o], s);
    }
#pragma unroll
    for (int d = 1; d < 16; d <<= 1) s += __shfl_xor(s, d);
    int e = row0 + rl;
    if (ocol == 0 && e < E) out[e] = s + bb2;
  }
}

// ---------------- launch ----------------
extern "C" void kernel_launch(void* const* d_in, const int* in_sizes, int n_in,
                              void* d_out, int out_size, void* d_ws, size_t ws_size,
                              hipStream_t stream) {
  const int* src = (const int*)d_in[0];
  const int* dst = (const int*)d_in[1];
  const float* t = (const float*)d_in[2];
  const float* msg = (const float*)d_in[3];
  const float* price_seq = (const float*)d_in[4];
  const int* x_static = (const int*)d_in[6];
  const float* memory = (const float*)d_in[7];
  const float* last_update = (const float*)d_in[8];
  const float* time_w = (const float*)d_in[9];
  const float* time_b = (const float*)d_in[10];
  const float* gWih = (const float*)d_in[11];
  const float* gWhh = (const float*)d_in[12];
  const float* gbih = (const float*)d_in[13];
  const float* gbhh = (const float*)d_in[14];
  const float* party_emb = (const float*)d_in[15];
  const float* state_emb = (const float*)d_in[16];
  const float* static_W = (const float*)d_in[17];
  const float* static_b = (const float*)d_in[18];
  const float* lWih = (const float*)d_in[19];
  const float* lWhh = (const float*)d_in[20];
  const float* lbih = (const float*)d_in[21];
  const float* lbhh = (const float*)d_in[22];
  const float* price_W = (const float*)d_in[23];
  const float* price_b = (const float*)d_in[24];
  const float* W1 = (const float*)d_in[25];
  const float* b1 = (const float*)d_in[26];
  const float* W2 = (const float*)d_in[27];
  const float* b2 = (const float*)d_in[28];
  float* out = (float*)d_out;

  const int E = in_sizes[0];
  const int N = in_sizes[8];

  char* ws = (char*)d_ws;
  size_t off = 0;
  auto alloc = [&](size_t bytes) { size_t o = off; off += (bytes + 255) & ~(size_t)255; return o; };
  int* cnt       = (int*)(ws + alloc((size_t)N * 4));
  int* offs      = (int*)(ws + alloc((size_t)(N + 1) * 4));
  int* cursor    = (int*)(ws + alloc((size_t)N * 4));
  int* other     = (int*)(ws + alloc((size_t)2 * E * 4));
  int* eid       = (int*)(ws + alloc((size_t)2 * E * 4));
  ushort* WcatT  = (ushort*)(ws + alloc((size_t)GOUT * KTOT * 2));
  ushort* Wcombb = (ushort*)(ws + alloc((size_t)64 * KP * 2));
  float* tab_p   = (float*)(ws + alloc((size_t)4 * 64 * 4));
  float* tab_s   = (float*)(ws + alloc((size_t)50 * 64 * 4));
  float* bias2   = (float*)(ws + alloc((size_t)64 * 4));
  ushort* agg_b  = (ushort*)(ws + alloc((size_t)N * KTOT * 2));
  ushort* mem_newb = (ushort*)(ws + alloc((size_t)N * H * 2));
  ushort* houtb  = (ushort*)(ws + alloc((size_t)E * LH * 2));
  (void)ws_size;

  hipMemsetAsync(cnt, 0, (size_t)N * 4, stream);

  build_weights<<<(GOUT * KTOT + 255) / 256, 256, 0, stream>>>(gWih, gWhh, WcatT);
  prep_pred<<<1, 256, 0, stream>>>(W1, b1, static_W, static_b, price_W, price_b,
                                   party_emb, state_emb, Wcombb, tab_p, tab_s, bias2);
  count_kernel<<<(E + 255) / 256, 256, 0, stream>>>(src, dst, cnt, E);
  scan_kernel<<<1, 1024, 0, stream>>>(cnt, offs, cursor, N);
  fill_kernel<<<(E + 255) / 256, 256, 0, stream>>>(src, dst, cursor, other, eid, E);
  agg_kernel<<<N, 512, 0, stream>>>(offs, other, eid, memory, msg, t, last_update,
                                    time_w, time_b, cnt, agg_b, N);
  gru_gemm_mfma<<<(N + 31) / 32, 256, 0, stream>>>(agg_b, WcatT, memory, cnt,
                                                   gbih, gbhh, mem_newb, N);
  lstm_mfma_kernel<<<(E + 63) / 64, 256, 0, stream>>>(price_seq, lWih, lWhh, lbih, lbhh, houtb, E);
  pred_mfma<<<(E + 63) / 64, 256, 0, stream>>>(src, dst, x_static, mem_newb, houtb,
      Wcombb, tab_p, tab_s, bias2, W2, b2, out, E);
}

// Round 11
// 423.927 us; speedup vs baseline: 7.0521x; 1.0519x over previous
//
#include <hip/hip_runtime.h>

#define H 128
#define EF 32
#define TT 14
#define LH 32
#define KDIM 416   // 3H+EF
#define GOUT 512   // [r_pre, z_pre, i_n, h_n] each 128
#define KTOT 544   // 416 (agg) + 128 (memory)
#define KP 288     // pred GEMM K: 128 ms + 128 md + 32 h

typedef __attribute__((ext_vector_type(8))) short bf16x8;
typedef __attribute__((ext_vector_type(4))) float f32x4;

// native-HW nonlinearities: v_exp_f32 computes 2^x; v_rcp_f32 is ~1ulp.
__device__ __forceinline__ float sigmoidf_(float x) {
  float e = __builtin_amdgcn_exp2f(x * -1.442695041f);   // exp(-x)
  return __builtin_amdgcn_rcpf(1.0f + e);
}
__device__ __forceinline__ float tanhfast_(float x) {
  float e = __builtin_amdgcn_exp2f(x * 2.885390082f);    // exp(2x)
  return 1.0f - 2.0f * __builtin_amdgcn_rcpf(e + 1.0f);
}
__device__ __forceinline__ ushort f2bf(float x) {
  uint u = __float_as_uint(x);
  u += 0x7fff + ((u >> 16) & 1);   // RTNE
  return (ushort)(u >> 16);
}

// ---------------- K1: build WcatT bf16 [512][544] (o-major) ----------------
__global__ __launch_bounds__(256) void build_weights(
    const float* __restrict__ Wih, const float* __restrict__ Whh,
    ushort* __restrict__ WcatT) {
  int i = blockIdx.x * 256 + threadIdx.x;
  if (i >= GOUT * KTOT) return;
  int o = i / KTOT, k = i % KTOT;
  int j = o & 127;
  float v = 0.f;
  if (o < 256) {  // r (o<128) and z (o<256): gi+gh fused
    int row = (o < 128) ? j : (128 + j);
    v = (k < KDIM) ? Wih[row * KDIM + k] : Whh[row * H + (k - KDIM)];
  } else if (o < 384) {  // i_n
    v = (k < KDIM) ? Wih[(256 + j) * KDIM + k] : 0.f;
  } else {               // h_n
    v = (k < KDIM) ? 0.f : Whh[(256 + j) * H + (k - KDIM)];
  }
  WcatT[i] = f2bf(v);
}

// ---------------- K1b: predictor algebra collapse, 16 blocks x 4 o-rows ----------------
__global__ __launch_bounds__(256) void prep_pred(
    const float* __restrict__ W1, const float* __restrict__ b1,
    const float* __restrict__ static_W, const float* __restrict__ static_b,
    const float* __restrict__ price_W, const float* __restrict__ price_b,
    const float* __restrict__ party_emb, const float* __restrict__ state_emb,
    ushort* __restrict__ Wcombb, float* __restrict__ tab_p, float* __restrict__ tab_s,
    float* __restrict__ bias2) {
  __shared__ float G1s[4][32];
  int tid = threadIdx.x;
  int ob = blockIdx.x * 4;
  if (tid < 128) {
    int ol = tid >> 5, k = tid & 31;
    int o = ob + ol;
    float g = 0.f, m = 0.f;
    for (int j = 0; j < 128; j++) {
      g = fmaf(W1[o * 384 + j], static_W[j * 32 + k], g);
      m = fmaf(W1[o * 384 + 128 + j] + W1[o * 384 + 256 + j], price_W[j * 32 + k], m);
    }
    G1s[ol][k] = g;
    Wcombb[o * KP + 256 + k] = f2bf(m);
  }
  for (int idx = tid; idx < 1024; idx += 256) {
    int ol = idx >> 8, j = idx & 255;
    int o = ob + ol;
    Wcombb[o * KP + j] = f2bf(W1[o * 384 + j]);
  }
  __syncthreads();
  for (int idx = tid; idx < 216; idx += 256) {
    if (idx < 16) {
      int p = idx >> 2, ol = idx & 3;
      float s = 0.f;
      for (int k = 0; k < 16; k++) s = fmaf(G1s[ol][k], party_emb[p * 16 + k], s);
      tab_p[p * 64 + ob + ol] = s;
    } else {
      int i2 = idx - 16;
      int si = i2 >> 2, ol = i2 & 3;
      float s = 0.f;
      for (int k = 0; k < 16; k++) s = fmaf(G1s[ol][16 + k], state_emb[si * 16 + k], s);
      tab_s[si * 64 + ob + ol] = s;
    }
  }
  if (tid < 4) {
    int o = ob + tid;
    float s = b1[o];
    for (int j = 0; j < 128; j++) {
      s = fmaf(W1[o * 384 + j], static_b[j], s);
      s = fmaf(W1[o * 384 + 128 + j] + W1[o * 384 + 256 + j], price_b[j], s);
    }
    bias2[o] = s;
  }
}

// ---------------- K2a: degree count ----------------
__global__ void count_kernel(const int* __restrict__ src, const int* __restrict__ dst,
                             int* cnt, int E) {
  int e = blockIdx.x * blockDim.x + threadIdx.x;
  if (e < E) {
    atomicAdd(&cnt[dst[e]], 1);
    atomicAdd(&cnt[src[e]], 1);
  }
}

// ---------------- K2b: exclusive scan (single block) ----------------
__global__ __launch_bounds__(1024) void scan_kernel(const int* __restrict__ cnt,
                                                    int* __restrict__ offs,
                                                    int* __restrict__ cursor, int N) {
  __shared__ int part[1024];
  int tid = threadIdx.x;
  int chunk = (N + 1023) / 1024;
  int beg = tid * chunk;
  int end = min(beg + chunk, N);
  int s = 0;
  for (int i = beg; i < end; i++) s += cnt[i];
  part[tid] = s;
  __syncthreads();
  for (int d = 1; d < 1024; d <<= 1) {
    int v = (tid >= d) ? part[tid - d] : 0;
    __syncthreads();
    part[tid] += v;
    __syncthreads();
  }
  int run = (tid > 0) ? part[tid - 1] : 0;
  for (int i = beg; i < end; i++) {
    offs[i] = run;
    cursor[i] = run;
    run += cnt[i];
  }
  if (tid == 1023) offs[N] = part[1023];
}

// ---------------- K2c: CSR fill ----------------
__global__ void fill_kernel(const int* __restrict__ src, const int* __restrict__ dst,
                            int* cursor, int* __restrict__ other, int* __restrict__ eid, int E) {
  int e = blockIdx.x * blockDim.x + threadIdx.x;
  if (e >= E) return;
  int s = src[e], d = dst[e];
  int p1 = atomicAdd(&cursor[d], 1);
  other[p1] = s; eid[p1] = e;
  int p2 = atomicAdd(&cursor[s], 1);
  other[p2] = d; eid[p2] = e;
}

// ---------------- FUSED: lstm blocks [0,nL) + agg blocks [nL, nL+N) ----------------
// lstm depends only on price_seq; agg needs the CSR. Fusing them overlaps the
// VALU/trans-bound LSTM with the memory-latency-bound gather on the same CUs.
// lstm blocks come FIRST so the long-pole work starts immediately.
__global__ __launch_bounds__(512) void agg_lstm_kernel(
    const int* __restrict__ offs, const int* __restrict__ other, const int* __restrict__ eid,
    const float* __restrict__ mem, const float* __restrict__ msg,
    const float* __restrict__ t, const float* __restrict__ lu,
    const float* __restrict__ tw, const float* __restrict__ tb,
    const int* __restrict__ cnt, ushort* __restrict__ agg_b, int N,
    const float* __restrict__ price_seq,
    const float* __restrict__ lWih, const float* __restrict__ lWhh,
    const float* __restrict__ lbih, const float* __restrict__ lbhh,
    ushort* __restrict__ houtb, int E, int nL) {
  __shared__ union {
    struct { int ld_oth[256]; int ld_eid[256]; float red[16 * 292]; } a;  // 20.7 KB
    float ps[128][15];                                                    // 7.7 KB
  } sm;
  int tid = threadIdx.x;

  if ((int)blockIdx.x < nL) {
    // ================= LSTM path: 8 waves x 16 edges = 128 edges =================
    int lane = tid & 63;
    int el = lane & 15;
    int g = lane >> 4;
    int wv = tid >> 6;                 // 0..7
    int row0 = blockIdx.x * 128;
    int el_local = wv * 16 + el;       // 0..127
    int e = row0 + el_local;
    bool valid = (e < E);

    for (int idx = tid; idx < 128 * TT; idx += 512) {
      int row = idx / TT, col = idx % TT;
      int ee = min(row0 + row, E - 1);
      sm.ps[row][col] = price_seq[(size_t)ee * TT + col];
    }
    __syncthreads();

    union { uint u[4]; bf16x8 v; } afr[8];
#pragma unroll
    for (int b = 0; b < 8; b++) {
      const float* wr = lWhh + (16 * b + el) * LH + g * 8;
#pragma unroll
      for (int q = 0; q < 4; q++) {
        float lo = wr[2 * q], hi = wr[2 * q + 1];
        asm("v_cvt_pk_bf16_f32 %0, %1, %2" : "=v"(afr[b].u[q]) : "v"(lo), "v"(hi));
      }
    }
    uint afr2w[8];
#pragma unroll
    for (int b = 0; b < 8; b++) {
      float wvv = lWih[16 * b + el];
      float bv = lbih[16 * b + el] + lbhh[16 * b + el];
      uint pk;
      asm("v_cvt_pk_bf16_f32 %0, %1, %2" : "=v"(pk) : "v"(wvv), "v"(bv));
      afr2w[b] = (g == 0) ? pk : 0u;
    }

    int addr_i[4];
#pragma unroll
    for (int i = 0; i < 4; i++) addr_i[i] = (el + 16 * ((g & 1) * 2 + (i >> 1))) << 2;
    bool hi_sel = (g >> 1) != 0;

    float cst[8];
#pragma unroll
    for (int i = 0; i < 8; i++) cst[i] = 0.f;
    uint hpk[4] = {0u, 0u, 0u, 0u};
    const f32x4 zero4 = {0.f, 0.f, 0.f, 0.f};

#pragma unroll 1
    for (int tt = 0; tt < TT; tt++) {
      union { uint u[4]; bf16x8 v; } bfr;
#pragma unroll
      for (int i = 0; i < 4; i++) {
        uint lo = (uint)__builtin_amdgcn_ds_bpermute(addr_i[i], (int)hpk[i & 1]);
        uint hi = (uint)__builtin_amdgcn_ds_bpermute(addr_i[i], (int)hpk[2 + (i & 1)]);
        bfr.u[i] = hi_sel ? hi : lo;
      }
      float x = sm.ps[el_local][tt];
      union { uint u[4]; bf16x8 v; } bfr2;
      uint xp;
      asm("v_cvt_pk_bf16_f32 %0, %1, %2" : "=v"(xp) : "v"(x), "v"(1.0f));
      bfr2.u[0] = (g == 0) ? xp : 0u;
      bfr2.u[1] = 0u; bfr2.u[2] = 0u; bfr2.u[3] = 0u;

      float hval[8];
      f32x4 acc0, acc1, acc2, acc3, acc4, acc5, acc6, acc7;
#define STEPACC(b, A) \
      { union { uint u[4]; bf16x8 v; } a2; a2.u[0] = afr2w[b]; a2.u[1] = 0u; a2.u[2] = 0u; a2.u[3] = 0u; \
        A = __builtin_amdgcn_mfma_f32_16x16x32_bf16(a2.v, bfr2.v, zero4, 0, 0, 0); \
        A = __builtin_amdgcn_mfma_f32_16x16x32_bf16(afr[b].v, bfr.v, A, 0, 0, 0); }
      STEPACC(0, acc0) STEPACC(1, acc1) STEPACC(2, acc2) STEPACC(3, acc3)
      STEPACC(4, acc4) STEPACC(5, acc5) STEPACC(6, acc6) STEPACC(7, acc7)
#undef STEPACC
#define NONLIN(b1, AI, AF, AG, AO) \
      { _Pragma("unroll") for (int r = 0; r < 4; r++) { \
          int mi = 4 * b1 + r; \
          float ig = sigmoidf_(AI[r]); \
          float fg = sigmoidf_(AF[r]); \
          float gg = tanhfast_(AG[r]); \
          float og = sigmoidf_(AO[r]); \
          float cv = fmaf(fg, cst[mi], ig * gg); \
          cst[mi] = cv; \
          hval[mi] = og * tanhfast_(cv); } }
      NONLIN(0, acc0, acc2, acc4, acc6)
      NONLIN(1, acc1, acc3, acc5, acc7)
#undef NONLIN
#pragma unroll
      for (int i = 0; i < 4; i++)
        asm("v_cvt_pk_bf16_f32 %0, %1, %2" : "=v"(hpk[i]) : "v"(hval[2 * i]), "v"(hval[2 * i + 1]));
    }

    if (valid) {
      uint2* rowp = reinterpret_cast<uint2*>(houtb + (size_t)e * LH);
      rowp[g] = make_uint2(hpk[0], hpk[1]);
      rowp[4 + g] = make_uint2(hpk[2], hpk[3]);
    }
  } else {
    // ================= AGG path: 16 groups x 32 lanes =================
    int grp = tid >> 5;
    int l = tid & 31;
    int v = blockIdx.x - nL;
    int beg = offs[v], end = offs[v + 1];
    int deg = end - beg;
    int ndeg = min(deg, 256);
    for (int i = tid; i < ndeg; i += 512) {
      sm.a.ld_oth[i] = other[beg + i];
      sm.a.ld_eid[i] = eid[beg + i];
    }
    __syncthreads();

    float lupd = lu[v];
    float4 w4 = *reinterpret_cast<const float4*>(tw + 4 * l);
    float4 b4 = *reinterpret_cast<const float4*>(tb + 4 * l);
    float a0q0 = 0.f, a0q1 = 0.f, a0q2 = 0.f, a0q3 = 0.f;
    float ac0 = 0.f, ac1 = 0.f, ac2 = 0.f, ac3 = 0.f;
    float amsg = 0.f;
    for (int p = grp; p < deg; p += 16) {
      int u, e;
      if (p < 256) { u = sm.a.ld_oth[p]; e = sm.a.ld_eid[p]; }
      else { u = other[beg + p]; e = eid[beg + p]; }
      float4 mrow = *reinterpret_cast<const float4*>(mem + (size_t)u * H + 4 * l);
      float te = t[e];
      amsg += msg[e * EF + l];
      float dt = te - lupd;
      a0q0 += mrow.x; a0q1 += mrow.y; a0q2 += mrow.z; a0q3 += mrow.w;
      ac0 += __cosf(fmaf(dt, w4.x, b4.x));
      ac1 += __cosf(fmaf(dt, w4.y, b4.y));
      ac2 += __cosf(fmaf(dt, w4.z, b4.z));
      ac3 += __cosf(fmaf(dt, w4.w, b4.w));
    }
    float* r = sm.a.red + grp * 292;
    r[4 * l + 0] = a0q0; r[4 * l + 1] = a0q1; r[4 * l + 2] = a0q2; r[4 * l + 3] = a0q3;
    r[128 + 4 * l + 0] = ac0; r[128 + 4 * l + 1] = ac1;
    r[128 + 4 * l + 2] = ac2; r[128 + 4 * l + 3] = ac3;
    r[256 + l] = amsg;
    __syncthreads();

    int cv = cnt[v];
    float inv = 1.f / (float)max(cv, 1);
    ushort* arow = agg_b + (size_t)v * KTOT;
    if (tid < 288) {
      float s = 0.f;
#pragma unroll
      for (int g2 = 0; g2 < 16; g2++) s += sm.a.red[g2 * 292 + tid];
      s *= inv;
      if (tid < 128) arow[tid] = f2bf(s);                     // mean neighbor mem
      else if (tid < 256) arow[288 + (tid - 128)] = f2bf(s);  // mean cos
      else arow[256 + (tid - 256)] = f2bf(s);                 // mean msg
    } else if (tid < 416) {
      int c = tid - 288;
      float mv = mem[(size_t)v * H + c];
      arow[128 + c] = f2bf((cv > 0) ? mv : 0.f);  // mean of cv copies of mem[v]
      arow[416 + c] = f2bf(mv);                   // Whh operand
    }
  }
}

// ---------------- K3: MFMA GEMM + fused GRU finalize -> mem_newb bf16 [N][128] ----------------
__global__ __launch_bounds__(256) void gru_gemm_mfma(
    const ushort* __restrict__ aggb, const ushort* __restrict__ WcatT,
    const float* __restrict__ mem, const int* __restrict__ cnt,
    const float* __restrict__ bih, const float* __restrict__ bhh,
    ushort* __restrict__ mem_newb, int N) {
  __shared__ union {
    ushort a[32 * 552];       // 35.3 KB
    float g[4][32][132];      // 67.6 KB
  } sm;
  int tid = threadIdx.x;
  int lane = tid & 63;
  int w = tid >> 6;
  int n0 = blockIdx.x * 32;

#pragma unroll
  for (int i = 0; i < 8; i++) {
    int row = w * 8 + i;
    int gr = min(n0 + row, N - 1);
    const uint4* srcp = reinterpret_cast<const uint4*>(aggb + (size_t)gr * KTOT);
    uint4* dstp = reinterpret_cast<uint4*>(sm.a + row * 552);
    dstp[lane] = srcp[lane];
    if (lane < 4) dstp[64 + lane] = srcp[64 + lane];
  }
  __syncthreads();

  f32x4 acc[2][8] = {};
  int arow_b = (lane & 15);
  int koff = (lane >> 4) * 8;
  for (int ks = 0; ks < 17; ks++) {
    int k = ks * 32 + koff;
    bf16x8 afr0 = *reinterpret_cast<const bf16x8*>(sm.a + (arow_b) * 552 + k);
    bf16x8 afr1 = *reinterpret_cast<const bf16x8*>(sm.a + (16 + arow_b) * 552 + k);
#pragma unroll
    for (int nt = 0; nt < 8; nt++) {
      int o = w * 128 + nt * 16 + (lane & 15);
      bf16x8 bfr = *reinterpret_cast<const bf16x8*>(WcatT + (size_t)o * KTOT + k);
      acc[0][nt] = __builtin_amdgcn_mfma_f32_16x16x32_bf16(afr0, bfr, acc[0][nt], 0, 0, 0);
      acc[1][nt] = __builtin_amdgcn_mfma_f32_16x16x32_bf16(afr1, bfr, acc[1][nt], 0, 0, 0);
    }
  }
  __syncthreads();  // A reads done; reuse LDS

#pragma unroll
  for (int mt = 0; mt < 2; mt++)
#pragma unroll
    for (int nt = 0; nt < 8; nt++)
#pragma unroll
      for (int r = 0; r < 4; r++)
        sm.g[w][mt * 16 + (lane >> 4) * 4 + r][nt * 16 + (lane & 15)] = acc[mt][nt][r];
  __syncthreads();

  int row = tid >> 3, j0 = (tid & 7) * 16;
  int n = n0 + row;
  if (n < N) {
    int cv = cnt[n];
#pragma unroll
    for (int jj = 0; jj < 16; jj++) {
      int j = j0 + jj;
      float m = mem[(size_t)n * H + j];
      float o;
      if (cv > 0) {
        float rp = sm.g[0][row][j] + bih[j] + bhh[j];
        float zp = sm.g[1][row][j] + bih[128 + j] + bhh[128 + j];
        float ip = sm.g[2][row][j] + bih[256 + j];
        float hp = sm.g[3][row][j] + bhh[256 + j];
        float r = sigmoidf_(rp), z = sigmoidf_(zp);
        float nn = tanhfast_(ip + r * hp);
        o = (1.f - z) * nn + z * m;
      } else {
        o = m;
      }
      mem_newb[(size_t)n * H + j] = f2bf(o);
    }
  }
}

// ---------------- K5b: pred bf16 MFMA: out[E] from X[E][288] @ Wcombb^T ----------------
__global__ __launch_bounds__(256) void pred_mfma(
    const int* __restrict__ src, const int* __restrict__ dst,
    const int* __restrict__ x_static,
    const ushort* __restrict__ mem_newb, const ushort* __restrict__ houtb,
    const ushort* __restrict__ Wcombb, const float* __restrict__ tab_p,
    const float* __restrict__ tab_s, const float* __restrict__ bias2,
    const float* __restrict__ W2, const float* __restrict__ b2,
    float* __restrict__ out, int E) {
  __shared__ ushort Asm[64 * 296];
  __shared__ int pidx[64], stix[64];
  __shared__ int sidx[64], didx[64];
  int tid = threadIdx.x;
  int row0 = blockIdx.x * 64;
  if (tid < 64) {
    int e = min(row0 + tid, E - 1);
    int s = src[e], d = dst[e];
    sidx[tid] = s; didx[tid] = d;
    pidx[tid] = x_static[s * 2]; stix[tid] = x_static[s * 2 + 1];
  }
  __syncthreads();
  // stage A: 64 rows x 36 16B-chunks (16 ms + 16 md + 4 h)
#pragma unroll
  for (int i = 0; i < 9; i++) {
    int idx = tid + i * 256;
    int row = idx / 36, c = idx % 36;
    int e = min(row0 + row, E - 1);
    uint4 v;
    if (c < 16) v = reinterpret_cast<const uint4*>(mem_newb + (size_t)sidx[row] * H)[c];
    else if (c < 32) v = reinterpret_cast<const uint4*>(mem_newb + (size_t)didx[row] * H)[c - 16];
    else v = reinterpret_cast<const uint4*>(houtb + (size_t)e * LH)[c - 32];
    *reinterpret_cast<uint4*>(Asm + row * 296 + c * 8) = v;
  }
  __syncthreads();

  int lane = tid & 63;
  int w = tid >> 6;
  f32x4 acc[4] = {};
  int arow = w * 16 + (lane & 15);
  int koff = (lane >> 4) * 8;
  for (int ks = 0; ks < 9; ks++) {
    int k = ks * 32 + koff;
    bf16x8 afr = *reinterpret_cast<const bf16x8*>(Asm + arow * 296 + k);
#pragma unroll
    for (int nt = 0; nt < 4; nt++) {
      int o = nt * 16 + (lane & 15);
      bf16x8 bfr = *reinterpret_cast<const bf16x8*>(Wcombb + (size_t)o * KP + k);
      acc[nt] = __builtin_amdgcn_mfma_f32_16x16x32_bf16(afr, bfr, acc[nt], 0, 0, 0);
    }
  }
  // epilogue: lane holds D[edge=(lane>>4)*4+r][o=nt*16+(lane&15)]
  int ocol = lane & 15;
  float bb2 = b2[0];
#pragma unroll
  for (int r = 0; r < 4; r++) {
    int rl = w * 16 + (lane >> 4) * 4 + r;
    int p = pidx[rl], st = stix[rl];
    float s = 0.f;
#pragma unroll
    for (int nt = 0; nt < 4; nt++) {
      int o = nt * 16 + ocol;
      float hv = acc[nt][r] + bias2[o] + tab_p[p * 64 + o] + tab_s[st * 64 + o];
      s = fmaf(fmaxf(hv, 0.f), W2[o], s);
    }
#pragma unroll
    for (int d = 1; d < 16; d <<= 1) s += __shfl_xor(s, d);
    int e = row0 + rl;
    if (ocol == 0 && e < E) out[e] = s + bb2;
  }
}

// ---------------- launch ----------------
extern "C" void kernel_launch(void* const* d_in, const int* in_sizes, int n_in,
                              void* d_out, int out_size, void* d_ws, size_t ws_size,
                              hipStream_t stream) {
  const int* src = (const int*)d_in[0];
  const int* dst = (const int*)d_in[1];
  const float* t = (const float*)d_in[2];
  const float* msg = (const float*)d_in[3];
  const float* price_seq = (const float*)d_in[4];
  const int* x_static = (const int*)d_in[6];
  const float* memory = (const float*)d_in[7];
  const float* last_update = (const float*)d_in[8];
  const float* time_w = (const float*)d_in[9];
  const float* time_b = (const float*)d_in[10];
  const float* gWih = (const float*)d_in[11];
  const float* gWhh = (const float*)d_in[12];
  const float* gbih = (const float*)d_in[13];
  const float* gbhh = (const float*)d_in[14];
  const float* party_emb = (const float*)d_in[15];
  const float* state_emb = (const float*)d_in[16];
  const float* static_W = (const float*)d_in[17];
  const float* static_b = (const float*)d_in[18];
  const float* lWih = (const float*)d_in[19];
  const float* lWhh = (const float*)d_in[20];
  const float* lbih = (const float*)d_in[21];
  const float* lbhh = (const float*)d_in[22];
  const float* price_W = (const float*)d_in[23];
  const float* price_b = (const float*)d_in[24];
  const float* W1 = (const float*)d_in[25];
  const float* b1 = (const float*)d_in[26];
  const float* W2 = (const float*)d_in[27];
  const float* b2 = (const float*)d_in[28];
  float* out = (float*)d_out;

  const int E = in_sizes[0];
  const int N = in_sizes[8];

  char* ws = (char*)d_ws;
  size_t off = 0;
  auto alloc = [&](size_t bytes) { size_t o = off; off += (bytes + 255) & ~(size_t)255; return o; };
  int* cnt       = (int*)(ws + alloc((size_t)N * 4));
  int* offs      = (int*)(ws + alloc((size_t)(N + 1) * 4));
  int* cursor    = (int*)(ws + alloc((size_t)N * 4));
  int* other     = (int*)(ws + alloc((size_t)2 * E * 4));
  int* eid       = (int*)(ws + alloc((size_t)2 * E * 4));
  ushort* WcatT  = (ushort*)(ws + alloc((size_t)GOUT * KTOT * 2));
  ushort* Wcombb = (ushort*)(ws + alloc((size_t)64 * KP * 2));
  float* tab_p   = (float*)(ws + alloc((size_t)4 * 64 * 4));
  float* tab_s   = (float*)(ws + alloc((size_t)50 * 64 * 4));
  float* bias2   = (float*)(ws + alloc((size_t)64 * 4));
  ushort* agg_b  = (ushort*)(ws + alloc((size_t)N * KTOT * 2));
  ushort* mem_newb = (ushort*)(ws + alloc((size_t)N * H * 2));
  ushort* houtb  = (ushort*)(ws + alloc((size_t)E * LH * 2));
  (void)ws_size;

  hipMemsetAsync(cnt, 0, (size_t)N * 4, stream);

  build_weights<<<(GOUT * KTOT + 255) / 256, 256, 0, stream>>>(gWih, gWhh, WcatT);
  prep_pred<<<16, 256, 0, stream>>>(W1, b1, static_W, static_b, price_W, price_b,
                                    party_emb, state_emb, Wcombb, tab_p, tab_s, bias2);
  count_kernel<<<(E + 255) / 256, 256, 0, stream>>>(src, dst, cnt, E);
  scan_kernel<<<1, 1024, 0, stream>>>(cnt, offs, cursor, N);
  fill_kernel<<<(E + 255) / 256, 256, 0, stream>>>(src, dst, cursor, other, eid, E);
  int nL = (E + 127) / 128;
  agg_lstm_kernel<<<nL + N, 512, 0, stream>>>(offs, other, eid, memory, msg, t, last_update,
                                              time_w, time_b, cnt, agg_b, N,
                                              price_seq, lWih, lWhh, lbih, lbhh, houtb, E, nL);
  gru_gemm_mfma<<<(N + 31) / 32, 256, 0, stream>>>(agg_b, WcatT, memory, cnt,
                                                   gbih, gbhh, mem_newb, N);
  pred_mfma<<<(E + 63) / 64, 256, 0, stream>>>(src, dst, x_static, mem_newb, houtb,
      Wcombb, tab_p, tab_s, bias2, W2, b2, out, E);
}

// Round 12
// 412.992 us; speedup vs baseline: 7.2388x; 1.0265x over previous
//
#include <hip/hip_runtime.h>

#define H 128
#define EF 32
#define TT 14
#define LH 32
#define KDIM 416   // 3H+EF
#define GOUT 512   // [r_pre, z_pre, i_n, h_n] each 128
#define KTOT 544   // 416 (agg) + 128 (memory)
#define KP 288     // pred GEMM K: 128 ms + 128 md + 32 h

typedef __attribute__((ext_vector_type(8))) short bf16x8;
typedef __attribute__((ext_vector_type(4))) float f32x4;

// native-HW nonlinearities: v_exp_f32 computes 2^x; v_rcp_f32 is ~1ulp.
__device__ __forceinline__ float sigmoidf_(float x) {
  float e = __builtin_amdgcn_exp2f(x * -1.442695041f);   // exp(-x)
  return __builtin_amdgcn_rcpf(1.0f + e);
}
__device__ __forceinline__ float tanhfast_(float x) {
  float e = __builtin_amdgcn_exp2f(x * 2.885390082f);    // exp(2x)
  return 1.0f - 2.0f * __builtin_amdgcn_rcpf(e + 1.0f);
}
__device__ __forceinline__ ushort f2bf(float x) {
  uint u = __float_as_uint(x);
  u += 0x7fff + ((u >> 16) & 1);   // RTNE
  return (ushort)(u >> 16);
}

// ---------- K_pre: fused {mem->bf16 convert | count | build WcatT | prep_pred} ----------
__global__ __launch_bounds__(256) void pre_kernel(
    const float* __restrict__ Wih, const float* __restrict__ Whh,
    ushort* __restrict__ WcatT,
    const float* __restrict__ W1, const float* __restrict__ b1,
    const float* __restrict__ static_W, const float* __restrict__ static_b,
    const float* __restrict__ price_W, const float* __restrict__ price_b,
    const float* __restrict__ party_emb, const float* __restrict__ state_emb,
    ushort* __restrict__ Wcombb, float* __restrict__ tab_p, float* __restrict__ tab_s,
    float* __restrict__ bias2,
    const float* __restrict__ mem, ushort* __restrict__ mem_b,
    const int* __restrict__ src, const int* __restrict__ dst, int* cnt,
    int E, int N, int nbC, int nbN, int nbB) {
  __shared__ float G1s[4][32];
  int b = blockIdx.x;
  int tid = threadIdx.x;
  if (b < nbC) {
    // convert memory -> bf16 rows (gather operand for agg)
    int total = N * H;
    for (int i = tid + 256 * b; i < total; i += 256 * nbC) mem_b[i] = f2bf(mem[i]);
  } else if (b < nbC + nbN) {
    // degree count
    int cb = b - nbC;
    for (int e = tid + 256 * cb; e < E; e += 256 * nbN) {
      atomicAdd(&cnt[dst[e]], 1);
      atomicAdd(&cnt[src[e]], 1);
    }
  } else if (b < nbC + nbN + nbB) {
    // build WcatT bf16 [512][544]
    int i = (b - nbC - nbN) * 256 + tid;
    if (i < GOUT * KTOT) {
      int o = i / KTOT, k = i % KTOT;
      int j = o & 127;
      float v = 0.f;
      if (o < 256) {
        int row = (o < 128) ? j : (128 + j);
        v = (k < KDIM) ? Wih[row * KDIM + k] : Whh[row * H + (k - KDIM)];
      } else if (o < 384) {
        v = (k < KDIM) ? Wih[(256 + j) * KDIM + k] : 0.f;
      } else {
        v = (k < KDIM) ? 0.f : Whh[(256 + j) * H + (k - KDIM)];
      }
      WcatT[i] = f2bf(v);
    }
  } else {
    // prep_pred: 16 blocks x 4 o-rows
    int ob = (b - nbC - nbN - nbB) * 4;
    if (tid < 128) {
      int ol = tid >> 5, k = tid & 31;
      int o = ob + ol;
      float g = 0.f, m = 0.f;
      for (int j = 0; j < 128; j++) {
        g = fmaf(W1[o * 384 + j], static_W[j * 32 + k], g);
        m = fmaf(W1[o * 384 + 128 + j] + W1[o * 384 + 256 + j], price_W[j * 32 + k], m);
      }
      G1s[ol][k] = g;
      Wcombb[o * KP + 256 + k] = f2bf(m);
    }
    for (int idx = tid; idx < 1024; idx += 256) {
      int ol = idx >> 8, j = idx & 255;
      int o = ob + ol;
      Wcombb[o * KP + j] = f2bf(W1[o * 384 + j]);
    }
    __syncthreads();
    for (int idx = tid; idx < 216; idx += 256) {
      if (idx < 16) {
        int p = idx >> 2, ol = idx & 3;
        float s = 0.f;
        for (int k = 0; k < 16; k++) s = fmaf(G1s[ol][k], party_emb[p * 16 + k], s);
        tab_p[p * 64 + ob + ol] = s;
      } else {
        int i2 = idx - 16;
        int si = i2 >> 2, ol = i2 & 3;
        float s = 0.f;
        for (int k = 0; k < 16; k++) s = fmaf(G1s[ol][16 + k], state_emb[si * 16 + k], s);
        tab_s[si * 64 + ob + ol] = s;
      }
    }
    if (tid < 4) {
      int o = ob + tid;
      float s = b1[o];
      for (int j = 0; j < 128; j++) {
        s = fmaf(W1[o * 384 + j], static_b[j], s);
        s = fmaf(W1[o * 384 + 128 + j] + W1[o * 384 + 256 + j], price_b[j], s);
      }
      bias2[o] = s;
    }
  }
}

// ---------------- K2b: exclusive scan (single block) ----------------
__global__ __launch_bounds__(1024) void scan_kernel(const int* __restrict__ cnt,
                                                    int* __restrict__ offs,
                                                    int* __restrict__ cursor, int N) {
  __shared__ int part[1024];
  int tid = threadIdx.x;
  int chunk = (N + 1023) / 1024;
  int beg = tid * chunk;
  int end = min(beg + chunk, N);
  int s = 0;
  for (int i = beg; i < end; i++) s += cnt[i];
  part[tid] = s;
  __syncthreads();
  for (int d = 1; d < 1024; d <<= 1) {
    int v = (tid >= d) ? part[tid - d] : 0;
    __syncthreads();
    part[tid] += v;
    __syncthreads();
  }
  int run = (tid > 0) ? part[tid - 1] : 0;
  for (int i = beg; i < end; i++) {
    offs[i] = run;
    cursor[i] = run;
    run += cnt[i];
  }
  if (tid == 1023) offs[N] = part[1023];
}

// ---------------- K2c: CSR fill ----------------
__global__ void fill_kernel(const int* __restrict__ src, const int* __restrict__ dst,
                            int* cursor, int* __restrict__ other, int* __restrict__ eid, int E) {
  int e = blockIdx.x * blockDim.x + threadIdx.x;
  if (e >= E) return;
  int s = src[e], d = dst[e];
  int p1 = atomicAdd(&cursor[d], 1);
  other[p1] = s; eid[p1] = e;
  int p2 = atomicAdd(&cursor[s], 1);
  other[p2] = d; eid[p2] = e;
}

// ---------------- FUSED: lstm blocks [0,nL) + agg blocks [nL, nL+N) ----------------
__global__ __launch_bounds__(512) void agg_lstm_kernel(
    const int* __restrict__ offs, const int* __restrict__ other, const int* __restrict__ eid,
    const float* __restrict__ mem, const ushort* __restrict__ mem_b,
    const float* __restrict__ msg,
    const float* __restrict__ t, const float* __restrict__ lu,
    const float* __restrict__ tw, const float* __restrict__ tb,
    const int* __restrict__ cnt, ushort* __restrict__ agg_b, int N,
    const float* __restrict__ price_seq,
    const float* __restrict__ lWih, const float* __restrict__ lWhh,
    const float* __restrict__ lbih, const float* __restrict__ lbhh,
    ushort* __restrict__ houtb, int E, int nL) {
  __shared__ union {
    struct { int ld_oth[256]; int ld_eid[256]; float red[16 * 292]; } a;  // 20.7 KB
    float ps[128][15];                                                    // 7.7 KB
  } sm;
  int tid = threadIdx.x;

  if ((int)blockIdx.x < nL) {
    // ================= LSTM path: 8 waves x 16 edges = 128 edges =================
    int lane = tid & 63;
    int el = lane & 15;
    int g = lane >> 4;
    int wv = tid >> 6;                 // 0..7
    int row0 = blockIdx.x * 128;
    int el_local = wv * 16 + el;       // 0..127
    int e = row0 + el_local;
    bool valid = (e < E);

    for (int idx = tid; idx < 128 * TT; idx += 512) {
      int row = idx / TT, col = idx % TT;
      int ee = min(row0 + row, E - 1);
      sm.ps[row][col] = price_seq[(size_t)ee * TT + col];
    }
    __syncthreads();

    union { uint u[4]; bf16x8 v; } afr[8];
#pragma unroll
    for (int b = 0; b < 8; b++) {
      const float* wr = lWhh + (16 * b + el) * LH + g * 8;
#pragma unroll
      for (int q = 0; q < 4; q++) {
        float lo = wr[2 * q], hi = wr[2 * q + 1];
        asm("v_cvt_pk_bf16_f32 %0, %1, %2" : "=v"(afr[b].u[q]) : "v"(lo), "v"(hi));
      }
    }
    uint afr2w[8];
#pragma unroll
    for (int b = 0; b < 8; b++) {
      float wvv = lWih[16 * b + el];
      float bv = lbih[16 * b + el] + lbhh[16 * b + el];
      uint pk;
      asm("v_cvt_pk_bf16_f32 %0, %1, %2" : "=v"(pk) : "v"(wvv), "v"(bv));
      afr2w[b] = (g == 0) ? pk : 0u;
    }

    int addr_i[4];
#pragma unroll
    for (int i = 0; i < 4; i++) addr_i[i] = (el + 16 * ((g & 1) * 2 + (i >> 1))) << 2;
    bool hi_sel = (g >> 1) != 0;

    float cst[8];
#pragma unroll
    for (int i = 0; i < 8; i++) cst[i] = 0.f;
    uint hpk[4] = {0u, 0u, 0u, 0u};
    const f32x4 zero4 = {0.f, 0.f, 0.f, 0.f};

#pragma unroll 1
    for (int tt = 0; tt < TT; tt++) {
      union { uint u[4]; bf16x8 v; } bfr;
#pragma unroll
      for (int i = 0; i < 4; i++) {
        uint lo = (uint)__builtin_amdgcn_ds_bpermute(addr_i[i], (int)hpk[i & 1]);
        uint hi = (uint)__builtin_amdgcn_ds_bpermute(addr_i[i], (int)hpk[2 + (i & 1)]);
        bfr.u[i] = hi_sel ? hi : lo;
      }
      float x = sm.ps[el_local][tt];
      union { uint u[4]; bf16x8 v; } bfr2;
      uint xp;
      asm("v_cvt_pk_bf16_f32 %0, %1, %2" : "=v"(xp) : "v"(x), "v"(1.0f));
      bfr2.u[0] = (g == 0) ? xp : 0u;
      bfr2.u[1] = 0u; bfr2.u[2] = 0u; bfr2.u[3] = 0u;

      float hval[8];
      f32x4 acc0, acc1, acc2, acc3, acc4, acc5, acc6, acc7;
#define STEPACC(b, A) \
      { union { uint u[4]; bf16x8 v; } a2; a2.u[0] = afr2w[b]; a2.u[1] = 0u; a2.u[2] = 0u; a2.u[3] = 0u; \
        A = __builtin_amdgcn_mfma_f32_16x16x32_bf16(a2.v, bfr2.v, zero4, 0, 0, 0); \
        A = __builtin_amdgcn_mfma_f32_16x16x32_bf16(afr[b].v, bfr.v, A, 0, 0, 0); }
      STEPACC(0, acc0) STEPACC(1, acc1) STEPACC(2, acc2) STEPACC(3, acc3)
      STEPACC(4, acc4) STEPACC(5, acc5) STEPACC(6, acc6) STEPACC(7, acc7)
#undef STEPACC
#define NONLIN(b1, AI, AF, AG, AO) \
      { _Pragma("unroll") for (int r = 0; r < 4; r++) { \
          int mi = 4 * b1 + r; \
          float ig = sigmoidf_(AI[r]); \
          float fg = sigmoidf_(AF[r]); \
          float gg = tanhfast_(AG[r]); \
          float og = sigmoidf_(AO[r]); \
          float cv = fmaf(fg, cst[mi], ig * gg); \
          cst[mi] = cv; \
          hval[mi] = og * tanhfast_(cv); } }
      NONLIN(0, acc0, acc2, acc4, acc6)
      NONLIN(1, acc1, acc3, acc5, acc7)
#undef NONLIN
#pragma unroll
      for (int i = 0; i < 4; i++)
        asm("v_cvt_pk_bf16_f32 %0, %1, %2" : "=v"(hpk[i]) : "v"(hval[2 * i]), "v"(hval[2 * i + 1]));
    }

    if (valid) {
      uint2* rowp = reinterpret_cast<uint2*>(houtb + (size_t)e * LH);
      rowp[g] = make_uint2(hpk[0], hpk[1]);
      rowp[4 + g] = make_uint2(hpk[2], hpk[3]);
    }
  } else {
    // ================= AGG path: 16 groups x 32 lanes, 4-deep gather =================
    int grp = tid >> 5;
    int l = tid & 31;
    int v = blockIdx.x - nL;
    int beg = offs[v], end = offs[v + 1];
    int deg = end - beg;
    int ndeg = min(deg, 256);
    for (int i = tid; i < ndeg; i += 512) {
      sm.a.ld_oth[i] = other[beg + i];
      sm.a.ld_eid[i] = eid[beg + i];
    }
    __syncthreads();

    float lupd = lu[v];
    float4 w4 = *reinterpret_cast<const float4*>(tw + 4 * l);
    float4 b4 = *reinterpret_cast<const float4*>(tb + 4 * l);
    float a0q0 = 0.f, a0q1 = 0.f, a0q2 = 0.f, a0q3 = 0.f;
    float ac0 = 0.f, ac1 = 0.f, ac2 = 0.f, ac3 = 0.f;
    float amsg = 0.f;
    for (int p0 = grp; p0 < deg; p0 += 64) {
      int uu[4], ee[4];
      float mk[4];
#pragma unroll
      for (int i = 0; i < 4; i++) {
        int p = p0 + 16 * i;
        bool val = (p < deg);
        int ps = val ? p : p0;
        int u, e;
        if (ps < 256) { u = sm.a.ld_oth[ps]; e = sm.a.ld_eid[ps]; }
        else { u = other[beg + ps]; e = eid[beg + ps]; }
        uu[i] = u; ee[i] = e; mk[i] = val ? 1.f : 0.f;
      }
      uint2 mr[4];
      float tv[4], mg[4];
#pragma unroll
      for (int i = 0; i < 4; i++) {
        mr[i] = *reinterpret_cast<const uint2*>(mem_b + (size_t)uu[i] * H + 4 * l);
        tv[i] = t[ee[i]];
        mg[i] = msg[ee[i] * EF + l];
      }
#pragma unroll
      for (int i = 0; i < 4; i++) {
        float m = mk[i];
        float x0 = __uint_as_float(mr[i].x << 16);
        float x1 = __uint_as_float(mr[i].x & 0xffff0000u);
        float x2 = __uint_as_float(mr[i].y << 16);
        float x3 = __uint_as_float(mr[i].y & 0xffff0000u);
        a0q0 = fmaf(x0, m, a0q0); a0q1 = fmaf(x1, m, a0q1);
        a0q2 = fmaf(x2, m, a0q2); a0q3 = fmaf(x3, m, a0q3);
        float dt = tv[i] - lupd;
        ac0 = fmaf(__cosf(fmaf(dt, w4.x, b4.x)), m, ac0);
        ac1 = fmaf(__cosf(fmaf(dt, w4.y, b4.y)), m, ac1);
        ac2 = fmaf(__cosf(fmaf(dt, w4.z, b4.z)), m, ac2);
        ac3 = fmaf(__cosf(fmaf(dt, w4.w, b4.w)), m, ac3);
        amsg = fmaf(mg[i], m, amsg);
      }
    }
    float* r = sm.a.red + grp * 292;
    r[4 * l + 0] = a0q0; r[4 * l + 1] = a0q1; r[4 * l + 2] = a0q2; r[4 * l + 3] = a0q3;
    r[128 + 4 * l + 0] = ac0; r[128 + 4 * l + 1] = ac1;
    r[128 + 4 * l + 2] = ac2; r[128 + 4 * l + 3] = ac3;
    r[256 + l] = amsg;
    __syncthreads();

    int cv = cnt[v];
    float inv = 1.f / (float)max(cv, 1);
    ushort* arow = agg_b + (size_t)v * KTOT;
    if (tid < 288) {
      float s = 0.f;
#pragma unroll
      for (int g2 = 0; g2 < 16; g2++) s += sm.a.red[g2 * 292 + tid];
      s *= inv;
      if (tid < 128) arow[tid] = f2bf(s);                     // mean neighbor mem
      else if (tid < 256) arow[288 + (tid - 128)] = f2bf(s);  // mean cos
      else arow[256 + (tid - 256)] = f2bf(s);                 // mean msg
    } else if (tid < 416) {
      int c = tid - 288;
      float mv = mem[(size_t)v * H + c];
      arow[128 + c] = f2bf((cv > 0) ? mv : 0.f);  // mean of cv copies of mem[v]
      arow[416 + c] = f2bf(mv);                   // Whh operand
    }
  }
}

// ---------------- K3: MFMA GEMM + fused GRU finalize -> mem_newb bf16 [N][128] ----------------
__global__ __launch_bounds__(256) void gru_gemm_mfma(
    const ushort* __restrict__ aggb, const ushort* __restrict__ WcatT,
    const float* __restrict__ mem, const int* __restrict__ cnt,
    const float* __restrict__ bih, const float* __restrict__ bhh,
    ushort* __restrict__ mem_newb, int N) {
  __shared__ union {
    ushort a[32 * 552];       // 35.3 KB
    float g[4][32][132];      // 67.6 KB
  } sm;
  int tid = threadIdx.x;
  int lane = tid & 63;
  int w = tid >> 6;
  int n0 = blockIdx.x * 32;

#pragma unroll
  for (int i = 0; i < 8; i++) {
    int row = w * 8 + i;
    int gr = min(n0 + row, N - 1);
    const uint4* srcp = reinterpret_cast<const uint4*>(aggb + (size_t)gr * KTOT);
    uint4* dstp = reinterpret_cast<uint4*>(sm.a + row * 552);
    dstp[lane] = srcp[lane];
    if (lane < 4) dstp[64 + lane] = srcp[64 + lane];
  }
  __syncthreads();

  f32x4 acc[2][8] = {};
  int arow_b = (lane & 15);
  int koff = (lane >> 4) * 8;
  for (int ks = 0; ks < 17; ks++) {
    int k = ks * 32 + koff;
    bf16x8 afr0 = *reinterpret_cast<const bf16x8*>(sm.a + (arow_b) * 552 + k);
    bf16x8 afr1 = *reinterpret_cast<const bf16x8*>(sm.a + (16 + arow_b) * 552 + k);
#pragma unroll
    for (int nt = 0; nt < 8; nt++) {
      int o = w * 128 + nt * 16 + (lane & 15);
      bf16x8 bfr = *reinterpret_cast<const bf16x8*>(WcatT + (size_t)o * KTOT + k);
      acc[0][nt] = __builtin_amdgcn_mfma_f32_16x16x32_bf16(afr0, bfr, acc[0][nt], 0, 0, 0);
      acc[1][nt] = __builtin_amdgcn_mfma_f32_16x16x32_bf16(afr1, bfr, acc[1][nt], 0, 0, 0);
    }
  }
  __syncthreads();  // A reads done; reuse LDS

#pragma unroll
  for (int mt = 0; mt < 2; mt++)
#pragma unroll
    for (int nt = 0; nt < 8; nt++)
#pragma unroll
      for (int r = 0; r < 4; r++)
        sm.g[w][mt * 16 + (lane >> 4) * 4 + r][nt * 16 + (lane & 15)] = acc[mt][nt][r];
  __syncthreads();

  int row = tid >> 3, j0 = (tid & 7) * 16;
  int n = n0 + row;
  if (n < N) {
    int cv = cnt[n];
#pragma unroll
    for (int jj = 0; jj < 16; jj++) {
      int j = j0 + jj;
      float m = mem[(size_t)n * H + j];
      float o;
      if (cv > 0) {
        float rp = sm.g[0][row][j] + bih[j] + bhh[j];
        float zp = sm.g[1][row][j] + bih[128 + j] + bhh[128 + j];
        float ip = sm.g[2][row][j] + bih[256 + j];
        float hp = sm.g[3][row][j] + bhh[256 + j];
        float r = sigmoidf_(rp), z = sigmoidf_(zp);
        float nn = tanhfast_(ip + r * hp);
        o = (1.f - z) * nn + z * m;
      } else {
        o = m;
      }
      mem_newb[(size_t)n * H + j] = f2bf(o);
    }
  }
}

// ---------------- K5b: pred bf16 MFMA: out[E] from X[E][288] @ Wcombb^T ----------------
__global__ __launch_bounds__(256) void pred_mfma(
    const int* __restrict__ src, const int* __restrict__ dst,
    const int* __restrict__ x_static,
    const ushort* __restrict__ mem_newb, const ushort* __restrict__ houtb,
    const ushort* __restrict__ Wcombb, const float* __restrict__ tab_p,
    const float* __restrict__ tab_s, const float* __restrict__ bias2,
    const float* __restrict__ W2, const float* __restrict__ b2,
    float* __restrict__ out, int E) {
  __shared__ ushort Asm[64 * 296];
  __shared__ int pidx[64], stix[64];
  __shared__ int sidx[64], didx[64];
  int tid = threadIdx.x;
  int row0 = blockIdx.x * 64;
  if (tid < 64) {
    int e = min(row0 + tid, E - 1);
    int s = src[e], d = dst[e];
    sidx[tid] = s; didx[tid] = d;
    pidx[tid] = x_static[s * 2]; stix[tid] = x_static[s * 2 + 1];
  }
  __syncthreads();
  // stage A: 64 rows x 36 16B-chunks (16 ms + 16 md + 4 h)
#pragma unroll
  for (int i = 0; i < 9; i++) {
    int idx = tid + i * 256;
    int row = idx / 36, c = idx % 36;
    int e = min(row0 + row, E - 1);
    uint4 v;
    if (c < 16) v = reinterpret_cast<const uint4*>(mem_newb + (size_t)sidx[row] * H)[c];
    else if (c < 32) v = reinterpret_cast<const uint4*>(mem_newb + (size_t)didx[row] * H)[c - 16];
    else v = reinterpret_cast<const uint4*>(houtb + (size_t)e * LH)[c - 32];
    *reinterpret_cast<uint4*>(Asm + row * 296 + c * 8) = v;
  }
  __syncthreads();

  int lane = tid & 63;
  int w = tid >> 6;
  f32x4 acc[4] = {};
  int arow = w * 16 + (lane & 15);
  int koff = (lane >> 4) * 8;
  for (int ks = 0; ks < 9; ks++) {
    int k = ks * 32 + koff;
    bf16x8 afr = *reinterpret_cast<const bf16x8*>(Asm + arow * 296 + k);
#pragma unroll
    for (int nt = 0; nt < 4; nt++) {
      int o = nt * 16 + (lane & 15);
      bf16x8 bfr = *reinterpret_cast<const bf16x8*>(Wcombb + (size_t)o * KP + k);
      acc[nt] = __builtin_amdgcn_mfma_f32_16x16x32_bf16(afr, bfr, acc[nt], 0, 0, 0);
    }
  }
  // epilogue: lane holds D[edge=(lane>>4)*4+r][o=nt*16+(lane&15)]
  int ocol = lane & 15;
  float bb2 = b2[0];
#pragma unroll
  for (int r = 0; r < 4; r++) {
    int rl = w * 16 + (lane >> 4) * 4 + r;
    int p = pidx[rl], st = stix[rl];
    float s = 0.f;
#pragma unroll
    for (int nt = 0; nt < 4; nt++) {
      int o = nt * 16 + ocol;
      float hv = acc[nt][r] + bias2[o] + tab_p[p * 64 + o] + tab_s[st * 64 + o];
      s = fmaf(fmaxf(hv, 0.f), W2[o], s);
    }
#pragma unroll
    for (int d = 1; d < 16; d <<= 1) s += __shfl_xor(s, d);
    int e = row0 + rl;
    if (ocol == 0 && e < E) out[e] = s + bb2;
  }
}

// ---------------- launch ----------------
extern "C" void kernel_launch(void* const* d_in, const int* in_sizes, int n_in,
                              void* d_out, int out_size, void* d_ws, size_t ws_size,
                              hipStream_t stream) {
  const int* src = (const int*)d_in[0];
  const int* dst = (const int*)d_in[1];
  const float* t = (const float*)d_in[2];
  const float* msg = (const float*)d_in[3];
  const float* price_seq = (const float*)d_in[4];
  const int* x_static = (const int*)d_in[6];
  const float* memory = (const float*)d_in[7];
  const float* last_update = (const float*)d_in[8];
  const float* time_w = (const float*)d_in[9];
  const float* time_b = (const float*)d_in[10];
  const float* gWih = (const float*)d_in[11];
  const float* gWhh = (const float*)d_in[12];
  const float* gbih = (const float*)d_in[13];
  const float* gbhh = (const float*)d_in[14];
  const float* party_emb = (const float*)d_in[15];
  const float* state_emb = (const float*)d_in[16];
  const float* static_W = (const float*)d_in[17];
  const float* static_b = (const float*)d_in[18];
  const float* lWih = (const float*)d_in[19];
  const float* lWhh = (const float*)d_in[20];
  const float* lbih = (const float*)d_in[21];
  const float* lbhh = (const float*)d_in[22];
  const float* price_W = (const float*)d_in[23];
  const float* price_b = (const float*)d_in[24];
  const float* W1 = (const float*)d_in[25];
  const float* b1 = (const float*)d_in[26];
  const float* W2 = (const float*)d_in[27];
  const float* b2 = (const float*)d_in[28];
  float* out = (float*)d_out;

  const int E = in_sizes[0];
  const int N = in_sizes[8];

  char* ws = (char*)d_ws;
  size_t off = 0;
  auto alloc = [&](size_t bytes) { size_t o = off; off += (bytes + 255) & ~(size_t)255; return o; };
  int* cnt       = (int*)(ws + alloc((size_t)N * 4));
  int* offs      = (int*)(ws + alloc((size_t)(N + 1) * 4));
  int* cursor    = (int*)(ws + alloc((size_t)N * 4));
  int* other     = (int*)(ws + alloc((size_t)2 * E * 4));
  int* eid       = (int*)(ws + alloc((size_t)2 * E * 4));
  ushort* WcatT  = (ushort*)(ws + alloc((size_t)GOUT * KTOT * 2));
  ushort* Wcombb = (ushort*)(ws + alloc((size_t)64 * KP * 2));
  float* tab_p   = (float*)(ws + alloc((size_t)4 * 64 * 4));
  float* tab_s   = (float*)(ws + alloc((size_t)50 * 64 * 4));
  float* bias2   = (float*)(ws + alloc((size_t)64 * 4));
  ushort* agg_b  = (ushort*)(ws + alloc((size_t)N * KTOT * 2));
  ushort* mem_newb = (ushort*)(ws + alloc((size_t)N * H * 2));
  ushort* houtb  = (ushort*)(ws + alloc((size_t)E * LH * 2));
  ushort* mem_b  = (ushort*)(ws + alloc((size_t)N * H * 2));
  (void)ws_size;

  hipMemsetAsync(cnt, 0, (size_t)N * 4, stream);

  int nbC = 128, nbN = 128, nbB = (GOUT * KTOT + 255) / 256, nbP = 16;
  pre_kernel<<<nbC + nbN + nbB + nbP, 256, 0, stream>>>(
      gWih, gWhh, WcatT, W1, b1, static_W, static_b, price_W, price_b,
      party_emb, state_emb, Wcombb, tab_p, tab_s, bias2,
      memory, mem_b, src, dst, cnt, E, N, nbC, nbN, nbB);
  scan_kernel<<<1, 1024, 0, stream>>>(cnt, offs, cursor, N);
  fill_kernel<<<(E + 255) / 256, 256, 0, stream>>>(src, dst, cursor, other, eid, E);
  int nL = (E + 127) / 128;
  agg_lstm_kernel<<<nL + N, 512, 0, stream>>>(offs, other, eid, memory, mem_b, msg, t,
                                              last_update, time_w, time_b, cnt, agg_b, N,
                                              price_seq, lWih, lWhh, lbih, lbhh, houtb, E, nL);
  gru_gemm_mfma<<<(N + 31) / 32, 256, 0, stream>>>(agg_b, WcatT, memory, cnt,
                                                   gbih, gbhh, mem_newb, N);
  pred_mfma<<<(E + 63) / 64, 256, 0, stream>>>(src, dst, x_static, mem_newb, houtb,
      Wcombb, tab_p, tab_s, bias2, W2, b2, out, E);
}